// Round 4
// baseline (604.946 us; speedup 1.0000x reference)
//
#include <hip/hip_runtime.h>
#include <hip/hip_bf16.h>
#include <cmath>

namespace {
constexpr int B_ = 16, N_ = 307, T_ = 24, C_ = 128, H_ = 8, D_ = 16, S_ = 20, U_ = 20;
constexpr int NROW = B_ * N_ * T_;          // 117888
constexpr int NX = NROW * C_;               // 15089664
constexpr int TEPE_N = B_ * T_ * C_;        // 49152
constexpr int FF = 4 * C_;                  // 512
constexpr int BM = 32;                      // rows per MFMA block (qkv/out_ln)
constexpr int NBLK_MM = NROW / BM;          // 3684
constexpr int BMF = 64;                     // rows per FF block
constexpr int NBLK_FF = NROW / BMF;         // 1842
}

typedef __attribute__((ext_vector_type(8))) short short8;
typedef __attribute__((ext_vector_type(4))) short short4_;
typedef __attribute__((ext_vector_type(4))) float f32x4;

__device__ inline short f2bf(float v) {
    union { float f; unsigned u; } a; a.f = v;
    unsigned r = a.u + 0x7fff + ((a.u >> 16) & 1);   // round-to-nearest-even
    return (short)(r >> 16);
}

// ---------------- kernel 0: tepe[b,t,c] = pos_emb(t,c) + sum of 5 embedding lookups
__global__ void k_tepe(const int* __restrict__ te,
                       const float* __restrict__ e_min, const float* __restrict__ e_hr,
                       const float* __restrict__ e_wd, const float* __restrict__ e_mo,
                       const float* __restrict__ e_yr, float* __restrict__ tepe) {
    int i = blockIdx.x * blockDim.x + threadIdx.x;
    if (i >= TEPE_N) return;
    int c = i & (C_ - 1);
    int bt = i >> 7;              // b*T + t
    int t = bt % T_;
    const int* enc = te + bt * 5;
    float v = e_min[enc[0] * C_ + c] + e_hr[enc[1] * C_ + c] + e_wd[enc[2] * C_ + c]
            + e_mo[enc[3] * C_ + c] + e_yr[enc[4] * C_ + c];
    float ang = (float)t * expf(-(float)(c & ~1) * (9.210340371976184f / 128.0f));
    v += (c & 1) ? cosf(ang) : sinf(ang);
    tepe[i] = v;
}

// ---------------- kernel 0b: xbf = bf16(query + tepe), one float4 per thread
__global__ void k_xprep(const float* __restrict__ query, const float* __restrict__ tepe,
                        short* __restrict__ xbf) {
    int i = blockIdx.x * 256 + threadIdx.x;     // i indexes float4s; NX/4 total
    int c4 = i & 31;
    int gr = i >> 5;
    int t = gr % T_;
    int b = gr / (N_ * T_);
    float4 q = *(const float4*)(query + 4 * (size_t)i);
    float4 p = *(const float4*)(tepe + (size_t)(b * T_ + t) * C_ + c4 * 4);
    short4_ s;
    s.x = f2bf(q.x + p.x); s.y = f2bf(q.y + p.y);
    s.z = f2bf(q.z + p.z); s.w = f2bf(q.w + p.w);
    *(short4_*)&xbf[4 * (size_t)i] = s;
}

// ---------------- weight converts
__global__ void k_wcvt_qkv(const float* __restrict__ Wq, const float* __restrict__ Wk,
                           const float* __restrict__ Wv, short* __restrict__ wqkvT) {
    int i = blockIdx.x * 256 + threadIdx.x;     // 49152
    int c_all = i >> 7, k = i & (C_ - 1);
    int m = c_all >> 7, c = c_all & (C_ - 1);
    const float* W = (m == 0) ? Wq : (m == 1) ? Wk : Wv;
    wqkvT[i] = f2bf(W[k * C_ + c]);
}

__global__ void k_wcvt2(const float* __restrict__ w1, const float* __restrict__ w2,
                        const float* __restrict__ Wo,
                        short* __restrict__ w1t, short* __restrict__ w2t,
                        short* __restrict__ woT) {
    int i = blockIdx.x * 256 + threadIdx.x;     // 147456
    if (i < C_ * FF) {
        int j = i >> 7, k = i & (C_ - 1);
        w1t[i] = f2bf(w1[k * FF + j]);
    } else if (i < 2 * C_ * FF) {
        int i2 = i - C_ * FF;
        int c = i2 >> 9, j = i2 & (FF - 1);
        w2t[i2] = f2bf(w2[j * C_ + c]);
    } else {
        int i3 = i - 2 * C_ * FF;
        int c = i3 >> 7, k = i3 & (C_ - 1);
        woT[i3] = f2bf(Wo[k * C_ + c]);
    }
}

// ---------------- kernel 1: QKV projection via MFMA
__global__ __launch_bounds__(256) void k_qkv_mfma(
    const short* __restrict__ xbf, const short* __restrict__ wqkvT,
    float* __restrict__ Q, float* __restrict__ K, float* __restrict__ V) {
    __shared__ __align__(16) short xs[BM * C_];
    int tid = threadIdx.x;
    int r0 = blockIdx.x * BM;
    {
        int row = tid >> 3;                 // 0..31
        int cb = (tid & 7) * 16;
        const short* src = xbf + (size_t)(r0 + row) * C_ + cb;
        short8 v0 = *(const short8*)(src);
        short8 v1 = *(const short8*)(src + 8);
        *(short8*)&xs[(row * C_ + cb) ^ ((row & 7) << 3)] = v0;
        *(short8*)&xs[(row * C_ + cb + 8) ^ ((row & 7) << 3)] = v1;
    }
    __syncthreads();
    int w = tid >> 6, l = tid & 63;
    int lr = l & 15, lk = l >> 4;
    int rt = w & 1;
    int rrow = rt * 16 + lr;
    short8 bx[4];
#pragma unroll
    for (int ks = 0; ks < 4; ks++)
        bx[ks] = *(const short8*)&xs[(rrow * C_ + ks * 32 + lk * 8) ^ ((rrow & 7) << 3)];
    int gr = r0 + rrow;
    int t = gr % T_;
    int n = (gr / T_) % N_;
    int b = gr / (N_ * T_);
    size_t base = ((size_t)b * H_ * N_ + n) * (T_ * D_) + t * D_;
    int cg = w >> 1;
#pragma unroll
    for (int jt = 0; jt < 12; jt++) {
        int c_all0 = (cg * 12 + jt) * 16;       // tile base col in [0,384)
        const short* ap = wqkvT + (size_t)(c_all0 + lr) * C_;
        f32x4 acc = {0.f, 0.f, 0.f, 0.f};
#pragma unroll
        for (int ks = 0; ks < 4; ks++) {
            short8 af = *(const short8*)(ap + ks * 32 + lk * 8);
            acc = __builtin_amdgcn_mfma_f32_16x16x32_bf16(af, bx[ks], acc, 0, 0, 0);
        }
        int c0 = c_all0 + lk * 4;
        int m = c0 >> 7;
        int c = c0 & (C_ - 1);
        int h = c >> 4, d = c & 15;
        float* dst = (m == 0) ? Q : (m == 1) ? K : V;
        *(float4*)&dst[base + (size_t)h * (N_ * T_ * D_) + d] = *(float4*)&acc;
    }
}

// helper: dot of two 16-float LDS rows (16B-aligned)
__device__ inline float dot16(const float* a, const float* b) {
    float4 a0 = *(const float4*)(a), a1 = *(const float4*)(a + 4);
    float4 a2 = *(const float4*)(a + 8), a3 = *(const float4*)(a + 12);
    float4 b0 = *(const float4*)(b), b1 = *(const float4*)(b + 4);
    float4 b2 = *(const float4*)(b + 8), b3 = *(const float4*)(b + 12);
    float s = a0.x * b0.x + a0.y * b0.y + a0.z * b0.z + a0.w * b0.w;
    s += a1.x * b1.x + a1.y * b1.y + a1.z * b1.z + a1.w * b1.w;
    s += a2.x * b2.x + a2.y * b2.y + a2.z * b2.z + a2.w * b2.w;
    s += a3.x * b3.x + a3.y * b3.y + a3.z * b3.z + a3.w * b3.w;
    return s;
}

// ---------------- kernel 2: attention core, one block per (b,h,n)
__global__ __launch_bounds__(128) void k_attn(
    const float* __restrict__ Q, const float* __restrict__ K, const float* __restrict__ V,
    const int* __restrict__ idxs, float* __restrict__ ctx) {
    __shared__ __align__(16) float Qs[T_][D_], Ks[T_][D_], Vs[T_][D_];
    __shared__ float qk[T_][S_ + 1];
    __shared__ float sc[T_][T_ + 1];
    __shared__ float Mv[T_];
    __shared__ int keep[T_];
    __shared__ float meanV[D_];
    __shared__ int sidx[T_ * S_];
    int e = blockIdx.x;
    int tid = threadIdx.x;
    const float* qb = Q + (size_t)e * T_ * D_;
    const float* kb = K + (size_t)e * T_ * D_;
    const float* vb = V + (size_t)e * T_ * D_;
    for (int i = tid; i < T_ * D_; i += 128) {
        ((float*)Qs)[i] = qb[i];
        ((float*)Ks)[i] = kb[i];
        ((float*)Vs)[i] = vb[i];
    }
    for (int i = tid; i < T_ * S_; i += 128) sidx[i] = idxs[i];
    __syncthreads();
    for (int i = tid; i < T_ * S_; i += 128) {
        int t = i / S_, s = i - t * S_;
        qk[t][s] = dot16(Qs[t], Ks[sidx[i]]);
    }
    __syncthreads();
    if (tid < T_) {
        float mx = -1e30f, sm = 0.f;
        for (int s = 0; s < S_; s++) { float v = qk[tid][s]; mx = fmaxf(mx, v); sm += v; }
        Mv[tid] = mx - sm * (1.0f / S_);
    } else if (tid >= 64 && tid < 64 + D_) {
        int d = tid - 64;
        float s = 0.f;
        for (int t = 0; t < T_; t++) s += Vs[t][d];
        meanV[d] = s * (1.0f / T_);
    }
    __syncthreads();
    if (tid < T_) {
        float mt = Mv[tid];
        int cnt = 0;
        for (int t2 = 0; t2 < T_; t2++) {
            float m2 = Mv[t2];
            cnt += (m2 > mt) || (m2 == mt && t2 < tid);
        }
        keep[tid] = (cnt < U_) ? 1 : 0;
    }
    for (int i = tid; i < T_ * T_; i += 128) {
        int t = i / T_, t2 = i - t * T_;
        sc[t][t2] = 0.25f * dot16(Qs[t], Ks[t2]);   // 1/sqrt(16)
    }
    __syncthreads();
    if (tid < T_) {
        float mx = -1e30f;
        for (int t2 = 0; t2 < T_; t2++) mx = fmaxf(mx, sc[tid][t2]);
        float sum = 0.f;
        for (int t2 = 0; t2 < T_; t2++) { float ev = expf(sc[tid][t2] - mx); sc[tid][t2] = ev; sum += ev; }
        float inv = 1.0f / sum;
        for (int t2 = 0; t2 < T_; t2++) sc[tid][t2] *= inv;
    }
    __syncthreads();
    int b = e / (H_ * N_);
    int h = (e / N_) % H_;
    int n = e % N_;
    for (int i = tid; i < T_ * D_; i += 128) {
        int t = i >> 4, d = i & 15;
        float o;
        if (keep[t]) {
            float s = 0.f;
            for (int t2 = 0; t2 < T_; t2++) s += sc[t][t2] * Vs[t2][d];
            o = s;
        } else {
            o = meanV[d];
        }
        ctx[((b * N_ + n) * T_ + t) * C_ + h * D_ + d] = o;
    }
}

// ---------------- kernel 3: att_out = ctx@Wo + bo (MFMA); y = att_out + x; x1 = LN1(y)
__global__ __launch_bounds__(256) void k_out_ln_mfma(
    const float* __restrict__ ctx, const short* __restrict__ woT, const float* __restrict__ bo,
    const float* __restrict__ query, const float* __restrict__ tepe,
    const float* __restrict__ g1, const float* __restrict__ b1,
    float* __restrict__ x1) {
    __shared__ __align__(16) short cbf[BM * C_];
    __shared__ __align__(16) float xf[BM][132];
    int tid = threadIdx.x;
    int r0 = blockIdx.x * BM;
    {
        int row = tid >> 3;
        int cb = (tid & 7) * 16;
        int gr = r0 + row;
        int t = gr % T_;
        int b = gr / (N_ * T_);
        const float* src = ctx + (size_t)gr * C_ + cb;
        const float* qsrc = query + (size_t)gr * C_ + cb;
        const float* tsrc = tepe + (size_t)(b * T_ + t) * C_ + cb;
#pragma unroll
        for (int i = 0; i < 4; i++) {
            float4 v = *(const float4*)(src + 4 * i);
            short4_ sv;
            sv.x = f2bf(v.x); sv.y = f2bf(v.y); sv.z = f2bf(v.z); sv.w = f2bf(v.w);
            *(short4_*)&cbf[(row * C_ + cb + 4 * i) ^ ((row & 7) << 3)] = sv;
            float4 q4 = *(const float4*)(qsrc + 4 * i);
            float4 t4 = *(const float4*)(tsrc + 4 * i);
            float4 xr;
            xr.x = q4.x + t4.x; xr.y = q4.y + t4.y;
            xr.z = q4.z + t4.z; xr.w = q4.w + t4.w;
            *(float4*)&xf[row][cb + 4 * i] = xr;
        }
    }
    __syncthreads();
    int w = tid >> 6, l = tid & 63;
    int lr = l & 15, lk = l >> 4;
    int rt = w & 1;
    int rrow = rt * 16 + lr;
    short8 bc[4];
#pragma unroll
    for (int ks = 0; ks < 4; ks++)
        bc[ks] = *(const short8*)&cbf[(rrow * C_ + ks * 32 + lk * 8) ^ ((rrow & 7) << 3)];
    int cg = w >> 1;
#pragma unroll
    for (int ct = 0; ct < 4; ct++) {
        int c0t = cg * 64 + ct * 16;
        const short* ap = woT + (size_t)(c0t + lr) * C_;
        f32x4 acc = {0.f, 0.f, 0.f, 0.f};
#pragma unroll
        for (int ks = 0; ks < 4; ks++) {
            short8 af = *(const short8*)(ap + ks * 32 + lk * 8);
            acc = __builtin_amdgcn_mfma_f32_16x16x32_bf16(af, bc[ks], acc, 0, 0, 0);
        }
        int cc = c0t + lk * 4;
        float4 bias = *(const float4*)(bo + cc);
        float4 res = *(const float4*)&xf[rrow][cc];
        float4 o;
        o.x = acc.x + bias.x + res.x;
        o.y = acc.y + bias.y + res.y;
        o.z = acc.z + bias.z + res.z;
        o.w = acc.w + bias.w + res.w;
        *(float4*)&xf[rrow][cc] = o;
    }
    __syncthreads();
    {
        int r = tid >> 3;
        int q = tid & 7;
        int cb = q * 16;
        float vals[16];
        float s = 0.f;
#pragma unroll
        for (int i = 0; i < 16; i++) { vals[i] = xf[r][cb + i]; s += vals[i]; }
        s += __shfl_xor(s, 1, 8);
        s += __shfl_xor(s, 2, 8);
        s += __shfl_xor(s, 4, 8);
        float mean = s * (1.f / C_);
        float vv = 0.f;
#pragma unroll
        for (int i = 0; i < 16; i++) { float d = vals[i] - mean; vv += d * d; }
        vv += __shfl_xor(vv, 1, 8);
        vv += __shfl_xor(vv, 2, 8);
        vv += __shfl_xor(vv, 4, 8);
        float rstd = rsqrtf(vv * (1.f / C_) + 1e-5f);
        float* op = x1 + (size_t)(r0 + r) * C_ + cb;
#pragma unroll
        for (int i4 = 0; i4 < 4; i4++) {
            float4 gv = *(const float4*)(g1 + cb + 4 * i4);
            float4 bv = *(const float4*)(b1 + cb + 4 * i4);
            float4 ov;
            ov.x = (vals[4 * i4 + 0] - mean) * rstd * gv.x + bv.x;
            ov.y = (vals[4 * i4 + 1] - mean) * rstd * gv.y + bv.y;
            ov.z = (vals[4 * i4 + 2] - mean) * rstd * gv.z + bv.z;
            ov.w = (vals[4 * i4 + 3] - mean) * rstd * gv.w + bv.w;
            *(float4*)(op + 4 * i4) = ov;
        }
    }
}

// ---------------- kernel 4: FF via bf16 MFMA + residual + LN2 -> out
// BMF=64 rows, 512 threads (8 waves), LDS = xbf(16K) + hbf(64K) = 80KB -> 2 blocks/CU
// = 16 waves/CU (4/SIMD). GEMM1: 1-deep weight prefetch. GEMM2: ks-outer, 4
// independent acc tiles per wave, 1-deep prefetch of a[4]+bh. y is written into
// the hbf region (dead after the post-loop barrier); residual re-read from x1.
__global__ __launch_bounds__(512, 4) void k_ff_mfma(
    const float* __restrict__ x1, const short* __restrict__ w1t, const float* __restrict__ b1f,
    const short* __restrict__ w2t, const float* __restrict__ b2f,
    const float* __restrict__ g2, const float* __restrict__ b2ln,
    float* __restrict__ out) {
    __shared__ __align__(16) short xbf[BMF * C_];    // 16 KB, bf16 x, swizzled
    __shared__ __align__(16) short hbf[BMF * FF];    // 64 KB, bf16 hidden, swizzled
    float (*yf)[132] = (float(*)[132])hbf;           // f32 y aliases hbf (33 KB)
    int tid = threadIdx.x;
    int r0 = blockIdx.x * BMF;
    // ---- stage x tile (f32 -> bf16, swizzled)
    {
        int row = tid >> 3;                 // 0..63
        int cb = (tid & 7) * 16;
        const float* src = x1 + (size_t)(r0 + row) * C_ + cb;
#pragma unroll
        for (int i = 0; i < 4; i++) {
            float4 v = *(const float4*)(src + 4 * i);
            short4_ sv;
            sv.x = f2bf(v.x); sv.y = f2bf(v.y); sv.z = f2bf(v.z); sv.w = f2bf(v.w);
            *(short4_*)&xbf[(row * C_ + cb + 4 * i) ^ ((row & 7) << 3)] = sv;
        }
    }
    __syncthreads();
    int w = tid >> 6, l = tid & 63;
    int lr = l & 15, lk = l >> 4;           // lk in 0..3
    int rt = w & 3;                         // 4 row-tiles of 16
    int rrow = rt * 16 + lr;                // 0..63
    // ---- GEMM1: hidden^T tiles; wave covers j in [jh*256, jh*256+256)
    {
        short8 bx[4];
#pragma unroll
        for (int ks = 0; ks < 4; ks++)
            bx[ks] = *(const short8*)&xbf[(rrow * C_ + ks * 32 + lk * 8) ^ ((rrow & 7) << 3)];
        int j0base = (w >> 2) * 256;
        const short* wbase = w1t + (size_t)(j0base + lr) * C_ + lk * 8;
        short8 acur[4], anxt[4];
#pragma unroll
        for (int ks = 0; ks < 4; ks++) acur[ks] = *(const short8*)(wbase + ks * 32);
#pragma unroll
        for (int jt = 0; jt < 16; jt++) {
            if (jt < 15) {
                const short* np = wbase + (size_t)(jt + 1) * 16 * C_;
#pragma unroll
                for (int ks = 0; ks < 4; ks++) anxt[ks] = *(const short8*)(np + ks * 32);
            }
            f32x4 acc = {0.f, 0.f, 0.f, 0.f};
#pragma unroll
            for (int ks = 0; ks < 4; ks++)
                acc = __builtin_amdgcn_mfma_f32_16x16x32_bf16(acur[ks], bx[ks], acc, 0, 0, 0);
            int j0 = j0base + jt * 16 + lk * 4;
            float4 bias = *(const float4*)(b1f + j0);
            short4_ hv;
            hv.x = f2bf(fmaxf(acc.x + bias.x, 0.f));
            hv.y = f2bf(fmaxf(acc.y + bias.y, 0.f));
            hv.z = f2bf(fmaxf(acc.z + bias.z, 0.f));
            hv.w = f2bf(fmaxf(acc.w + bias.w, 0.f));
            *(short4_*)&hbf[(rrow * FF + j0) ^ ((rrow & 7) << 3)] = hv;
#pragma unroll
            for (int ks = 0; ks < 4; ks++) acur[ks] = anxt[ks];
        }
    }
    __syncthreads();
    // ---- GEMM2: out^T tiles; wave covers c in [cg*64, cg*64+64), rows rt*16..+16
    f32x4 acc2[4];
    int cg = w >> 2;
    int c0base = cg * 64;
    {
#pragma unroll
        for (int ct = 0; ct < 4; ct++) acc2[ct] = (f32x4){0.f, 0.f, 0.f, 0.f};
        short8 aA[4], aB[4], hA, hB;
#pragma unroll
        for (int ct = 0; ct < 4; ct++)
            aA[ct] = *(const short8*)(w2t + (size_t)(c0base + ct * 16 + lr) * FF + lk * 8);
        hA = *(const short8*)&hbf[(rrow * FF + lk * 8) ^ ((rrow & 7) << 3)];
#pragma unroll
        for (int ks = 0; ks < 16; ks++) {
            if (ks < 15) {
                int k1 = (ks + 1) * 32 + lk * 8;
#pragma unroll
                for (int ct = 0; ct < 4; ct++)
                    aB[ct] = *(const short8*)(w2t + (size_t)(c0base + ct * 16 + lr) * FF + k1);
                hB = *(const short8*)&hbf[(rrow * FF + k1) ^ ((rrow & 7) << 3)];
            }
#pragma unroll
            for (int ct = 0; ct < 4; ct++)
                acc2[ct] = __builtin_amdgcn_mfma_f32_16x16x32_bf16(aA[ct], hA, acc2[ct], 0, 0, 0);
#pragma unroll
            for (int ct = 0; ct < 4; ct++) aA[ct] = aB[ct];
            hA = hB;
        }
    }
    // residual + bias loads overlap the barrier wait
    float4 res[4], bias2[4];
#pragma unroll
    for (int ct = 0; ct < 4; ct++) {
        int cc = c0base + ct * 16 + lk * 4;
        res[ct] = *(const float4*)(x1 + (size_t)(r0 + rrow) * C_ + cc);
        bias2[ct] = *(const float4*)(b2f + cc);
    }
    __syncthreads();    // all hbf reads done -> safe to overwrite with y
#pragma unroll
    for (int ct = 0; ct < 4; ct++) {
        int cc = c0base + ct * 16 + lk * 4;
        float4 o;
        o.x = acc2[ct].x + bias2[ct].x + res[ct].x;
        o.y = acc2[ct].y + bias2[ct].y + res[ct].y;
        o.z = acc2[ct].z + bias2[ct].z + res[ct].z;
        o.w = acc2[ct].w + bias2[ct].w + res[ct].w;
        *(float4*)&yf[rrow][cc] = o;
    }
    __syncthreads();
    // ---- LN2 + store
    {
        int r = tid >> 3;                   // 0..63
        int q = tid & 7;
        int cb = q * 16;
        float vals[16];
        float s = 0.f;
#pragma unroll
        for (int i = 0; i < 16; i++) { vals[i] = yf[r][cb + i]; s += vals[i]; }
        s += __shfl_xor(s, 1, 8);
        s += __shfl_xor(s, 2, 8);
        s += __shfl_xor(s, 4, 8);
        float mean = s * (1.f / C_);
        float vv = 0.f;
#pragma unroll
        for (int i = 0; i < 16; i++) { float d = vals[i] - mean; vv += d * d; }
        vv += __shfl_xor(vv, 1, 8);
        vv += __shfl_xor(vv, 2, 8);
        vv += __shfl_xor(vv, 4, 8);
        float rstd = rsqrtf(vv * (1.f / C_) + 1e-5f);
        float* op = out + (size_t)(r0 + r) * C_ + cb;
#pragma unroll
        for (int i4 = 0; i4 < 4; i4++) {
            float4 gv = *(const float4*)(g2 + cb + 4 * i4);
            float4 bv = *(const float4*)(b2ln + cb + 4 * i4);
            float4 ov;
            ov.x = (vals[4 * i4 + 0] - mean) * rstd * gv.x + bv.x;
            ov.y = (vals[4 * i4 + 1] - mean) * rstd * gv.y + bv.y;
            ov.z = (vals[4 * i4 + 2] - mean) * rstd * gv.z + bv.z;
            ov.w = (vals[4 * i4 + 3] - mean) * rstd * gv.w + bv.w;
            *(float4*)(op + 4 * i4) = ov;
        }
    }
}

extern "C" void kernel_launch(void* const* d_in, const int* in_sizes, int n_in,
                              void* d_out, int out_size, void* d_ws, size_t ws_size,
                              hipStream_t stream) {
    const float* query = (const float*)d_in[2];
    const int* time_enc = (const int*)d_in[4];
    const int* index_sample = (const int*)d_in[5];
    const float* e_min = (const float*)d_in[6];
    const float* e_hr  = (const float*)d_in[7];
    const float* e_wd  = (const float*)d_in[8];
    const float* e_mo  = (const float*)d_in[9];
    const float* e_yr  = (const float*)d_in[10];
    const float* Wq = (const float*)d_in[11];
    const float* Wk = (const float*)d_in[12];
    const float* Wv = (const float*)d_in[13];
    const float* Wo = (const float*)d_in[14];
    const float* bo = (const float*)d_in[15];
    const float* ffw1 = (const float*)d_in[16];
    const float* ffb1 = (const float*)d_in[17];
    const float* ffw2 = (const float*)d_in[18];
    const float* ffb2 = (const float*)d_in[19];
    const float* ln1g = (const float*)d_in[20];
    const float* ln1b = (const float*)d_in[21];
    const float* ln2g = (const float*)d_in[22];
    const float* ln2b = (const float*)d_in[23];

    float* ws = (float*)d_ws;
    float* tepe = ws;                 // TEPE_N floats
    float* Qb = ws + TEPE_N;          // NX floats; x1 aliases after attn
    float* Kb = Qb + NX;              // NX floats; w1t/w2t/woT alias after attn
    float* Vb = Kb + NX;              // NX floats
    float* ctxb = Vb + NX;            // NX floats; xbf + wqkvT alias before attn
    float* x1 = Qb;

    short* xbf = (short*)ctxb;                  // NX shorts (first half of ctx region)
    short* wqkvT = (short*)ctxb + NX;           // 49152 shorts (second half; dead before attn)
    short* w1t = (short*)Kb;                    // 65536 shorts (K dead after attn)
    short* w2t = w1t + C_ * FF;                 // 65536 shorts
    short* woT = w2t + C_ * FF;                 // 16384 shorts

    k_tepe<<<dim3(TEPE_N / 256), dim3(256), 0, stream>>>(
        time_enc, e_min, e_hr, e_wd, e_mo, e_yr, tepe);
    k_xprep<<<dim3(NX / 4 / 256), dim3(256), 0, stream>>>(query, tepe, xbf);
    k_wcvt_qkv<<<dim3(384 * C_ / 256), dim3(256), 0, stream>>>(Wq, Wk, Wv, wqkvT);
    k_qkv_mfma<<<dim3(NBLK_MM), dim3(256), 0, stream>>>(xbf, wqkvT, Qb, Kb, Vb);
    k_attn<<<dim3(B_ * H_ * N_), dim3(128), 0, stream>>>(
        Qb, Kb, Vb, index_sample, ctxb);
    k_wcvt2<<<dim3((2 * C_ * FF + C_ * C_) / 256), dim3(256), 0, stream>>>(
        ffw1, ffw2, Wo, w1t, w2t, woT);
    k_out_ln_mfma<<<dim3(NBLK_MM), dim3(256), 0, stream>>>(
        ctxb, woT, bo, query, tepe, ln1g, ln1b, x1);
    k_ff_mfma<<<dim3(NBLK_FF), dim3(512), 0, stream>>>(
        x1, w1t, ffb1, w2t, ffb2, ln2g, ln2b, (float*)d_out);
}

// Round 5
// 377.399 us; speedup vs baseline: 1.6029x; 1.6029x over previous
//
#include <hip/hip_runtime.h>
#include <hip/hip_bf16.h>
#include <cmath>

namespace {
constexpr int B_ = 16, N_ = 307, T_ = 24, C_ = 128, H_ = 8, D_ = 16, S_ = 20, U_ = 20;
constexpr int NROW = B_ * N_ * T_;          // 117888
constexpr int NX = NROW * C_;               // 15089664
constexpr int TEPE_N = B_ * T_ * C_;        // 49152
constexpr int FF = 4 * C_;                  // 512
constexpr int BM = 32;                      // rows per MFMA block (qkv/out_ln)
constexpr int NBLK_MM = NROW / BM;          // 3684
constexpr int BMF = 64;                     // rows per FF block
constexpr int NBLK_FF = NROW / BMF;         // 1842
}

typedef __attribute__((ext_vector_type(8))) short short8;
typedef __attribute__((ext_vector_type(4))) short short4_;
typedef __attribute__((ext_vector_type(4))) float f32x4;

__device__ inline short f2bf(float v) {
    union { float f; unsigned u; } a; a.f = v;
    unsigned r = a.u + 0x7fff + ((a.u >> 16) & 1);   // round-to-nearest-even
    return (short)(r >> 16);
}

// ---------------- kernel 0: tepe[b,t,c] = pos_emb(t,c) + sum of 5 embedding lookups
__global__ void k_tepe(const int* __restrict__ te,
                       const float* __restrict__ e_min, const float* __restrict__ e_hr,
                       const float* __restrict__ e_wd, const float* __restrict__ e_mo,
                       const float* __restrict__ e_yr, float* __restrict__ tepe) {
    int i = blockIdx.x * blockDim.x + threadIdx.x;
    if (i >= TEPE_N) return;
    int c = i & (C_ - 1);
    int bt = i >> 7;              // b*T + t
    int t = bt % T_;
    const int* enc = te + bt * 5;
    float v = e_min[enc[0] * C_ + c] + e_hr[enc[1] * C_ + c] + e_wd[enc[2] * C_ + c]
            + e_mo[enc[3] * C_ + c] + e_yr[enc[4] * C_ + c];
    float ang = (float)t * expf(-(float)(c & ~1) * (9.210340371976184f / 128.0f));
    v += (c & 1) ? cosf(ang) : sinf(ang);
    tepe[i] = v;
}

// ---------------- kernel 0b: xbf = bf16(query + tepe), one float4 per thread
__global__ void k_xprep(const float* __restrict__ query, const float* __restrict__ tepe,
                        short* __restrict__ xbf) {
    int i = blockIdx.x * 256 + threadIdx.x;     // i indexes float4s; NX/4 total
    int c4 = i & 31;
    int gr = i >> 5;
    int t = gr % T_;
    int b = gr / (N_ * T_);
    float4 q = *(const float4*)(query + 4 * (size_t)i);
    float4 p = *(const float4*)(tepe + (size_t)(b * T_ + t) * C_ + c4 * 4);
    short4_ s;
    s.x = f2bf(q.x + p.x); s.y = f2bf(q.y + p.y);
    s.z = f2bf(q.z + p.z); s.w = f2bf(q.w + p.w);
    *(short4_*)&xbf[4 * (size_t)i] = s;
}

// ---------------- weight converts: FRAGMENT-LINEAR layout.
// A 16x32 MFMA A-tile is stored as 512 contiguous shorts: lane l (lr=l&15,
// lk=l>>4) reads shorts [l*8, l*8+8) = A[row0+lr][k0 + lk*8 .. +8].
// So in-kernel weight loads are base + l*16B: perfectly coalesced 1KB/wave.

// wqkvf: tiles over c_all (24 tiles of 16) x ks (4): tile = (c_all/16)*4 + ks
__global__ void k_wcvt_qkv(const float* __restrict__ Wq, const float* __restrict__ Wk,
                           const float* __restrict__ Wv, short* __restrict__ wqkvf) {
    int i = blockIdx.x * 256 + threadIdx.x;     // 49152
    int tile = i >> 9, l = (i >> 3) & 63, e = i & 7;
    int c_tile = tile >> 2, ks = tile & 3;
    int c_all = c_tile * 16 + (l & 15);
    int k = ks * 32 + (l >> 4) * 8 + e;
    int m = c_all >> 7, c = c_all & (C_ - 1);
    const float* W = (m == 0) ? Wq : (m == 1) ? Wk : Wv;
    wqkvf[i] = f2bf(W[k * C_ + c]);
}

// w1f: 32 j-tiles x 4 ks; w2f: 8 c-tiles x 16 ks; wof: 8 c-tiles x 4 ks
__global__ void k_wcvt2(const float* __restrict__ w1, const float* __restrict__ w2,
                        const float* __restrict__ Wo,
                        short* __restrict__ w1f, short* __restrict__ w2f,
                        short* __restrict__ wof) {
    int i = blockIdx.x * 256 + threadIdx.x;     // 147456
    if (i < C_ * FF) {
        int tile = i >> 9, l = (i >> 3) & 63, e = i & 7;
        int jtile = tile >> 2, ks = tile & 3;
        int j = jtile * 16 + (l & 15);
        int k = ks * 32 + (l >> 4) * 8 + e;
        w1f[i] = f2bf(w1[k * FF + j]);          // w1 is [C][FF] = [k][j]
    } else if (i < 2 * C_ * FF) {
        int i2 = i - C_ * FF;
        int tile = i2 >> 9, l = (i2 >> 3) & 63, e = i2 & 7;
        int c_tile = tile >> 4, ks = tile & 15;
        int c = c_tile * 16 + (l & 15);
        int j = ks * 32 + (l >> 4) * 8 + e;
        w2f[i2] = f2bf(w2[j * C_ + c]);         // w2 is [FF][C] = [j][c]
    } else {
        int i3 = i - 2 * C_ * FF;
        int tile = i3 >> 9, l = (i3 >> 3) & 63, e = i3 & 7;
        int c_tile = tile >> 2, ks = tile & 3;
        int c = c_tile * 16 + (l & 15);
        int k = ks * 32 + (l >> 4) * 8 + e;
        wof[i3] = f2bf(Wo[k * C_ + c]);         // Wo is [C][C] = [k][c]
    }
}

// ---------------- kernel 1: QKV projection via MFMA (frag-linear weights)
__global__ __launch_bounds__(256) void k_qkv_mfma(
    const short* __restrict__ xbf, const short* __restrict__ wqkvf,
    float* __restrict__ Q, float* __restrict__ K, float* __restrict__ V) {
    __shared__ __align__(16) short xs[BM * C_];
    int tid = threadIdx.x;
    int r0 = blockIdx.x * BM;
    {
        int row = tid >> 3;                 // 0..31
        int cb = (tid & 7) * 16;
        const short* src = xbf + (size_t)(r0 + row) * C_ + cb;
        short8 v0 = *(const short8*)(src);
        short8 v1 = *(const short8*)(src + 8);
        *(short8*)&xs[(row * C_ + cb) ^ ((row & 7) << 3)] = v0;
        *(short8*)&xs[(row * C_ + cb + 8) ^ ((row & 7) << 3)] = v1;
    }
    __syncthreads();
    int w = tid >> 6, l = tid & 63;
    int lr = l & 15, lk = l >> 4;
    int rt = w & 1;
    int rrow = rt * 16 + lr;
    short8 bx[4];
#pragma unroll
    for (int ks = 0; ks < 4; ks++)
        bx[ks] = *(const short8*)&xs[(rrow * C_ + ks * 32 + lk * 8) ^ ((rrow & 7) << 3)];
    int gr = r0 + rrow;
    int t = gr % T_;
    int n = (gr / T_) % N_;
    int b = gr / (N_ * T_);
    size_t base = ((size_t)b * H_ * N_ + n) * (T_ * D_) + t * D_;
    int cg = w >> 1;
#pragma unroll
    for (int jt = 0; jt < 12; jt++) {
        int ctile = cg * 12 + jt;               // c-tile index 0..23
        const short* ap = wqkvf + (size_t)ctile * 2048 + l * 8;
        f32x4 acc = {0.f, 0.f, 0.f, 0.f};
#pragma unroll
        for (int ks = 0; ks < 4; ks++) {
            short8 af = *(const short8*)(ap + ks * 512);
            acc = __builtin_amdgcn_mfma_f32_16x16x32_bf16(af, bx[ks], acc, 0, 0, 0);
        }
        int c0 = ctile * 16 + lk * 4;
        int m = c0 >> 7;
        int c = c0 & (C_ - 1);
        int h = c >> 4, d = c & 15;
        float* dst = (m == 0) ? Q : (m == 1) ? K : V;
        *(float4*)&dst[base + (size_t)h * (N_ * T_ * D_) + d] = *(float4*)&acc;
    }
}

// helper: dot of two 16-float LDS rows (16B-aligned)
__device__ inline float dot16(const float* a, const float* b) {
    float4 a0 = *(const float4*)(a), a1 = *(const float4*)(a + 4);
    float4 a2 = *(const float4*)(a + 8), a3 = *(const float4*)(a + 12);
    float4 b0 = *(const float4*)(b), b1 = *(const float4*)(b + 4);
    float4 b2 = *(const float4*)(b + 8), b3 = *(const float4*)(b + 12);
    float s = a0.x * b0.x + a0.y * b0.y + a0.z * b0.z + a0.w * b0.w;
    s += a1.x * b1.x + a1.y * b1.y + a1.z * b1.z + a1.w * b1.w;
    s += a2.x * b2.x + a2.y * b2.y + a2.z * b2.z + a2.w * b2.w;
    s += a3.x * b3.x + a3.y * b3.y + a3.z * b3.z + a3.w * b3.w;
    return s;
}

// ---------------- kernel 2: attention core, one block per (b,h,n)
__global__ __launch_bounds__(128) void k_attn(
    const float* __restrict__ Q, const float* __restrict__ K, const float* __restrict__ V,
    const int* __restrict__ idxs, float* __restrict__ ctx) {
    __shared__ __align__(16) float Qs[T_][D_], Ks[T_][D_], Vs[T_][D_];
    __shared__ float qk[T_][S_ + 1];
    __shared__ float sc[T_][T_ + 1];
    __shared__ float Mv[T_];
    __shared__ int keep[T_];
    __shared__ float meanV[D_];
    __shared__ int sidx[T_ * S_];
    int e = blockIdx.x;
    int tid = threadIdx.x;
    const float* qb = Q + (size_t)e * T_ * D_;
    const float* kb = K + (size_t)e * T_ * D_;
    const float* vb = V + (size_t)e * T_ * D_;
    for (int i = tid; i < T_ * D_; i += 128) {
        ((float*)Qs)[i] = qb[i];
        ((float*)Ks)[i] = kb[i];
        ((float*)Vs)[i] = vb[i];
    }
    for (int i = tid; i < T_ * S_; i += 128) sidx[i] = idxs[i];
    __syncthreads();
    for (int i = tid; i < T_ * S_; i += 128) {
        int t = i / S_, s = i - t * S_;
        qk[t][s] = dot16(Qs[t], Ks[sidx[i]]);
    }
    __syncthreads();
    if (tid < T_) {
        float mx = -1e30f, sm = 0.f;
        for (int s = 0; s < S_; s++) { float v = qk[tid][s]; mx = fmaxf(mx, v); sm += v; }
        Mv[tid] = mx - sm * (1.0f / S_);
    } else if (tid >= 64 && tid < 64 + D_) {
        int d = tid - 64;
        float s = 0.f;
        for (int t = 0; t < T_; t++) s += Vs[t][d];
        meanV[d] = s * (1.0f / T_);
    }
    __syncthreads();
    if (tid < T_) {
        float mt = Mv[tid];
        int cnt = 0;
        for (int t2 = 0; t2 < T_; t2++) {
            float m2 = Mv[t2];
            cnt += (m2 > mt) || (m2 == mt && t2 < tid);
        }
        keep[tid] = (cnt < U_) ? 1 : 0;
    }
    for (int i = tid; i < T_ * T_; i += 128) {
        int t = i / T_, t2 = i - t * T_;
        sc[t][t2] = 0.25f * dot16(Qs[t], Ks[t2]);   // 1/sqrt(16)
    }
    __syncthreads();
    if (tid < T_) {
        float mx = -1e30f;
        for (int t2 = 0; t2 < T_; t2++) mx = fmaxf(mx, sc[tid][t2]);
        float sum = 0.f;
        for (int t2 = 0; t2 < T_; t2++) { float ev = expf(sc[tid][t2] - mx); sc[tid][t2] = ev; sum += ev; }
        float inv = 1.0f / sum;
        for (int t2 = 0; t2 < T_; t2++) sc[tid][t2] *= inv;
    }
    __syncthreads();
    int b = e / (H_ * N_);
    int h = (e / N_) % H_;
    int n = e % N_;
    for (int i = tid; i < T_ * D_; i += 128) {
        int t = i >> 4, d = i & 15;
        float o;
        if (keep[t]) {
            float s = 0.f;
            for (int t2 = 0; t2 < T_; t2++) s += sc[t][t2] * Vs[t2][d];
            o = s;
        } else {
            o = meanV[d];
        }
        ctx[((b * N_ + n) * T_ + t) * C_ + h * D_ + d] = o;
    }
}

// ---------------- kernel 3: att_out = ctx@Wo + bo (MFMA); y = att_out + x; x1 = LN1(y)
__global__ __launch_bounds__(256) void k_out_ln_mfma(
    const float* __restrict__ ctx, const short* __restrict__ wof, const float* __restrict__ bo,
    const float* __restrict__ query, const float* __restrict__ tepe,
    const float* __restrict__ g1, const float* __restrict__ b1,
    float* __restrict__ x1) {
    __shared__ __align__(16) short cbf[BM * C_];
    __shared__ __align__(16) float xf[BM][132];
    int tid = threadIdx.x;
    int r0 = blockIdx.x * BM;
    {
        int row = tid >> 3;
        int cb = (tid & 7) * 16;
        int gr = r0 + row;
        int t = gr % T_;
        int b = gr / (N_ * T_);
        const float* src = ctx + (size_t)gr * C_ + cb;
        const float* qsrc = query + (size_t)gr * C_ + cb;
        const float* tsrc = tepe + (size_t)(b * T_ + t) * C_ + cb;
#pragma unroll
        for (int i = 0; i < 4; i++) {
            float4 v = *(const float4*)(src + 4 * i);
            short4_ sv;
            sv.x = f2bf(v.x); sv.y = f2bf(v.y); sv.z = f2bf(v.z); sv.w = f2bf(v.w);
            *(short4_*)&cbf[(row * C_ + cb + 4 * i) ^ ((row & 7) << 3)] = sv;
            float4 q4 = *(const float4*)(qsrc + 4 * i);
            float4 t4 = *(const float4*)(tsrc + 4 * i);
            float4 xr;
            xr.x = q4.x + t4.x; xr.y = q4.y + t4.y;
            xr.z = q4.z + t4.z; xr.w = q4.w + t4.w;
            *(float4*)&xf[row][cb + 4 * i] = xr;
        }
    }
    __syncthreads();
    int w = tid >> 6, l = tid & 63;
    int lr = l & 15, lk = l >> 4;
    int rt = w & 1;
    int rrow = rt * 16 + lr;
    short8 bc[4];
#pragma unroll
    for (int ks = 0; ks < 4; ks++)
        bc[ks] = *(const short8*)&cbf[(rrow * C_ + ks * 32 + lk * 8) ^ ((rrow & 7) << 3)];
    int cg = w >> 1;
#pragma unroll
    for (int ct = 0; ct < 4; ct++) {
        int c_tile = cg * 4 + ct;               // 0..7
        const short* ap = wof + (size_t)c_tile * 2048 + l * 8;
        f32x4 acc = {0.f, 0.f, 0.f, 0.f};
#pragma unroll
        for (int ks = 0; ks < 4; ks++) {
            short8 af = *(const short8*)(ap + ks * 512);
            acc = __builtin_amdgcn_mfma_f32_16x16x32_bf16(af, bc[ks], acc, 0, 0, 0);
        }
        int cc = c_tile * 16 + lk * 4;
        float4 bias = *(const float4*)(bo + cc);
        float4 res = *(const float4*)&xf[rrow][cc];
        float4 o;
        o.x = acc.x + bias.x + res.x;
        o.y = acc.y + bias.y + res.y;
        o.z = acc.z + bias.z + res.z;
        o.w = acc.w + bias.w + res.w;
        *(float4*)&xf[rrow][cc] = o;
    }
    __syncthreads();
    {
        int r = tid >> 3;
        int q = tid & 7;
        int cb = q * 16;
        float vals[16];
        float s = 0.f;
#pragma unroll
        for (int i = 0; i < 16; i++) { vals[i] = xf[r][cb + i]; s += vals[i]; }
        s += __shfl_xor(s, 1, 8);
        s += __shfl_xor(s, 2, 8);
        s += __shfl_xor(s, 4, 8);
        float mean = s * (1.f / C_);
        float vv = 0.f;
#pragma unroll
        for (int i = 0; i < 16; i++) { float d = vals[i] - mean; vv += d * d; }
        vv += __shfl_xor(vv, 1, 8);
        vv += __shfl_xor(vv, 2, 8);
        vv += __shfl_xor(vv, 4, 8);
        float rstd = rsqrtf(vv * (1.f / C_) + 1e-5f);
        float* op = x1 + (size_t)(r0 + r) * C_ + cb;
#pragma unroll
        for (int i4 = 0; i4 < 4; i4++) {
            float4 gv = *(const float4*)(g1 + cb + 4 * i4);
            float4 bv = *(const float4*)(b1 + cb + 4 * i4);
            float4 ov;
            ov.x = (vals[4 * i4 + 0] - mean) * rstd * gv.x + bv.x;
            ov.y = (vals[4 * i4 + 1] - mean) * rstd * gv.y + bv.y;
            ov.z = (vals[4 * i4 + 2] - mean) * rstd * gv.z + bv.z;
            ov.w = (vals[4 * i4 + 3] - mean) * rstd * gv.w + bv.w;
            *(float4*)(op + 4 * i4) = ov;
        }
    }
}

// ---------------- kernel 4: FF via bf16 MFMA + residual + LN2 -> out
// Frag-linear weights: every weight load is base + lane*16B (coalesced 1KB/wave).
__global__ __launch_bounds__(512, 4) void k_ff_mfma(
    const float* __restrict__ x1, const short* __restrict__ w1f, const float* __restrict__ b1f,
    const short* __restrict__ w2f, const float* __restrict__ b2f,
    const float* __restrict__ g2, const float* __restrict__ b2ln,
    float* __restrict__ out) {
    __shared__ __align__(16) short xbf[BMF * C_];    // 16 KB, bf16 x, swizzled
    __shared__ __align__(16) short hbf[BMF * FF];    // 64 KB, bf16 hidden, swizzled
    float (*yf)[132] = (float(*)[132])hbf;           // f32 y aliases hbf (33 KB)
    int tid = threadIdx.x;
    int r0 = blockIdx.x * BMF;
    // ---- stage x tile (f32 -> bf16, swizzled)
    {
        int row = tid >> 3;                 // 0..63
        int cb = (tid & 7) * 16;
        const float* src = x1 + (size_t)(r0 + row) * C_ + cb;
#pragma unroll
        for (int i = 0; i < 4; i++) {
            float4 v = *(const float4*)(src + 4 * i);
            short4_ sv;
            sv.x = f2bf(v.x); sv.y = f2bf(v.y); sv.z = f2bf(v.z); sv.w = f2bf(v.w);
            *(short4_*)&xbf[(row * C_ + cb + 4 * i) ^ ((row & 7) << 3)] = sv;
        }
    }
    __syncthreads();
    int w = tid >> 6, l = tid & 63;
    int lr = l & 15, lk = l >> 4;           // lk in 0..3
    int rt = w & 3;                         // 4 row-tiles of 16
    int rrow = rt * 16 + lr;                // 0..63
    // ---- GEMM1: hidden^T tiles; wave covers j in [jh*256, jh*256+256)
    {
        short8 bx[4];
#pragma unroll
        for (int ks = 0; ks < 4; ks++)
            bx[ks] = *(const short8*)&xbf[(rrow * C_ + ks * 32 + lk * 8) ^ ((rrow & 7) << 3)];
        int jh = w >> 2;                    // j-half
        // tiles for this half: jtile = jh*16 + jt, each tile 4 ks x 512 shorts
        const short* wbase = w1f + (size_t)jh * 16 * 2048 + l * 8;
        short8 acur[4], anxt[4];
#pragma unroll
        for (int ks = 0; ks < 4; ks++) acur[ks] = *(const short8*)(wbase + ks * 512);
#pragma unroll
        for (int jt = 0; jt < 16; jt++) {
            if (jt < 15) {
                const short* np = wbase + (size_t)(jt + 1) * 2048;
#pragma unroll
                for (int ks = 0; ks < 4; ks++) anxt[ks] = *(const short8*)(np + ks * 512);
            }
            f32x4 acc = {0.f, 0.f, 0.f, 0.f};
#pragma unroll
            for (int ks = 0; ks < 4; ks++)
                acc = __builtin_amdgcn_mfma_f32_16x16x32_bf16(acur[ks], bx[ks], acc, 0, 0, 0);
            int j0 = (jh * 16 + jt) * 16 + lk * 4;
            float4 bias = *(const float4*)(b1f + j0);
            short4_ hv;
            hv.x = f2bf(fmaxf(acc.x + bias.x, 0.f));
            hv.y = f2bf(fmaxf(acc.y + bias.y, 0.f));
            hv.z = f2bf(fmaxf(acc.z + bias.z, 0.f));
            hv.w = f2bf(fmaxf(acc.w + bias.w, 0.f));
            *(short4_*)&hbf[(rrow * FF + j0) ^ ((rrow & 7) << 3)] = hv;
#pragma unroll
            for (int ks = 0; ks < 4; ks++) acur[ks] = anxt[ks];
        }
    }
    __syncthreads();
    // ---- GEMM2: out^T tiles; wave covers c in [cg*64, cg*64+64), rows rt*16..+16
    f32x4 acc2[4];
    int cg = w >> 2;
    int c0base = cg * 64;
    {
#pragma unroll
        for (int ct = 0; ct < 4; ct++) acc2[ct] = (f32x4){0.f, 0.f, 0.f, 0.f};
        short8 aA[4], aB[4], hA, hB;
        // w2f tile index: (cg*4 + ct)*16 + ks, tile stride 512 shorts
#pragma unroll
        for (int ct = 0; ct < 4; ct++)
            aA[ct] = *(const short8*)(w2f + ((size_t)(cg * 4 + ct) * 16) * 512 + l * 8);
        hA = *(const short8*)&hbf[(rrow * FF + lk * 8) ^ ((rrow & 7) << 3)];
#pragma unroll
        for (int ks = 0; ks < 16; ks++) {
            if (ks < 15) {
                int k1 = (ks + 1) * 32 + lk * 8;
#pragma unroll
                for (int ct = 0; ct < 4; ct++)
                    aB[ct] = *(const short8*)(w2f + ((size_t)(cg * 4 + ct) * 16 + ks + 1) * 512 + l * 8);
                hB = *(const short8*)&hbf[(rrow * FF + k1) ^ ((rrow & 7) << 3)];
            }
#pragma unroll
            for (int ct = 0; ct < 4; ct++)
                acc2[ct] = __builtin_amdgcn_mfma_f32_16x16x32_bf16(aA[ct], hA, acc2[ct], 0, 0, 0);
#pragma unroll
            for (int ct = 0; ct < 4; ct++) aA[ct] = aB[ct];
            hA = hB;
        }
    }
    // residual + bias loads overlap the barrier wait
    float4 res[4], bias2[4];
#pragma unroll
    for (int ct = 0; ct < 4; ct++) {
        int cc = c0base + ct * 16 + lk * 4;
        res[ct] = *(const float4*)(x1 + (size_t)(r0 + rrow) * C_ + cc);
        bias2[ct] = *(const float4*)(b2f + cc);
    }
    __syncthreads();    // all hbf reads done -> safe to overwrite with y
#pragma unroll
    for (int ct = 0; ct < 4; ct++) {
        int cc = c0base + ct * 16 + lk * 4;
        float4 o;
        o.x = acc2[ct].x + bias2[ct].x + res[ct].x;
        o.y = acc2[ct].y + bias2[ct].y + res[ct].y;
        o.z = acc2[ct].z + bias2[ct].z + res[ct].z;
        o.w = acc2[ct].w + bias2[ct].w + res[ct].w;
        *(float4*)&yf[rrow][cc] = o;
    }
    __syncthreads();
    // ---- LN2 + store
    {
        int r = tid >> 3;                   // 0..63
        int q = tid & 7;
        int cb = q * 16;
        float vals[16];
        float s = 0.f;
#pragma unroll
        for (int i = 0; i < 16; i++) { vals[i] = yf[r][cb + i]; s += vals[i]; }
        s += __shfl_xor(s, 1, 8);
        s += __shfl_xor(s, 2, 8);
        s += __shfl_xor(s, 4, 8);
        float mean = s * (1.f / C_);
        float vv = 0.f;
#pragma unroll
        for (int i = 0; i < 16; i++) { float d = vals[i] - mean; vv += d * d; }
        vv += __shfl_xor(vv, 1, 8);
        vv += __shfl_xor(vv, 2, 8);
        vv += __shfl_xor(vv, 4, 8);
        float rstd = rsqrtf(vv * (1.f / C_) + 1e-5f);
        float* op = out + (size_t)(r0 + r) * C_ + cb;
#pragma unroll
        for (int i4 = 0; i4 < 4; i4++) {
            float4 gv = *(const float4*)(g2 + cb + 4 * i4);
            float4 bv = *(const float4*)(b2ln + cb + 4 * i4);
            float4 ov;
            ov.x = (vals[4 * i4 + 0] - mean) * rstd * gv.x + bv.x;
            ov.y = (vals[4 * i4 + 1] - mean) * rstd * gv.y + bv.y;
            ov.z = (vals[4 * i4 + 2] - mean) * rstd * gv.z + bv.z;
            ov.w = (vals[4 * i4 + 3] - mean) * rstd * gv.w + bv.w;
            *(float4*)(op + 4 * i4) = ov;
        }
    }
}

extern "C" void kernel_launch(void* const* d_in, const int* in_sizes, int n_in,
                              void* d_out, int out_size, void* d_ws, size_t ws_size,
                              hipStream_t stream) {
    const float* query = (const float*)d_in[2];
    const int* time_enc = (const int*)d_in[4];
    const int* index_sample = (const int*)d_in[5];
    const float* e_min = (const float*)d_in[6];
    const float* e_hr  = (const float*)d_in[7];
    const float* e_wd  = (const float*)d_in[8];
    const float* e_mo  = (const float*)d_in[9];
    const float* e_yr  = (const float*)d_in[10];
    const float* Wq = (const float*)d_in[11];
    const float* Wk = (const float*)d_in[12];
    const float* Wv = (const float*)d_in[13];
    const float* Wo = (const float*)d_in[14];
    const float* bo = (const float*)d_in[15];
    const float* ffw1 = (const float*)d_in[16];
    const float* ffb1 = (const float*)d_in[17];
    const float* ffw2 = (const float*)d_in[18];
    const float* ffb2 = (const float*)d_in[19];
    const float* ln1g = (const float*)d_in[20];
    const float* ln1b = (const float*)d_in[21];
    const float* ln2g = (const float*)d_in[22];
    const float* ln2b = (const float*)d_in[23];

    float* ws = (float*)d_ws;
    float* tepe = ws;                 // TEPE_N floats
    float* Qb = ws + TEPE_N;          // NX floats; x1 aliases after attn
    float* Kb = Qb + NX;              // NX floats; w1f/w2f/wof alias after attn
    float* Vb = Kb + NX;              // NX floats
    float* ctxb = Vb + NX;            // NX floats; xbf + wqkvf alias before attn
    float* x1 = Qb;

    short* xbf = (short*)ctxb;                  // NX shorts (first half of ctx region)
    short* wqkvf = (short*)ctxb + NX;           // 49152 shorts (second half; dead before attn)
    short* w1f = (short*)Kb;                    // 65536 shorts (K dead after attn)
    short* w2f = w1f + C_ * FF;                 // 65536 shorts
    short* wof = w2f + C_ * FF;                 // 16384 shorts

    k_tepe<<<dim3(TEPE_N / 256), dim3(256), 0, stream>>>(
        time_enc, e_min, e_hr, e_wd, e_mo, e_yr, tepe);
    k_xprep<<<dim3(NX / 4 / 256), dim3(256), 0, stream>>>(query, tepe, xbf);
    k_wcvt_qkv<<<dim3(384 * C_ / 256), dim3(256), 0, stream>>>(Wq, Wk, Wv, wqkvf);
    k_qkv_mfma<<<dim3(NBLK_MM), dim3(256), 0, stream>>>(xbf, wqkvf, Qb, Kb, Vb);
    k_attn<<<dim3(B_ * H_ * N_), dim3(128), 0, stream>>>(
        Qb, Kb, Vb, index_sample, ctxb);
    k_wcvt2<<<dim3((2 * C_ * FF + C_ * C_) / 256), dim3(256), 0, stream>>>(
        ffw1, ffw2, Wo, w1f, w2f, wof);
    k_out_ln_mfma<<<dim3(NBLK_MM), dim3(256), 0, stream>>>(
        ctxb, wof, bo, query, tepe, ln1g, ln1b, x1);
    k_ff_mfma<<<dim3(NBLK_FF), dim3(512), 0, stream>>>(
        x1, w1f, ffb1, w2f, ffb2, ln2g, ln2b, (float*)d_out);
}

// Round 6
// 279.084 us; speedup vs baseline: 2.1676x; 1.3523x over previous
//
#include <hip/hip_runtime.h>
#include <hip/hip_bf16.h>
#include <cmath>

namespace {
constexpr int B_ = 16, N_ = 307, T_ = 24, C_ = 128, H_ = 8, D_ = 16, S_ = 20, U_ = 20;
constexpr int NROW = B_ * N_ * T_;          // 117888
constexpr int NX = NROW * C_;               // 15089664
constexpr int TEPE_N = B_ * T_ * C_;        // 49152
constexpr int FF = 4 * C_;                  // 512
constexpr int BM = 32;                      // rows per MFMA block (qkv/out_ln)
constexpr int NBLK_MM = NROW / BM;          // 3684
constexpr int BMF = 64;                     // rows per FF block
constexpr int NBLK_FF = NROW / BMF;         // 1842
}

typedef __attribute__((ext_vector_type(8))) short short8;
typedef __attribute__((ext_vector_type(4))) short short4_;
typedef __attribute__((ext_vector_type(4))) float f32x4;

__device__ inline short f2bf(float v) {
    union { float f; unsigned u; } a; a.f = v;
    unsigned r = a.u + 0x7fff + ((a.u >> 16) & 1);   // round-to-nearest-even
    return (short)(r >> 16);
}

// ---------------- kernel 0: tepe[b,t,c] = pos_emb(t,c) + sum of 5 embedding lookups
__global__ void k_tepe(const int* __restrict__ te,
                       const float* __restrict__ e_min, const float* __restrict__ e_hr,
                       const float* __restrict__ e_wd, const float* __restrict__ e_mo,
                       const float* __restrict__ e_yr, float* __restrict__ tepe) {
    int i = blockIdx.x * blockDim.x + threadIdx.x;
    if (i >= TEPE_N) return;
    int c = i & (C_ - 1);
    int bt = i >> 7;              // b*T + t
    int t = bt % T_;
    const int* enc = te + bt * 5;
    float v = e_min[enc[0] * C_ + c] + e_hr[enc[1] * C_ + c] + e_wd[enc[2] * C_ + c]
            + e_mo[enc[3] * C_ + c] + e_yr[enc[4] * C_ + c];
    float ang = (float)t * expf(-(float)(c & ~1) * (9.210340371976184f / 128.0f));
    v += (c & 1) ? cosf(ang) : sinf(ang);
    tepe[i] = v;
}

// ---------------- kernel 0b: xbf = bf16(query + tepe), one float4 per thread
__global__ void k_xprep(const float* __restrict__ query, const float* __restrict__ tepe,
                        short* __restrict__ xbf) {
    int i = blockIdx.x * 256 + threadIdx.x;     // i indexes float4s; NX/4 total
    int c4 = i & 31;
    int gr = i >> 5;
    int t = gr % T_;
    int b = gr / (N_ * T_);
    float4 q = *(const float4*)(query + 4 * (size_t)i);
    float4 p = *(const float4*)(tepe + (size_t)(b * T_ + t) * C_ + c4 * 4);
    short4_ s;
    s.x = f2bf(q.x + p.x); s.y = f2bf(q.y + p.y);
    s.z = f2bf(q.z + p.z); s.w = f2bf(q.w + p.w);
    *(short4_*)&xbf[4 * (size_t)i] = s;
}

// ---------------- weight converts: FRAGMENT-LINEAR layout (see round 4 notes).
__global__ void k_wcvt_qkv(const float* __restrict__ Wq, const float* __restrict__ Wk,
                           const float* __restrict__ Wv, short* __restrict__ wqkvf) {
    int i = blockIdx.x * 256 + threadIdx.x;     // 49152
    int tile = i >> 9, l = (i >> 3) & 63, e = i & 7;
    int c_tile = tile >> 2, ks = tile & 3;
    int c_all = c_tile * 16 + (l & 15);
    int k = ks * 32 + (l >> 4) * 8 + e;
    int m = c_all >> 7, c = c_all & (C_ - 1);
    const float* W = (m == 0) ? Wq : (m == 1) ? Wk : Wv;
    wqkvf[i] = f2bf(W[k * C_ + c]);
}

__global__ void k_wcvt2(const float* __restrict__ w1, const float* __restrict__ w2,
                        const float* __restrict__ Wo,
                        short* __restrict__ w1f, short* __restrict__ w2f,
                        short* __restrict__ wof) {
    int i = blockIdx.x * 256 + threadIdx.x;     // 147456
    if (i < C_ * FF) {
        int tile = i >> 9, l = (i >> 3) & 63, e = i & 7;
        int jtile = tile >> 2, ks = tile & 3;
        int j = jtile * 16 + (l & 15);
        int k = ks * 32 + (l >> 4) * 8 + e;
        w1f[i] = f2bf(w1[k * FF + j]);          // w1 is [C][FF] = [k][j]
    } else if (i < 2 * C_ * FF) {
        int i2 = i - C_ * FF;
        int tile = i2 >> 9, l = (i2 >> 3) & 63, e = i2 & 7;
        int c_tile = tile >> 4, ks = tile & 15;
        int c = c_tile * 16 + (l & 15);
        int j = ks * 32 + (l >> 4) * 8 + e;
        w2f[i2] = f2bf(w2[j * C_ + c]);         // w2 is [FF][C] = [j][c]
    } else {
        int i3 = i - 2 * C_ * FF;
        int tile = i3 >> 9, l = (i3 >> 3) & 63, e = i3 & 7;
        int c_tile = tile >> 2, ks = tile & 3;
        int c = c_tile * 16 + (l & 15);
        int k = ks * 32 + (l >> 4) * 8 + e;
        wof[i3] = f2bf(Wo[k * C_ + c]);         // Wo is [C][C] = [k][c]
    }
}

// ---------------- kernel 1: QKV projection via MFMA (frag-linear weights)
__global__ __launch_bounds__(256) void k_qkv_mfma(
    const short* __restrict__ xbf, const short* __restrict__ wqkvf,
    float* __restrict__ Q, float* __restrict__ K, float* __restrict__ V) {
    __shared__ __align__(16) short xs[BM * C_];
    int tid = threadIdx.x;
    int r0 = blockIdx.x * BM;
    {
        int row = tid >> 3;                 // 0..31
        int cb = (tid & 7) * 16;
        const short* src = xbf + (size_t)(r0 + row) * C_ + cb;
        short8 v0 = *(const short8*)(src);
        short8 v1 = *(const short8*)(src + 8);
        *(short8*)&xs[(row * C_ + cb) ^ ((row & 7) << 3)] = v0;
        *(short8*)&xs[(row * C_ + cb + 8) ^ ((row & 7) << 3)] = v1;
    }
    __syncthreads();
    int w = tid >> 6, l = tid & 63;
    int lr = l & 15, lk = l >> 4;
    int rt = w & 1;
    int rrow = rt * 16 + lr;
    short8 bx[4];
#pragma unroll
    for (int ks = 0; ks < 4; ks++)
        bx[ks] = *(const short8*)&xs[(rrow * C_ + ks * 32 + lk * 8) ^ ((rrow & 7) << 3)];
    int gr = r0 + rrow;
    int t = gr % T_;
    int n = (gr / T_) % N_;
    int b = gr / (N_ * T_);
    size_t base = ((size_t)b * H_ * N_ + n) * (T_ * D_) + t * D_;
    int cg = w >> 1;
#pragma unroll
    for (int jt = 0; jt < 12; jt++) {
        int ctile = cg * 12 + jt;               // c-tile index 0..23
        const short* ap = wqkvf + (size_t)ctile * 2048 + l * 8;
        f32x4 acc = {0.f, 0.f, 0.f, 0.f};
#pragma unroll
        for (int ks = 0; ks < 4; ks++) {
            short8 af = *(const short8*)(ap + ks * 512);
            acc = __builtin_amdgcn_mfma_f32_16x16x32_bf16(af, bx[ks], acc, 0, 0, 0);
        }
        int c0 = ctile * 16 + lk * 4;
        int m = c0 >> 7;
        int c = c0 & (C_ - 1);
        int h = c >> 4, d = c & 15;
        float* dst = (m == 0) ? Q : (m == 1) ? K : V;
        *(float4*)&dst[base + (size_t)h * (N_ * T_ * D_) + d] = *(float4*)&acc;
    }
}

// ---------------- kernel 2: attention core, one wave per (b,h,n)
// Selection path (QK_samp -> M -> top-k) in f32 on VALU; scores and PV on MFMA.
// f32 LDS rows stride 20 (8-way bank spread); bf16 rows stride 24/40 (16B aligned).
__global__ __launch_bounds__(64) void k_attn(
    const float* __restrict__ Q, const float* __restrict__ K, const float* __restrict__ V,
    const int* __restrict__ idxs, float* __restrict__ ctx) {
    __shared__ __align__(16) float Qsf[T_ * 20], Ksf[T_ * 20];
    __shared__ __align__(16) short Qbf[32 * 24], Kbf[32 * 24];   // rows 24-31 garbage (confined)
    __shared__ __align__(16) short Vt[16 * 40];                  // [d][t2], cols 24-31 zeroed
    __shared__ __align__(16) short Pbf[32 * 40];                 // attn weights, cols 24-31 zeroed
    __shared__ float Mv[T_];
    __shared__ int keepS[T_];
    __shared__ float meanVs[D_];
    int e = blockIdx.x;
    int tid = threadIdx.x;
    const float* qb = Q + (size_t)e * (T_ * D_);
    const float* kb = K + (size_t)e * (T_ * D_);
    const float* vb = V + (size_t)e * (T_ * D_);
    // ---- stage: Q,K -> f32 + bf16 LDS; V -> transposed bf16
    for (int i = tid; i < 96; i += 64) {
        int t = i >> 2, c4 = i & 3;
        float4 qv = *(const float4*)(qb + i * 4);
        float4 kv = *(const float4*)(kb + i * 4);
        float4 vv = *(const float4*)(vb + i * 4);
        *(float4*)&Qsf[t * 20 + c4 * 4] = qv;
        *(float4*)&Ksf[t * 20 + c4 * 4] = kv;
        short4_ qs, ks;
        qs.x = f2bf(qv.x); qs.y = f2bf(qv.y); qs.z = f2bf(qv.z); qs.w = f2bf(qv.w);
        ks.x = f2bf(kv.x); ks.y = f2bf(kv.y); ks.z = f2bf(kv.z); ks.w = f2bf(kv.w);
        *(short4_*)&Qbf[t * 24 + c4 * 4] = qs;
        *(short4_*)&Kbf[t * 24 + c4 * 4] = ks;
        Vt[(c4 * 4 + 0) * 40 + t] = f2bf(vv.x);
        Vt[(c4 * 4 + 1) * 40 + t] = f2bf(vv.y);
        Vt[(c4 * 4 + 2) * 40 + t] = f2bf(vv.z);
        Vt[(c4 * 4 + 3) * 40 + t] = f2bf(vv.w);
    }
    for (int i = tid; i < 128; i += 64) {       // zero Vt cols 24-31
        int d = i >> 3, c = 24 + (i & 7);
        Vt[d * 40 + c] = 0;
    }
    __syncthreads();
    // ---- QK_samp (f32) -> M, lanes 0-47; meanV on lanes 48-63
    if (tid < 48) {
        int t = tid >> 1, half = tid & 1;
        float qreg[16];
#pragma unroll
        for (int j = 0; j < 16; j++) qreg[j] = Qsf[t * 20 + j];
        float mx = -1e30f, sm = 0.f;
        const int* ip = idxs + t * S_ + half * 10;
        for (int s5 = 0; s5 < 10; s5++) {
            int kr = ip[s5];
            const float* kp = &Ksf[kr * 20];
            float d = 0.f;
#pragma unroll
            for (int j = 0; j < 16; j++) d += qreg[j] * kp[j];
            mx = fmaxf(mx, d); sm += d;
        }
        mx = fmaxf(mx, __shfl_xor(mx, 1));
        sm += __shfl_xor(sm, 1);
        if (half == 0) Mv[t] = mx - sm * (1.0f / S_);
    } else if (tid < 48 + D_) {
        int d = tid - 48;
        float s = 0.f;
        for (int t = 0; t < T_; t++) s += __bfloat162float(*(const __hip_bfloat16*)&Vt[d * 40 + t]);
        meanVs[d] = s * (1.0f / T_);
    }
    __syncthreads();
    // ---- keep mask (top-U as a set, tie-break lower index)
    if (tid < T_) {
        float mt = Mv[tid];
        int cnt = 0;
        for (int t2 = 0; t2 < T_; t2++) {
            float m2 = Mv[t2];
            cnt += (m2 > mt) || (m2 == mt && t2 < tid);
        }
        keepS[tid] = (cnt < U_) ? 1 : 0;
    }
    // ---- scores via MFMA: sc[t][t2], A = K rows (t2), B = Q rows (t)
    int lr = tid & 15, lk = tid >> 4;
    short8 zz = {};
    short8 kf0 = zz, kf1 = zz, qf0 = zz, qf1 = zz;
    if (lk < 2) {
        kf0 = *(const short8*)&Kbf[lr * 24 + lk * 8];
        kf1 = *(const short8*)&Kbf[(16 + lr) * 24 + lk * 8];
        qf0 = *(const short8*)&Qbf[lr * 24 + lk * 8];
        qf1 = *(const short8*)&Qbf[(16 + lr) * 24 + lk * 8];
    }
    f32x4 zf = {0.f, 0.f, 0.f, 0.f};
    f32x4 s00 = __builtin_amdgcn_mfma_f32_16x16x32_bf16(kf0, qf0, zf, 0, 0, 0);
    f32x4 s01 = __builtin_amdgcn_mfma_f32_16x16x32_bf16(kf1, qf0, zf, 0, 0, 0);
    f32x4 s10 = __builtin_amdgcn_mfma_f32_16x16x32_bf16(kf0, qf1, zf, 0, 0, 0);
    f32x4 s11 = __builtin_amdgcn_mfma_f32_16x16x32_bf16(kf1, qf1, zf, 0, 0, 0);
    // ---- softmax in registers (row = lr within row-tile; reduce over lk via shfl)
#pragma unroll
    for (int rt = 0; rt < 2; rt++) {
        f32x4 c0 = rt ? s10 : s00;
        f32x4 c1 = rt ? s11 : s01;
        float lm = fmaxf(fmaxf(c0[0], c0[1]), fmaxf(c0[2], c0[3]));
        if (lk < 2) lm = fmaxf(lm, fmaxf(fmaxf(c1[0], c1[1]), fmaxf(c1[2], c1[3])));
        lm = fmaxf(lm, __shfl_xor(lm, 16));
        lm = fmaxf(lm, __shfl_xor(lm, 32));
        float e0[4], e1[4];
        float ls = 0.f;
#pragma unroll
        for (int i = 0; i < 4; i++) { e0[i] = __expf(0.25f * (c0[i] - lm)); ls += e0[i]; }
#pragma unroll
        for (int i = 0; i < 4; i++) { e1[i] = (lk < 2) ? __expf(0.25f * (c1[i] - lm)) : 0.f; ls += e1[i]; }
        ls += __shfl_xor(ls, 16);
        ls += __shfl_xor(ls, 32);
        float inv = 1.0f / ls;
        short4_ w0, w1;
        w0.x = f2bf(e0[0] * inv); w0.y = f2bf(e0[1] * inv);
        w0.z = f2bf(e0[2] * inv); w0.w = f2bf(e0[3] * inv);
        w1.x = f2bf(e1[0] * inv); w1.y = f2bf(e1[1] * inv);
        w1.z = f2bf(e1[2] * inv); w1.w = f2bf(e1[3] * inv);
        int trow = rt * 16 + lr;
        *(short4_*)&Pbf[trow * 40 + lk * 4] = w0;
        *(short4_*)&Pbf[trow * 40 + 16 + lk * 4] = w1;    // lk>=2 writes zeros (cols 24-31)
    }
    __syncthreads();
    // ---- PV via MFMA: upd[t][d], A = Vt rows (d), B = attn rows (t), K = 32
    short8 vf = *(const short8*)&Vt[lr * 40 + lk * 8];
    short8 pf0 = *(const short8*)&Pbf[lr * 40 + lk * 8];
    short8 pf1 = *(const short8*)&Pbf[(16 + lr) * 40 + lk * 8];
    f32x4 u0 = __builtin_amdgcn_mfma_f32_16x16x32_bf16(vf, pf0, zf, 0, 0, 0);
    f32x4 u1 = __builtin_amdgcn_mfma_f32_16x16x32_bf16(vf, pf1, zf, 0, 0, 0);
    // ---- store: kept rows get upd, dropped rows get meanV
    int b = e / (H_ * N_);
    int h = (e / N_) % H_;
    int n = e % N_;
    float4 mv4 = *(const float4*)&meanVs[lk * 4];
#pragma unroll
    for (int rt = 0; rt < 2; rt++) {
        int t = rt * 16 + lr;
        if (t < T_) {
            f32x4 u = rt ? u1 : u0;
            float4 o;
            if (keepS[t]) { o.x = u[0]; o.y = u[1]; o.z = u[2]; o.w = u[3]; }
            else o = mv4;
            *(float4*)&ctx[((size_t)(b * N_ + n) * T_ + t) * C_ + h * D_ + lk * 4] = o;
        }
    }
}

// ---------------- kernel 3: att_out = ctx@Wo + bo (MFMA); y = att_out + x; x1 = LN1(y)
__global__ __launch_bounds__(256) void k_out_ln_mfma(
    const float* __restrict__ ctx, const short* __restrict__ wof, const float* __restrict__ bo,
    const float* __restrict__ query, const float* __restrict__ tepe,
    const float* __restrict__ g1, const float* __restrict__ b1,
    float* __restrict__ x1) {
    __shared__ __align__(16) short cbf[BM * C_];
    __shared__ __align__(16) float xf[BM][132];
    int tid = threadIdx.x;
    int r0 = blockIdx.x * BM;
    {
        int row = tid >> 3;
        int cb = (tid & 7) * 16;
        int gr = r0 + row;
        int t = gr % T_;
        int b = gr / (N_ * T_);
        const float* src = ctx + (size_t)gr * C_ + cb;
        const float* qsrc = query + (size_t)gr * C_ + cb;
        const float* tsrc = tepe + (size_t)(b * T_ + t) * C_ + cb;
#pragma unroll
        for (int i = 0; i < 4; i++) {
            float4 v = *(const float4*)(src + 4 * i);
            short4_ sv;
            sv.x = f2bf(v.x); sv.y = f2bf(v.y); sv.z = f2bf(v.z); sv.w = f2bf(v.w);
            *(short4_*)&cbf[(row * C_ + cb + 4 * i) ^ ((row & 7) << 3)] = sv;
            float4 q4 = *(const float4*)(qsrc + 4 * i);
            float4 t4 = *(const float4*)(tsrc + 4 * i);
            float4 xr;
            xr.x = q4.x + t4.x; xr.y = q4.y + t4.y;
            xr.z = q4.z + t4.z; xr.w = q4.w + t4.w;
            *(float4*)&xf[row][cb + 4 * i] = xr;
        }
    }
    __syncthreads();
    int w = tid >> 6, l = tid & 63;
    int lr = l & 15, lk = l >> 4;
    int rt = w & 1;
    int rrow = rt * 16 + lr;
    short8 bc[4];
#pragma unroll
    for (int ks = 0; ks < 4; ks++)
        bc[ks] = *(const short8*)&cbf[(rrow * C_ + ks * 32 + lk * 8) ^ ((rrow & 7) << 3)];
    int cg = w >> 1;
#pragma unroll
    for (int ct = 0; ct < 4; ct++) {
        int c_tile = cg * 4 + ct;               // 0..7
        const short* ap = wof + (size_t)c_tile * 2048 + l * 8;
        f32x4 acc = {0.f, 0.f, 0.f, 0.f};
#pragma unroll
        for (int ks = 0; ks < 4; ks++) {
            short8 af = *(const short8*)(ap + ks * 512);
            acc = __builtin_amdgcn_mfma_f32_16x16x32_bf16(af, bc[ks], acc, 0, 0, 0);
        }
        int cc = c_tile * 16 + lk * 4;
        float4 bias = *(const float4*)(bo + cc);
        float4 res = *(const float4*)&xf[rrow][cc];
        float4 o;
        o.x = acc[0] + bias.x + res.x;
        o.y = acc[1] + bias.y + res.y;
        o.z = acc[2] + bias.z + res.z;
        o.w = acc[3] + bias.w + res.w;
        *(float4*)&xf[rrow][cc] = o;
    }
    __syncthreads();
    {
        int r = tid >> 3;
        int q = tid & 7;
        int cb = q * 16;
        float vals[16];
        float s = 0.f;
#pragma unroll
        for (int i = 0; i < 16; i++) { vals[i] = xf[r][cb + i]; s += vals[i]; }
        s += __shfl_xor(s, 1, 8);
        s += __shfl_xor(s, 2, 8);
        s += __shfl_xor(s, 4, 8);
        float mean = s * (1.f / C_);
        float vv = 0.f;
#pragma unroll
        for (int i = 0; i < 16; i++) { float d = vals[i] - mean; vv += d * d; }
        vv += __shfl_xor(vv, 1, 8);
        vv += __shfl_xor(vv, 2, 8);
        vv += __shfl_xor(vv, 4, 8);
        float rstd = rsqrtf(vv * (1.f / C_) + 1e-5f);
        float* op = x1 + (size_t)(r0 + r) * C_ + cb;
#pragma unroll
        for (int i4 = 0; i4 < 4; i4++) {
            float4 gv = *(const float4*)(g1 + cb + 4 * i4);
            float4 bv = *(const float4*)(b1 + cb + 4 * i4);
            float4 ov;
            ov.x = (vals[4 * i4 + 0] - mean) * rstd * gv.x + bv.x;
            ov.y = (vals[4 * i4 + 1] - mean) * rstd * gv.y + bv.y;
            ov.z = (vals[4 * i4 + 2] - mean) * rstd * gv.z + bv.z;
            ov.w = (vals[4 * i4 + 3] - mean) * rstd * gv.w + bv.w;
            *(float4*)(op + 4 * i4) = ov;
        }
    }
}

// ---------------- kernel 4: FF via bf16 MFMA + residual + LN2 -> out
__global__ __launch_bounds__(512, 4) void k_ff_mfma(
    const float* __restrict__ x1, const short* __restrict__ w1f, const float* __restrict__ b1f,
    const short* __restrict__ w2f, const float* __restrict__ b2f,
    const float* __restrict__ g2, const float* __restrict__ b2ln,
    float* __restrict__ out) {
    __shared__ __align__(16) short xbf[BMF * C_];    // 16 KB, bf16 x, swizzled
    __shared__ __align__(16) short hbf[BMF * FF];    // 64 KB, bf16 hidden, swizzled
    float (*yf)[132] = (float(*)[132])hbf;           // f32 y aliases hbf (33 KB)
    int tid = threadIdx.x;
    int r0 = blockIdx.x * BMF;
    {
        int row = tid >> 3;                 // 0..63
        int cb = (tid & 7) * 16;
        const float* src = x1 + (size_t)(r0 + row) * C_ + cb;
#pragma unroll
        for (int i = 0; i < 4; i++) {
            float4 v = *(const float4*)(src + 4 * i);
            short4_ sv;
            sv.x = f2bf(v.x); sv.y = f2bf(v.y); sv.z = f2bf(v.z); sv.w = f2bf(v.w);
            *(short4_*)&xbf[(row * C_ + cb + 4 * i) ^ ((row & 7) << 3)] = sv;
        }
    }
    __syncthreads();
    int w = tid >> 6, l = tid & 63;
    int lr = l & 15, lk = l >> 4;
    int rt = w & 3;
    int rrow = rt * 16 + lr;
    {
        short8 bx[4];
#pragma unroll
        for (int ks = 0; ks < 4; ks++)
            bx[ks] = *(const short8*)&xbf[(rrow * C_ + ks * 32 + lk * 8) ^ ((rrow & 7) << 3)];
        int jh = w >> 2;
        const short* wbase = w1f + (size_t)jh * 16 * 2048 + l * 8;
        short8 acur[4], anxt[4];
#pragma unroll
        for (int ks = 0; ks < 4; ks++) acur[ks] = *(const short8*)(wbase + ks * 512);
#pragma unroll
        for (int jt = 0; jt < 16; jt++) {
            if (jt < 15) {
                const short* np = wbase + (size_t)(jt + 1) * 2048;
#pragma unroll
                for (int ks = 0; ks < 4; ks++) anxt[ks] = *(const short8*)(np + ks * 512);
            }
            f32x4 acc = {0.f, 0.f, 0.f, 0.f};
#pragma unroll
            for (int ks = 0; ks < 4; ks++)
                acc = __builtin_amdgcn_mfma_f32_16x16x32_bf16(acur[ks], bx[ks], acc, 0, 0, 0);
            int j0 = (jh * 16 + jt) * 16 + lk * 4;
            float4 bias = *(const float4*)(b1f + j0);
            short4_ hv;
            hv.x = f2bf(fmaxf(acc[0] + bias.x, 0.f));
            hv.y = f2bf(fmaxf(acc[1] + bias.y, 0.f));
            hv.z = f2bf(fmaxf(acc[2] + bias.z, 0.f));
            hv.w = f2bf(fmaxf(acc[3] + bias.w, 0.f));
            *(short4_*)&hbf[(rrow * FF + j0) ^ ((rrow & 7) << 3)] = hv;
#pragma unroll
            for (int ks = 0; ks < 4; ks++) acur[ks] = anxt[ks];
        }
    }
    __syncthreads();
    f32x4 acc2[4];
    int cg = w >> 2;
    int c0base = cg * 64;
    {
#pragma unroll
        for (int ct = 0; ct < 4; ct++) acc2[ct] = (f32x4){0.f, 0.f, 0.f, 0.f};
        short8 aA[4], aB[4], hA, hB;
#pragma unroll
        for (int ct = 0; ct < 4; ct++)
            aA[ct] = *(const short8*)(w2f + ((size_t)(cg * 4 + ct) * 16) * 512 + l * 8);
        hA = *(const short8*)&hbf[(rrow * FF + lk * 8) ^ ((rrow & 7) << 3)];
#pragma unroll
        for (int ks = 0; ks < 16; ks++) {
            if (ks < 15) {
                int k1 = (ks + 1) * 32 + lk * 8;
#pragma unroll
                for (int ct = 0; ct < 4; ct++)
                    aB[ct] = *(const short8*)(w2f + ((size_t)(cg * 4 + ct) * 16 + ks + 1) * 512 + l * 8);
                hB = *(const short8*)&hbf[(rrow * FF + k1) ^ ((rrow & 7) << 3)];
            }
#pragma unroll
            for (int ct = 0; ct < 4; ct++)
                acc2[ct] = __builtin_amdgcn_mfma_f32_16x16x32_bf16(aA[ct], hA, acc2[ct], 0, 0, 0);
#pragma unroll
            for (int ct = 0; ct < 4; ct++) aA[ct] = aB[ct];
            hA = hB;
        }
    }
    float4 res[4], bias2[4];
#pragma unroll
    for (int ct = 0; ct < 4; ct++) {
        int cc = c0base + ct * 16 + lk * 4;
        res[ct] = *(const float4*)(x1 + (size_t)(r0 + rrow) * C_ + cc);
        bias2[ct] = *(const float4*)(b2f + cc);
    }
    __syncthreads();
#pragma unroll
    for (int ct = 0; ct < 4; ct++) {
        int cc = c0base + ct * 16 + lk * 4;
        float4 o;
        o.x = acc2[ct][0] + bias2[ct].x + res[ct].x;
        o.y = acc2[ct][1] + bias2[ct].y + res[ct].y;
        o.z = acc2[ct][2] + bias2[ct].z + res[ct].z;
        o.w = acc2[ct][3] + bias2[ct].w + res[ct].w;
        *(float4*)&yf[rrow][cc] = o;
    }
    __syncthreads();
    {
        int r = tid >> 3;
        int q = tid & 7;
        int cb = q * 16;
        float vals[16];
        float s = 0.f;
#pragma unroll
        for (int i = 0; i < 16; i++) { vals[i] = yf[r][cb + i]; s += vals[i]; }
        s += __shfl_xor(s, 1, 8);
        s += __shfl_xor(s, 2, 8);
        s += __shfl_xor(s, 4, 8);
        float mean = s * (1.f / C_);
        float vv = 0.f;
#pragma unroll
        for (int i = 0; i < 16; i++) { float d = vals[i] - mean; vv += d * d; }
        vv += __shfl_xor(vv, 1, 8);
        vv += __shfl_xor(vv, 2, 8);
        vv += __shfl_xor(vv, 4, 8);
        float rstd = rsqrtf(vv * (1.f / C_) + 1e-5f);
        float* op = out + (size_t)(r0 + r) * C_ + cb;
#pragma unroll
        for (int i4 = 0; i4 < 4; i4++) {
            float4 gv = *(const float4*)(g2 + cb + 4 * i4);
            float4 bv = *(const float4*)(b2ln + cb + 4 * i4);
            float4 ov;
            ov.x = (vals[4 * i4 + 0] - mean) * rstd * gv.x + bv.x;
            ov.y = (vals[4 * i4 + 1] - mean) * rstd * gv.y + bv.y;
            ov.z = (vals[4 * i4 + 2] - mean) * rstd * gv.z + bv.z;
            ov.w = (vals[4 * i4 + 3] - mean) * rstd * gv.w + bv.w;
            *(float4*)(op + 4 * i4) = ov;
        }
    }
}

extern "C" void kernel_launch(void* const* d_in, const int* in_sizes, int n_in,
                              void* d_out, int out_size, void* d_ws, size_t ws_size,
                              hipStream_t stream) {
    const float* query = (const float*)d_in[2];
    const int* time_enc = (const int*)d_in[4];
    const int* index_sample = (const int*)d_in[5];
    const float* e_min = (const float*)d_in[6];
    const float* e_hr  = (const float*)d_in[7];
    const float* e_wd  = (const float*)d_in[8];
    const float* e_mo  = (const float*)d_in[9];
    const float* e_yr  = (const float*)d_in[10];
    const float* Wq = (const float*)d_in[11];
    const float* Wk = (const float*)d_in[12];
    const float* Wv = (const float*)d_in[13];
    const float* Wo = (const float*)d_in[14];
    const float* bo = (const float*)d_in[15];
    const float* ffw1 = (const float*)d_in[16];
    const float* ffb1 = (const float*)d_in[17];
    const float* ffw2 = (const float*)d_in[18];
    const float* ffb2 = (const float*)d_in[19];
    const float* ln1g = (const float*)d_in[20];
    const float* ln1b = (const float*)d_in[21];
    const float* ln2g = (const float*)d_in[22];
    const float* ln2b = (const float*)d_in[23];

    float* ws = (float*)d_ws;
    float* tepe = ws;                 // TEPE_N floats
    float* Qb = ws + TEPE_N;          // NX floats; x1 aliases after attn
    float* Kb = Qb + NX;              // NX floats; w1f/w2f/wof alias after attn
    float* Vb = Kb + NX;              // NX floats
    float* ctxb = Vb + NX;            // NX floats; xbf + wqkvf alias before attn
    float* x1 = Qb;

    short* xbf = (short*)ctxb;                  // NX shorts (first half of ctx region)
    short* wqkvf = (short*)ctxb + NX;           // 49152 shorts (second half; dead before attn)
    short* w1f = (short*)Kb;                    // 65536 shorts (K dead after attn)
    short* w2f = w1f + C_ * FF;                 // 65536 shorts
    short* wof = w2f + C_ * FF;                 // 16384 shorts

    k_tepe<<<dim3(TEPE_N / 256), dim3(256), 0, stream>>>(
        time_enc, e_min, e_hr, e_wd, e_mo, e_yr, tepe);
    k_xprep<<<dim3(NX / 4 / 256), dim3(256), 0, stream>>>(query, tepe, xbf);
    k_wcvt_qkv<<<dim3(384 * C_ / 256), dim3(256), 0, stream>>>(Wq, Wk, Wv, wqkvf);
    k_qkv_mfma<<<dim3(NBLK_MM), dim3(256), 0, stream>>>(xbf, wqkvf, Qb, Kb, Vb);
    k_attn<<<dim3(B_ * H_ * N_), dim3(64), 0, stream>>>(
        Qb, Kb, Vb, index_sample, ctxb);
    k_wcvt2<<<dim3((2 * C_ * FF + C_ * C_) / 256), dim3(256), 0, stream>>>(
        ffw1, ffw2, Wo, w1f, w2f, wof);
    k_out_ln_mfma<<<dim3(NBLK_MM), dim3(256), 0, stream>>>(
        ctxb, wof, bo, query, tepe, ln1g, ln1b, x1);
    k_ff_mfma<<<dim3(NBLK_FF), dim3(512), 0, stream>>>(
        x1, w1f, ffb1, w2f, ffb2, ln2g, ln2b, (float*)d_out);
}

// Round 7
// 240.177 us; speedup vs baseline: 2.5187x; 1.1620x over previous
//
#include <hip/hip_runtime.h>
#include <hip/hip_bf16.h>
#include <cmath>

namespace {
constexpr int B_ = 16, N_ = 307, T_ = 24, C_ = 128, H_ = 8, D_ = 16, S_ = 20, U_ = 20;
constexpr int NROW = B_ * N_ * T_;          // 117888
constexpr int NX = NROW * C_;               // 15089664
constexpr int TEPE_N = B_ * T_ * C_;        // 49152
constexpr int FF = 4 * C_;                  // 512
constexpr int BM = 32;                      // rows per MFMA block (qkv/out_ln)
constexpr int NBLK_MM = NROW / BM;          // 3684
constexpr int BMF = 64;                     // rows per FF block
constexpr int NBLK_FF = NROW / BMF;         // 1842
}

typedef __attribute__((ext_vector_type(8))) short short8;
typedef __attribute__((ext_vector_type(4))) short short4_;
typedef __attribute__((ext_vector_type(4))) float f32x4;

__device__ inline short f2bf(float v) {
    union { float f; unsigned u; } a; a.f = v;
    unsigned r = a.u + 0x7fff + ((a.u >> 16) & 1);   // round-to-nearest-even
    return (short)(r >> 16);
}

// ---------------- kernel 0: tepe[b,t,c] = pos_emb(t,c) + sum of 5 embedding lookups
__global__ void k_tepe(const int* __restrict__ te,
                       const float* __restrict__ e_min, const float* __restrict__ e_hr,
                       const float* __restrict__ e_wd, const float* __restrict__ e_mo,
                       const float* __restrict__ e_yr, float* __restrict__ tepe) {
    int i = blockIdx.x * blockDim.x + threadIdx.x;
    if (i >= TEPE_N) return;
    int c = i & (C_ - 1);
    int bt = i >> 7;              // b*T + t
    int t = bt % T_;
    const int* enc = te + bt * 5;
    float v = e_min[enc[0] * C_ + c] + e_hr[enc[1] * C_ + c] + e_wd[enc[2] * C_ + c]
            + e_mo[enc[3] * C_ + c] + e_yr[enc[4] * C_ + c];
    float ang = (float)t * expf(-(float)(c & ~1) * (9.210340371976184f / 128.0f));
    v += (c & 1) ? cosf(ang) : sinf(ang);
    tepe[i] = v;
}

// ---------------- kernel 0b: xbf = bf16(query + tepe), one float4 per thread
__global__ void k_xprep(const float* __restrict__ query, const float* __restrict__ tepe,
                        short* __restrict__ xbf) {
    int i = blockIdx.x * 256 + threadIdx.x;     // i indexes float4s; NX/4 total
    int c4 = i & 31;
    int gr = i >> 5;
    int t = gr % T_;
    int b = gr / (N_ * T_);
    float4 q = *(const float4*)(query + 4 * (size_t)i);
    float4 p = *(const float4*)(tepe + (size_t)(b * T_ + t) * C_ + c4 * 4);
    short4_ s;
    s.x = f2bf(q.x + p.x); s.y = f2bf(q.y + p.y);
    s.z = f2bf(q.z + p.z); s.w = f2bf(q.w + p.w);
    *(short4_*)&xbf[4 * (size_t)i] = s;
}

// ---------------- weight converts: FRAGMENT-LINEAR layout (see round 4 notes).
__global__ void k_wcvt_qkv(const float* __restrict__ Wq, const float* __restrict__ Wk,
                           const float* __restrict__ Wv, short* __restrict__ wqkvf) {
    int i = blockIdx.x * 256 + threadIdx.x;     // 49152
    int tile = i >> 9, l = (i >> 3) & 63, e = i & 7;
    int c_tile = tile >> 2, ks = tile & 3;
    int c_all = c_tile * 16 + (l & 15);
    int k = ks * 32 + (l >> 4) * 8 + e;
    int m = c_all >> 7, c = c_all & (C_ - 1);
    const float* W = (m == 0) ? Wq : (m == 1) ? Wk : Wv;
    wqkvf[i] = f2bf(W[k * C_ + c]);
}

__global__ void k_wcvt2(const float* __restrict__ w1, const float* __restrict__ w2,
                        const float* __restrict__ Wo,
                        short* __restrict__ w1f, short* __restrict__ w2f,
                        short* __restrict__ wof) {
    int i = blockIdx.x * 256 + threadIdx.x;     // 147456
    if (i < C_ * FF) {
        int tile = i >> 9, l = (i >> 3) & 63, e = i & 7;
        int jtile = tile >> 2, ks = tile & 3;
        int j = jtile * 16 + (l & 15);
        int k = ks * 32 + (l >> 4) * 8 + e;
        w1f[i] = f2bf(w1[k * FF + j]);          // w1 is [C][FF] = [k][j]
    } else if (i < 2 * C_ * FF) {
        int i2 = i - C_ * FF;
        int tile = i2 >> 9, l = (i2 >> 3) & 63, e = i2 & 7;
        int c_tile = tile >> 4, ks = tile & 15;
        int c = c_tile * 16 + (l & 15);
        int j = ks * 32 + (l >> 4) * 8 + e;
        w2f[i2] = f2bf(w2[j * C_ + c]);         // w2 is [FF][C] = [j][c]
    } else {
        int i3 = i - 2 * C_ * FF;
        int tile = i3 >> 9, l = (i3 >> 3) & 63, e = i3 & 7;
        int c_tile = tile >> 2, ks = tile & 3;
        int c = c_tile * 16 + (l & 15);
        int k = ks * 32 + (l >> 4) * 8 + e;
        wof[i3] = f2bf(Wo[k * C_ + c]);         // Wo is [C][C] = [k][c]
    }
}

// ---------------- kernel 1: QKV projection via MFMA (frag-linear weights)
// Wave w owns ctiles [w*6, w*6+6) and ALL 32 rows: weight frags shared across 2 row-tiles.
__global__ __launch_bounds__(256) void k_qkv_mfma(
    const short* __restrict__ xbf, const short* __restrict__ wqkvf,
    float* __restrict__ Q, float* __restrict__ K, float* __restrict__ V) {
    __shared__ __align__(16) short xs[BM * C_];
    int tid = threadIdx.x;
    int r0 = blockIdx.x * BM;
    {
        int row = tid >> 3;                 // 0..31
        int cb = (tid & 7) * 16;
        const short* src = xbf + (size_t)(r0 + row) * C_ + cb;
        short8 v0 = *(const short8*)(src);
        short8 v1 = *(const short8*)(src + 8);
        *(short8*)&xs[(row * C_ + cb) ^ ((row & 7) << 3)] = v0;
        *(short8*)&xs[(row * C_ + cb + 8) ^ ((row & 7) << 3)] = v1;
    }
    __syncthreads();
    int w = tid >> 6, l = tid & 63;
    int lr = l & 15, lk = l >> 4;
    int swz = (lr & 7) << 3;                // row-tile-invariant swizzle
    short8 bx[2][4];
#pragma unroll
    for (int rt = 0; rt < 2; rt++)
#pragma unroll
        for (int ks = 0; ks < 4; ks++)
            bx[rt][ks] = *(const short8*)&xs[((rt * 16 + lr) * C_ + ks * 32 + lk * 8) ^ swz];
    size_t base[2];
#pragma unroll
    for (int rt = 0; rt < 2; rt++) {
        int gr = r0 + rt * 16 + lr;
        int t = gr % T_;
        int n = (gr / T_) % N_;
        int b = gr / (N_ * T_);
        base[rt] = ((size_t)b * H_ * N_ + n) * (T_ * D_) + t * D_;
    }
#pragma unroll
    for (int jt = 0; jt < 6; jt++) {
        int ctile = w * 6 + jt;                 // c-tile index 0..23
        const short* ap = wqkvf + (size_t)ctile * 2048 + l * 8;
        short8 acur[4];
#pragma unroll
        for (int ks = 0; ks < 4; ks++) acur[ks] = *(const short8*)(ap + ks * 512);
        f32x4 acc[2] = {{0.f, 0.f, 0.f, 0.f}, {0.f, 0.f, 0.f, 0.f}};
#pragma unroll
        for (int ks = 0; ks < 4; ks++) {
#pragma unroll
            for (int rt = 0; rt < 2; rt++)
                acc[rt] = __builtin_amdgcn_mfma_f32_16x16x32_bf16(acur[ks], bx[rt][ks], acc[rt], 0, 0, 0);
        }
        int c0 = ctile * 16 + lk * 4;
        int m = c0 >> 7;
        int c = c0 & (C_ - 1);
        int h = c >> 4, d = c & 15;
        float* dst = (m == 0) ? Q : (m == 1) ? K : V;
#pragma unroll
        for (int rt = 0; rt < 2; rt++)
            *(float4*)&dst[base[rt] + (size_t)h * (N_ * T_ * D_) + d] = *(float4*)&acc[rt];
    }
}

// ---------------- kernel 2: attention core, one wave per (b,h,n)
__global__ __launch_bounds__(64) void k_attn(
    const float* __restrict__ Q, const float* __restrict__ K, const float* __restrict__ V,
    const int* __restrict__ idxs, float* __restrict__ ctx) {
    __shared__ __align__(16) float Qsf[T_ * 20], Ksf[T_ * 20];
    __shared__ __align__(16) short Qbf[32 * 24], Kbf[32 * 24];   // rows 24-31 garbage (confined)
    __shared__ __align__(16) short Vt[16 * 40];                  // [d][t2], cols 24-31 zeroed
    __shared__ __align__(16) short Pbf[32 * 40];                 // attn weights, cols 24-31 zeroed
    __shared__ float Mv[T_];
    __shared__ int keepS[T_];
    __shared__ float meanVs[D_];
    int e = blockIdx.x;
    int tid = threadIdx.x;
    const float* qb = Q + (size_t)e * (T_ * D_);
    const float* kb = K + (size_t)e * (T_ * D_);
    const float* vb = V + (size_t)e * (T_ * D_);
    for (int i = tid; i < 96; i += 64) {
        int t = i >> 2, c4 = i & 3;
        float4 qv = *(const float4*)(qb + i * 4);
        float4 kv = *(const float4*)(kb + i * 4);
        float4 vv = *(const float4*)(vb + i * 4);
        *(float4*)&Qsf[t * 20 + c4 * 4] = qv;
        *(float4*)&Ksf[t * 20 + c4 * 4] = kv;
        short4_ qs, ks;
        qs.x = f2bf(qv.x); qs.y = f2bf(qv.y); qs.z = f2bf(qv.z); qs.w = f2bf(qv.w);
        ks.x = f2bf(kv.x); ks.y = f2bf(kv.y); ks.z = f2bf(kv.z); ks.w = f2bf(kv.w);
        *(short4_*)&Qbf[t * 24 + c4 * 4] = qs;
        *(short4_*)&Kbf[t * 24 + c4 * 4] = ks;
        Vt[(c4 * 4 + 0) * 40 + t] = f2bf(vv.x);
        Vt[(c4 * 4 + 1) * 40 + t] = f2bf(vv.y);
        Vt[(c4 * 4 + 2) * 40 + t] = f2bf(vv.z);
        Vt[(c4 * 4 + 3) * 40 + t] = f2bf(vv.w);
    }
    for (int i = tid; i < 128; i += 64) {       // zero Vt cols 24-31
        int d = i >> 3, c = 24 + (i & 7);
        Vt[d * 40 + c] = 0;
    }
    __syncthreads();
    if (tid < 48) {
        int t = tid >> 1, half = tid & 1;
        float qreg[16];
#pragma unroll
        for (int j = 0; j < 16; j++) qreg[j] = Qsf[t * 20 + j];
        float mx = -1e30f, sm = 0.f;
        const int* ip = idxs + t * S_ + half * 10;
        for (int s5 = 0; s5 < 10; s5++) {
            int kr = ip[s5];
            const float* kp = &Ksf[kr * 20];
            float d = 0.f;
#pragma unroll
            for (int j = 0; j < 16; j++) d += qreg[j] * kp[j];
            mx = fmaxf(mx, d); sm += d;
        }
        mx = fmaxf(mx, __shfl_xor(mx, 1));
        sm += __shfl_xor(sm, 1);
        if (half == 0) Mv[t] = mx - sm * (1.0f / S_);
    } else if (tid < 48 + D_) {
        int d = tid - 48;
        float s = 0.f;
        for (int t = 0; t < T_; t++) s += __bfloat162float(*(const __hip_bfloat16*)&Vt[d * 40 + t]);
        meanVs[d] = s * (1.0f / T_);
    }
    __syncthreads();
    if (tid < T_) {
        float mt = Mv[tid];
        int cnt = 0;
        for (int t2 = 0; t2 < T_; t2++) {
            float m2 = Mv[t2];
            cnt += (m2 > mt) || (m2 == mt && t2 < tid);
        }
        keepS[tid] = (cnt < U_) ? 1 : 0;
    }
    int lr = tid & 15, lk = tid >> 4;
    short8 zz = {};
    short8 kf0 = zz, kf1 = zz, qf0 = zz, qf1 = zz;
    if (lk < 2) {
        kf0 = *(const short8*)&Kbf[lr * 24 + lk * 8];
        kf1 = *(const short8*)&Kbf[(16 + lr) * 24 + lk * 8];
        qf0 = *(const short8*)&Qbf[lr * 24 + lk * 8];
        qf1 = *(const short8*)&Qbf[(16 + lr) * 24 + lk * 8];
    }
    f32x4 zf = {0.f, 0.f, 0.f, 0.f};
    f32x4 s00 = __builtin_amdgcn_mfma_f32_16x16x32_bf16(kf0, qf0, zf, 0, 0, 0);
    f32x4 s01 = __builtin_amdgcn_mfma_f32_16x16x32_bf16(kf1, qf0, zf, 0, 0, 0);
    f32x4 s10 = __builtin_amdgcn_mfma_f32_16x16x32_bf16(kf0, qf1, zf, 0, 0, 0);
    f32x4 s11 = __builtin_amdgcn_mfma_f32_16x16x32_bf16(kf1, qf1, zf, 0, 0, 0);
#pragma unroll
    for (int rt = 0; rt < 2; rt++) {
        f32x4 c0 = rt ? s10 : s00;
        f32x4 c1 = rt ? s11 : s01;
        float lm = fmaxf(fmaxf(c0[0], c0[1]), fmaxf(c0[2], c0[3]));
        if (lk < 2) lm = fmaxf(lm, fmaxf(fmaxf(c1[0], c1[1]), fmaxf(c1[2], c1[3])));
        lm = fmaxf(lm, __shfl_xor(lm, 16));
        lm = fmaxf(lm, __shfl_xor(lm, 32));
        float e0[4], e1[4];
        float ls = 0.f;
#pragma unroll
        for (int i = 0; i < 4; i++) { e0[i] = __expf(0.25f * (c0[i] - lm)); ls += e0[i]; }
#pragma unroll
        for (int i = 0; i < 4; i++) { e1[i] = (lk < 2) ? __expf(0.25f * (c1[i] - lm)) : 0.f; ls += e1[i]; }
        ls += __shfl_xor(ls, 16);
        ls += __shfl_xor(ls, 32);
        float inv = 1.0f / ls;
        short4_ w0, w1;
        w0.x = f2bf(e0[0] * inv); w0.y = f2bf(e0[1] * inv);
        w0.z = f2bf(e0[2] * inv); w0.w = f2bf(e0[3] * inv);
        w1.x = f2bf(e1[0] * inv); w1.y = f2bf(e1[1] * inv);
        w1.z = f2bf(e1[2] * inv); w1.w = f2bf(e1[3] * inv);
        int trow = rt * 16 + lr;
        *(short4_*)&Pbf[trow * 40 + lk * 4] = w0;
        *(short4_*)&Pbf[trow * 40 + 16 + lk * 4] = w1;    // lk>=2 writes zeros (cols 24-31)
    }
    __syncthreads();
    short8 vf = *(const short8*)&Vt[lr * 40 + lk * 8];
    short8 pf0 = *(const short8*)&Pbf[lr * 40 + lk * 8];
    short8 pf1 = *(const short8*)&Pbf[(16 + lr) * 40 + lk * 8];
    f32x4 u0 = __builtin_amdgcn_mfma_f32_16x16x32_bf16(vf, pf0, zf, 0, 0, 0);
    f32x4 u1 = __builtin_amdgcn_mfma_f32_16x16x32_bf16(vf, pf1, zf, 0, 0, 0);
    int b = e / (H_ * N_);
    int h = (e / N_) % H_;
    int n = e % N_;
    float4 mv4 = *(const float4*)&meanVs[lk * 4];
#pragma unroll
    for (int rt = 0; rt < 2; rt++) {
        int t = rt * 16 + lr;
        if (t < T_) {
            f32x4 u = rt ? u1 : u0;
            float4 o;
            if (keepS[t]) { o.x = u[0]; o.y = u[1]; o.z = u[2]; o.w = u[3]; }
            else o = mv4;
            *(float4*)&ctx[((size_t)(b * N_ + n) * T_ + t) * C_ + h * D_ + lk * 4] = o;
        }
    }
}

// ---------------- kernel 3: att_out = ctx@Wo + bo (MFMA); y = att_out + x; x1 = LN1(y)
// Wave w owns ctiles [w*2, w*2+2) and ALL 32 rows.
__global__ __launch_bounds__(256) void k_out_ln_mfma(
    const float* __restrict__ ctx, const short* __restrict__ wof, const float* __restrict__ bo,
    const float* __restrict__ query, const float* __restrict__ tepe,
    const float* __restrict__ g1, const float* __restrict__ b1,
    float* __restrict__ x1) {
    __shared__ __align__(16) short cbf[BM * C_];
    __shared__ __align__(16) float xf[BM][132];
    int tid = threadIdx.x;
    int r0 = blockIdx.x * BM;
    {
        int row = tid >> 3;
        int cb = (tid & 7) * 16;
        int gr = r0 + row;
        int t = gr % T_;
        int b = gr / (N_ * T_);
        const float* src = ctx + (size_t)gr * C_ + cb;
        const float* qsrc = query + (size_t)gr * C_ + cb;
        const float* tsrc = tepe + (size_t)(b * T_ + t) * C_ + cb;
#pragma unroll
        for (int i = 0; i < 4; i++) {
            float4 v = *(const float4*)(src + 4 * i);
            short4_ sv;
            sv.x = f2bf(v.x); sv.y = f2bf(v.y); sv.z = f2bf(v.z); sv.w = f2bf(v.w);
            *(short4_*)&cbf[(row * C_ + cb + 4 * i) ^ ((row & 7) << 3)] = sv;
            float4 q4 = *(const float4*)(qsrc + 4 * i);
            float4 t4 = *(const float4*)(tsrc + 4 * i);
            float4 xr;
            xr.x = q4.x + t4.x; xr.y = q4.y + t4.y;
            xr.z = q4.z + t4.z; xr.w = q4.w + t4.w;
            *(float4*)&xf[row][cb + 4 * i] = xr;
        }
    }
    __syncthreads();
    int w = tid >> 6, l = tid & 63;
    int lr = l & 15, lk = l >> 4;
    int swz = (lr & 7) << 3;
    short8 bc[2][4];
#pragma unroll
    for (int rt = 0; rt < 2; rt++)
#pragma unroll
        for (int ks = 0; ks < 4; ks++)
            bc[rt][ks] = *(const short8*)&cbf[((rt * 16 + lr) * C_ + ks * 32 + lk * 8) ^ swz];
#pragma unroll
    for (int ct = 0; ct < 2; ct++) {
        int c_tile = w * 2 + ct;                // 0..7
        const short* ap = wof + (size_t)c_tile * 2048 + l * 8;
        short8 acur[4];
#pragma unroll
        for (int ks = 0; ks < 4; ks++) acur[ks] = *(const short8*)(ap + ks * 512);
        f32x4 acc[2] = {{0.f, 0.f, 0.f, 0.f}, {0.f, 0.f, 0.f, 0.f}};
#pragma unroll
        for (int ks = 0; ks < 4; ks++) {
#pragma unroll
            for (int rt = 0; rt < 2; rt++)
                acc[rt] = __builtin_amdgcn_mfma_f32_16x16x32_bf16(acur[ks], bc[rt][ks], acc[rt], 0, 0, 0);
        }
        int cc = c_tile * 16 + lk * 4;
        float4 bias = *(const float4*)(bo + cc);
#pragma unroll
        for (int rt = 0; rt < 2; rt++) {
            int rrow = rt * 16 + lr;
            float4 res = *(const float4*)&xf[rrow][cc];
            float4 o;
            o.x = acc[rt][0] + bias.x + res.x;
            o.y = acc[rt][1] + bias.y + res.y;
            o.z = acc[rt][2] + bias.z + res.z;
            o.w = acc[rt][3] + bias.w + res.w;
            *(float4*)&xf[rrow][cc] = o;
        }
    }
    __syncthreads();
    {
        int r = tid >> 3;
        int q = tid & 7;
        int cb = q * 16;
        float vals[16];
        float s = 0.f;
#pragma unroll
        for (int i = 0; i < 16; i++) { vals[i] = xf[r][cb + i]; s += vals[i]; }
        s += __shfl_xor(s, 1, 8);
        s += __shfl_xor(s, 2, 8);
        s += __shfl_xor(s, 4, 8);
        float mean = s * (1.f / C_);
        float vv = 0.f;
#pragma unroll
        for (int i = 0; i < 16; i++) { float d = vals[i] - mean; vv += d * d; }
        vv += __shfl_xor(vv, 1, 8);
        vv += __shfl_xor(vv, 2, 8);
        vv += __shfl_xor(vv, 4, 8);
        float rstd = rsqrtf(vv * (1.f / C_) + 1e-5f);
        float* op = x1 + (size_t)(r0 + r) * C_ + cb;
#pragma unroll
        for (int i4 = 0; i4 < 4; i4++) {
            float4 gv = *(const float4*)(g1 + cb + 4 * i4);
            float4 bv = *(const float4*)(b1 + cb + 4 * i4);
            float4 ov;
            ov.x = (vals[4 * i4 + 0] - mean) * rstd * gv.x + bv.x;
            ov.y = (vals[4 * i4 + 1] - mean) * rstd * gv.y + bv.y;
            ov.z = (vals[4 * i4 + 2] - mean) * rstd * gv.z + bv.z;
            ov.w = (vals[4 * i4 + 3] - mean) * rstd * gv.w + bv.w;
            *(float4*)(op + 4 * i4) = ov;
        }
    }
}

// ---------------- kernel 4: FF via bf16 MFMA + residual + LN2 -> out
// Wave w owns: GEMM1 jtiles [w*4, w*4+4) x ALL 64 rows (weight frag shared 4x);
// GEMM2 ctile w x ALL 64 rows (weight frag shared 4x). No two waves share a tile.
__global__ __launch_bounds__(512, 4) void k_ff_mfma(
    const float* __restrict__ x1, const short* __restrict__ w1f, const float* __restrict__ b1f,
    const short* __restrict__ w2f, const float* __restrict__ b2f,
    const float* __restrict__ g2, const float* __restrict__ b2ln,
    float* __restrict__ out) {
    __shared__ __align__(16) short xbf[BMF * C_];    // 16 KB, bf16 x, swizzled
    __shared__ __align__(16) short hbf[BMF * FF];    // 64 KB, bf16 hidden, swizzled
    float (*yf)[132] = (float(*)[132])hbf;           // f32 y aliases hbf (33 KB)
    int tid = threadIdx.x;
    int r0 = blockIdx.x * BMF;
    {
        int row = tid >> 3;                 // 0..63
        int cb = (tid & 7) * 16;
        const float* src = x1 + (size_t)(r0 + row) * C_ + cb;
#pragma unroll
        for (int i = 0; i < 4; i++) {
            float4 v = *(const float4*)(src + 4 * i);
            short4_ sv;
            sv.x = f2bf(v.x); sv.y = f2bf(v.y); sv.z = f2bf(v.z); sv.w = f2bf(v.w);
            *(short4_*)&xbf[(row * C_ + cb + 4 * i) ^ ((row & 7) << 3)] = sv;
        }
    }
    __syncthreads();
    int w = tid >> 6, l = tid & 63;
    int lr = l & 15, lk = l >> 4;           // lk in 0..3
    int swz = (lr & 7) << 3;                // row-tile-invariant swizzle
    // ---- GEMM1: x fragments for all 4 row-tiles in registers
    {
        short8 bx[4][4];
#pragma unroll
        for (int rt = 0; rt < 4; rt++)
#pragma unroll
            for (int ks = 0; ks < 4; ks++)
                bx[rt][ks] = *(const short8*)&xbf[((rt * 16 + lr) * C_ + ks * 32 + lk * 8) ^ swz];
#pragma unroll
        for (int jt = 0; jt < 4; jt++) {
            int jtile = w * 4 + jt;             // 0..31
            const short* ap = w1f + (size_t)jtile * 2048 + l * 8;
            short8 acur[4];
#pragma unroll
            for (int ks = 0; ks < 4; ks++) acur[ks] = *(const short8*)(ap + ks * 512);
            f32x4 acc[4] = {{0.f, 0.f, 0.f, 0.f}, {0.f, 0.f, 0.f, 0.f},
                            {0.f, 0.f, 0.f, 0.f}, {0.f, 0.f, 0.f, 0.f}};
#pragma unroll
            for (int ks = 0; ks < 4; ks++) {
#pragma unroll
                for (int rt = 0; rt < 4; rt++)
                    acc[rt] = __builtin_amdgcn_mfma_f32_16x16x32_bf16(acur[ks], bx[rt][ks], acc[rt], 0, 0, 0);
            }
            int j0 = jtile * 16 + lk * 4;
            float4 bias = *(const float4*)(b1f + j0);
#pragma unroll
            for (int rt = 0; rt < 4; rt++) {
                int rr = rt * 16 + lr;
                short4_ hv;
                hv.x = f2bf(fmaxf(acc[rt][0] + bias.x, 0.f));
                hv.y = f2bf(fmaxf(acc[rt][1] + bias.y, 0.f));
                hv.z = f2bf(fmaxf(acc[rt][2] + bias.z, 0.f));
                hv.w = f2bf(fmaxf(acc[rt][3] + bias.w, 0.f));
                *(short4_*)&hbf[(rr * FF + j0) ^ swz] = hv;
            }
        }
    }
    __syncthreads();
    // ---- GEMM2: wave owns c-tile w, all 64 rows
    f32x4 acc2[4] = {{0.f, 0.f, 0.f, 0.f}, {0.f, 0.f, 0.f, 0.f},
                     {0.f, 0.f, 0.f, 0.f}, {0.f, 0.f, 0.f, 0.f}};
    int ctile = w;
#pragma unroll 4
    for (int ks = 0; ks < 16; ks++) {
        short8 aw = *(const short8*)(w2f + ((size_t)(ctile * 16 + ks)) * 512 + l * 8);
#pragma unroll
        for (int rt = 0; rt < 4; rt++) {
            short8 hx = *(const short8*)&hbf[((rt * 16 + lr) * FF + ks * 32 + lk * 8) ^ swz];
            acc2[rt] = __builtin_amdgcn_mfma_f32_16x16x32_bf16(aw, hx, acc2[rt], 0, 0, 0);
        }
    }
    int cc = ctile * 16 + lk * 4;
    float4 bias2 = *(const float4*)(b2f + cc);
    float4 res[4];
#pragma unroll
    for (int rt = 0; rt < 4; rt++)
        res[rt] = *(const float4*)(x1 + (size_t)(r0 + rt * 16 + lr) * C_ + cc);
    __syncthreads();    // all hbf reads done -> safe to overwrite with y
#pragma unroll
    for (int rt = 0; rt < 4; rt++) {
        float4 o;
        o.x = acc2[rt][0] + bias2.x + res[rt].x;
        o.y = acc2[rt][1] + bias2.y + res[rt].y;
        o.z = acc2[rt][2] + bias2.z + res[rt].z;
        o.w = acc2[rt][3] + bias2.w + res[rt].w;
        *(float4*)&yf[rt * 16 + lr][cc] = o;
    }
    __syncthreads();
    // ---- LN2 + store
    {
        int r = tid >> 3;                   // 0..63
        int q = tid & 7;
        int cb = q * 16;
        float vals[16];
        float s = 0.f;
#pragma unroll
        for (int i = 0; i < 16; i++) { vals[i] = yf[r][cb + i]; s += vals[i]; }
        s += __shfl_xor(s, 1, 8);
        s += __shfl_xor(s, 2, 8);
        s += __shfl_xor(s, 4, 8);
        float mean = s * (1.f / C_);
        float vv = 0.f;
#pragma unroll
        for (int i = 0; i < 16; i++) { float d = vals[i] - mean; vv += d * d; }
        vv += __shfl_xor(vv, 1, 8);
        vv += __shfl_xor(vv, 2, 8);
        vv += __shfl_xor(vv, 4, 8);
        float rstd = rsqrtf(vv * (1.f / C_) + 1e-5f);
        float* op = out + (size_t)(r0 + r) * C_ + cb;
#pragma unroll
        for (int i4 = 0; i4 < 4; i4++) {
            float4 gv = *(const float4*)(g2 + cb + 4 * i4);
            float4 bv = *(const float4*)(b2ln + cb + 4 * i4);
            float4 ov;
            ov.x = (vals[4 * i4 + 0] - mean) * rstd * gv.x + bv.x;
            ov.y = (vals[4 * i4 + 1] - mean) * rstd * gv.y + bv.y;
            ov.z = (vals[4 * i4 + 2] - mean) * rstd * gv.z + bv.z;
            ov.w = (vals[4 * i4 + 3] - mean) * rstd * gv.w + bv.w;
            *(float4*)(op + 4 * i4) = ov;
        }
    }
}

extern "C" void kernel_launch(void* const* d_in, const int* in_sizes, int n_in,
                              void* d_out, int out_size, void* d_ws, size_t ws_size,
                              hipStream_t stream) {
    const float* query = (const float*)d_in[2];
    const int* time_enc = (const int*)d_in[4];
    const int* index_sample = (const int*)d_in[5];
    const float* e_min = (const float*)d_in[6];
    const float* e_hr  = (const float*)d_in[7];
    const float* e_wd  = (const float*)d_in[8];
    const float* e_mo  = (const float*)d_in[9];
    const float* e_yr  = (const float*)d_in[10];
    const float* Wq = (const float*)d_in[11];
    const float* Wk = (const float*)d_in[12];
    const float* Wv = (const float*)d_in[13];
    const float* Wo = (const float*)d_in[14];
    const float* bo = (const float*)d_in[15];
    const float* ffw1 = (const float*)d_in[16];
    const float* ffb1 = (const float*)d_in[17];
    const float* ffw2 = (const float*)d_in[18];
    const float* ffb2 = (const float*)d_in[19];
    const float* ln1g = (const float*)d_in[20];
    const float* ln1b = (const float*)d_in[21];
    const float* ln2g = (const float*)d_in[22];
    const float* ln2b = (const float*)d_in[23];

    float* ws = (float*)d_ws;
    float* tepe = ws;                 // TEPE_N floats
    float* Qb = ws + TEPE_N;          // NX floats; x1 aliases after attn
    float* Kb = Qb + NX;              // NX floats; w1f/w2f/wof alias after attn
    float* Vb = Kb + NX;              // NX floats
    float* ctxb = Vb + NX;            // NX floats; xbf + wqkvf alias before attn
    float* x1 = Qb;

    short* xbf = (short*)ctxb;                  // NX shorts (first half of ctx region)
    short* wqkvf = (short*)ctxb + NX;           // 49152 shorts (second half; dead before attn)
    short* w1f = (short*)Kb;                    // 65536 shorts (K dead after attn)
    short* w2f = w1f + C_ * FF;                 // 65536 shorts
    short* wof = w2f + C_ * FF;                 // 16384 shorts

    k_tepe<<<dim3(TEPE_N / 256), dim3(256), 0, stream>>>(
        time_enc, e_min, e_hr, e_wd, e_mo, e_yr, tepe);
    k_xprep<<<dim3(NX / 4 / 256), dim3(256), 0, stream>>>(query, tepe, xbf);
    k_wcvt_qkv<<<dim3(384 * C_ / 256), dim3(256), 0, stream>>>(Wq, Wk, Wv, wqkvf);
    k_qkv_mfma<<<dim3(NBLK_MM), dim3(256), 0, stream>>>(xbf, wqkvf, Qb, Kb, Vb);
    k_attn<<<dim3(B_ * H_ * N_), dim3(64), 0, stream>>>(
        Qb, Kb, Vb, index_sample, ctxb);
    k_wcvt2<<<dim3((2 * C_ * FF + C_ * C_) / 256), dim3(256), 0, stream>>>(
        ffw1, ffw2, Wo, w1f, w2f, wof);
    k_out_ln_mfma<<<dim3(NBLK_MM), dim3(256), 0, stream>>>(
        ctxb, wof, bo, query, tepe, ln1g, ln1b, x1);
    k_ff_mfma<<<dim3(NBLK_FF), dim3(512), 0, stream>>>(
        x1, w1f, ffb1, w2f, ffb2, ln2g, ln2b, (float*)d_out);
}

// Round 8
// 224.262 us; speedup vs baseline: 2.6975x; 1.0710x over previous
//
#include <hip/hip_runtime.h>
#include <hip/hip_bf16.h>
#include <cmath>

namespace {
constexpr int B_ = 16, N_ = 307, T_ = 24, C_ = 128, H_ = 8, D_ = 16, S_ = 20, U_ = 20;
constexpr int NROW = B_ * N_ * T_;          // 117888
constexpr int NX = NROW * C_;               // 15089664
constexpr int TEPE_N = B_ * T_ * C_;        // 49152
constexpr int FF = 4 * C_;                  // 512
constexpr int BM = 32;                      // rows per MFMA block (qkv/out_ln)
constexpr int NBLK_MM = NROW / BM;          // 3684
constexpr int BMF = 64;                     // rows per FF block
constexpr int NBLK_FF = NROW / BMF;         // 1842
}

typedef __attribute__((ext_vector_type(8))) short short8;
typedef __attribute__((ext_vector_type(4))) short short4_;
typedef __attribute__((ext_vector_type(4))) float f32x4;

__device__ inline short f2bf(float v) {
    union { float f; unsigned u; } a; a.f = v;
    unsigned r = a.u + 0x7fff + ((a.u >> 16) & 1);   // round-to-nearest-even
    return (short)(r >> 16);
}
__device__ inline float bf2f(short s) {
    return __bfloat162float(*(const __hip_bfloat16*)&s);
}

// ---------------- kernel 0: tepe[b,t,c] = pos_emb(t,c) + sum of 5 embedding lookups
__global__ void k_tepe(const int* __restrict__ te,
                       const float* __restrict__ e_min, const float* __restrict__ e_hr,
                       const float* __restrict__ e_wd, const float* __restrict__ e_mo,
                       const float* __restrict__ e_yr, float* __restrict__ tepe) {
    int i = blockIdx.x * blockDim.x + threadIdx.x;
    if (i >= TEPE_N) return;
    int c = i & (C_ - 1);
    int bt = i >> 7;              // b*T + t
    int t = bt % T_;
    const int* enc = te + bt * 5;
    float v = e_min[enc[0] * C_ + c] + e_hr[enc[1] * C_ + c] + e_wd[enc[2] * C_ + c]
            + e_mo[enc[3] * C_ + c] + e_yr[enc[4] * C_ + c];
    float ang = (float)t * expf(-(float)(c & ~1) * (9.210340371976184f / 128.0f));
    v += (c & 1) ? cosf(ang) : sinf(ang);
    tepe[i] = v;
}

// ---------------- kernel 0b: xbf = bf16(query + tepe)
__global__ void k_xprep(const float* __restrict__ query, const float* __restrict__ tepe,
                        short* __restrict__ xbf) {
    int i = blockIdx.x * 256 + threadIdx.x;     // i indexes float4s; NX/4 total
    int c4 = i & 31;
    int gr = i >> 5;
    int t = gr % T_;
    int b = gr / (N_ * T_);
    float4 q = *(const float4*)(query + 4 * (size_t)i);
    float4 p = *(const float4*)(tepe + (size_t)(b * T_ + t) * C_ + c4 * 4);
    short4_ s;
    s.x = f2bf(q.x + p.x); s.y = f2bf(q.y + p.y);
    s.z = f2bf(q.z + p.z); s.w = f2bf(q.w + p.w);
    *(short4_*)&xbf[4 * (size_t)i] = s;
}

// ---------------- weight converts: FRAGMENT-LINEAR layout (see round 4 notes).
__global__ void k_wcvt_qkv(const float* __restrict__ Wq, const float* __restrict__ Wk,
                           const float* __restrict__ Wv, short* __restrict__ wqkvf) {
    int i = blockIdx.x * 256 + threadIdx.x;     // 49152
    int tile = i >> 9, l = (i >> 3) & 63, e = i & 7;
    int c_tile = tile >> 2, ks = tile & 3;
    int c_all = c_tile * 16 + (l & 15);
    int k = ks * 32 + (l >> 4) * 8 + e;
    int m = c_all >> 7, c = c_all & (C_ - 1);
    const float* W = (m == 0) ? Wq : (m == 1) ? Wk : Wv;
    wqkvf[i] = f2bf(W[k * C_ + c]);
}

__global__ void k_wcvt2(const float* __restrict__ w1, const float* __restrict__ w2,
                        const float* __restrict__ Wo,
                        short* __restrict__ w1f, short* __restrict__ w2f,
                        short* __restrict__ wof) {
    int i = blockIdx.x * 256 + threadIdx.x;     // 147456
    if (i < C_ * FF) {
        int tile = i >> 9, l = (i >> 3) & 63, e = i & 7;
        int jtile = tile >> 2, ks = tile & 3;
        int j = jtile * 16 + (l & 15);
        int k = ks * 32 + (l >> 4) * 8 + e;
        w1f[i] = f2bf(w1[k * FF + j]);          // w1 is [C][FF] = [k][j]
    } else if (i < 2 * C_ * FF) {
        int i2 = i - C_ * FF;
        int tile = i2 >> 9, l = (i2 >> 3) & 63, e = i2 & 7;
        int c_tile = tile >> 4, ks = tile & 15;
        int c = c_tile * 16 + (l & 15);
        int j = ks * 32 + (l >> 4) * 8 + e;
        w2f[i2] = f2bf(w2[j * C_ + c]);         // w2 is [FF][C] = [j][c]
    } else {
        int i3 = i - 2 * C_ * FF;
        int tile = i3 >> 9, l = (i3 >> 3) & 63, e = i3 & 7;
        int c_tile = tile >> 2, ks = tile & 3;
        int c = c_tile * 16 + (l & 15);
        int k = ks * 32 + (l >> 4) * 8 + e;
        wof[i3] = f2bf(Wo[k * C_ + c]);         // Wo is [C][C] = [k][c]
    }
}

// ---------------- kernel 1: QKV projection via MFMA -> bf16 Q/K/V
__global__ __launch_bounds__(256) void k_qkv_mfma(
    const short* __restrict__ xbf, const short* __restrict__ wqkvf,
    short* __restrict__ Q, short* __restrict__ K, short* __restrict__ V) {
    __shared__ __align__(16) short xs[BM * C_];
    int tid = threadIdx.x;
    int r0 = blockIdx.x * BM;
    {
        int row = tid >> 3;                 // 0..31
        int cb = (tid & 7) * 16;
        const short* src = xbf + (size_t)(r0 + row) * C_ + cb;
        short8 v0 = *(const short8*)(src);
        short8 v1 = *(const short8*)(src + 8);
        *(short8*)&xs[(row * C_ + cb) ^ ((row & 7) << 3)] = v0;
        *(short8*)&xs[(row * C_ + cb + 8) ^ ((row & 7) << 3)] = v1;
    }
    __syncthreads();
    int w = tid >> 6, l = tid & 63;
    int lr = l & 15, lk = l >> 4;
    int swz = (lr & 7) << 3;                // row-tile-invariant swizzle
    short8 bx[2][4];
#pragma unroll
    for (int rt = 0; rt < 2; rt++)
#pragma unroll
        for (int ks = 0; ks < 4; ks++)
            bx[rt][ks] = *(const short8*)&xs[((rt * 16 + lr) * C_ + ks * 32 + lk * 8) ^ swz];
    size_t base[2];
#pragma unroll
    for (int rt = 0; rt < 2; rt++) {
        int gr = r0 + rt * 16 + lr;
        int t = gr % T_;
        int n = (gr / T_) % N_;
        int b = gr / (N_ * T_);
        base[rt] = ((size_t)b * H_ * N_ + n) * (T_ * D_) + t * D_;
    }
#pragma unroll
    for (int jt = 0; jt < 6; jt++) {
        int ctile = w * 6 + jt;                 // c-tile index 0..23
        const short* ap = wqkvf + (size_t)ctile * 2048 + l * 8;
        short8 acur[4];
#pragma unroll
        for (int ks = 0; ks < 4; ks++) acur[ks] = *(const short8*)(ap + ks * 512);
        f32x4 acc[2] = {{0.f, 0.f, 0.f, 0.f}, {0.f, 0.f, 0.f, 0.f}};
#pragma unroll
        for (int ks = 0; ks < 4; ks++) {
#pragma unroll
            for (int rt = 0; rt < 2; rt++)
                acc[rt] = __builtin_amdgcn_mfma_f32_16x16x32_bf16(acur[ks], bx[rt][ks], acc[rt], 0, 0, 0);
        }
        int c0 = ctile * 16 + lk * 4;
        int m = c0 >> 7;
        int c = c0 & (C_ - 1);
        int h = c >> 4, d = c & 15;
        short* dst = (m == 0) ? Q : (m == 1) ? K : V;
#pragma unroll
        for (int rt = 0; rt < 2; rt++) {
            short4_ sv;
            sv.x = f2bf(acc[rt][0]); sv.y = f2bf(acc[rt][1]);
            sv.z = f2bf(acc[rt][2]); sv.w = f2bf(acc[rt][3]);
            *(short4_*)&dst[base[rt] + (size_t)h * (N_ * T_ * D_) + d] = sv;
        }
    }
}

// ---------------- kernel 2: attention core, one wave per (b,h,n), bf16 in/out.
// Selection M[t] derived from the score MFMA via an LDS count table (handles
// duplicate sample indices); no separate f32 dot path.
__global__ __launch_bounds__(64) void k_attn(
    const short* __restrict__ Q, const short* __restrict__ K, const short* __restrict__ V,
    const int* __restrict__ idxs, short* __restrict__ ctx) {
    __shared__ __align__(16) short Qbf[32 * 24], Kbf[32 * 24];   // rows 24-31 garbage (confined)
    __shared__ __align__(16) short Vt[16 * 40];                  // [d][t2], cols 24-31 zeroed
    __shared__ __align__(16) short Pbf[32 * 40];                 // attn weights, cols 24-31 zeroed
    __shared__ int sidx[T_ * S_];                                // 480
    __shared__ unsigned char cnt[T_][32];                        // sample counts per (t, t2)
    __shared__ float Mv[T_];
    __shared__ int keepS[T_];
    __shared__ float meanVs[D_];
    int e = blockIdx.x;
    int tid = threadIdx.x;
    const short* qb = Q + (size_t)e * (T_ * D_);
    const short* kb = K + (size_t)e * (T_ * D_);
    const short* vb = V + (size_t)e * (T_ * D_);
    // ---- stage Q,K rows; V transposed
    if (tid < 48) {
        int t = tid >> 1, hf = tid & 1;
        *(short8*)&Qbf[t * 24 + hf * 8] = *(const short8*)(qb + t * 16 + hf * 8);
        *(short8*)&Kbf[t * 24 + hf * 8] = *(const short8*)(kb + t * 16 + hf * 8);
    }
    for (int i = tid; i < 96; i += 64) {
        int t = i >> 2, c4 = i & 3;
        short4_ v = *(const short4_*)(vb + t * 16 + c4 * 4);
        Vt[(c4 * 4 + 0) * 40 + t] = v.x;
        Vt[(c4 * 4 + 1) * 40 + t] = v.y;
        Vt[(c4 * 4 + 2) * 40 + t] = v.z;
        Vt[(c4 * 4 + 3) * 40 + t] = v.w;
    }
    for (int i = tid; i < 128; i += 64) {       // zero Vt cols 24-31
        int d = i >> 3, c = 24 + (i & 7);
        Vt[d * 40 + c] = 0;
    }
    for (int i = tid; i < T_ * S_; i += 64) sidx[i] = idxs[i];
    {
        int* ci = (int*)cnt;
        for (int i = tid; i < 192; i += 64) ci[i] = 0;
    }
    __syncthreads();
    // ---- counts (lanes 0-23) and meanV (lanes 48-63)
    if (tid < T_) {
        const int* ip = &sidx[tid * S_];
        for (int s = 0; s < S_; s++) cnt[tid][ip[s]]++;
    } else if (tid >= 48) {
        int d = tid - 48;
        float s = 0.f;
        for (int t = 0; t < T_; t++) s += bf2f(Vt[d * 40 + t]);
        meanVs[d] = s * (1.0f / T_);
    }
    __syncthreads();
    // ---- scores via MFMA: sc[t][t2], A = K rows (t2), B = Q rows (t)
    int lr = tid & 15, lk = tid >> 4;
    short8 zz = {};
    short8 kf0 = zz, kf1 = zz, qf0 = zz, qf1 = zz;
    if (lk < 2) {
        kf0 = *(const short8*)&Kbf[lr * 24 + lk * 8];
        kf1 = *(const short8*)&Kbf[(16 + lr) * 24 + lk * 8];
        qf0 = *(const short8*)&Qbf[lr * 24 + lk * 8];
        qf1 = *(const short8*)&Qbf[(16 + lr) * 24 + lk * 8];
    }
    f32x4 zf = {0.f, 0.f, 0.f, 0.f};
    f32x4 s00 = __builtin_amdgcn_mfma_f32_16x16x32_bf16(kf0, qf0, zf, 0, 0, 0);
    f32x4 s01 = __builtin_amdgcn_mfma_f32_16x16x32_bf16(kf1, qf0, zf, 0, 0, 0);
    f32x4 s10 = __builtin_amdgcn_mfma_f32_16x16x32_bf16(kf0, qf1, zf, 0, 0, 0);
    f32x4 s11 = __builtin_amdgcn_mfma_f32_16x16x32_bf16(kf1, qf1, zf, 0, 0, 0);
    // ---- M[t] = max(sampled) - sum(sampled)/S from the score registers
#pragma unroll
    for (int rt = 0; rt < 2; rt++) {
        int t = rt * 16 + lr;
        int tt = (t < T_) ? t : 0;
        f32x4 c0 = rt ? s10 : s00;
        f32x4 c1 = rt ? s11 : s01;
        float mx = -1e30f, sm = 0.f;
#pragma unroll
        for (int i = 0; i < 4; i++) {
            int cA = cnt[tt][lk * 4 + i];
            if (cA) { mx = fmaxf(mx, c0[i]); sm += (float)cA * c0[i]; }
        }
        if (lk < 2) {
#pragma unroll
            for (int i = 0; i < 4; i++) {
                int cB = cnt[tt][16 + lk * 4 + i];
                if (cB) { mx = fmaxf(mx, c1[i]); sm += (float)cB * c1[i]; }
            }
        }
        mx = fmaxf(mx, __shfl_xor(mx, 16));
        mx = fmaxf(mx, __shfl_xor(mx, 32));
        sm += __shfl_xor(sm, 16);
        sm += __shfl_xor(sm, 32);
        if (lk == 0 && t < T_) Mv[t] = mx - sm * (1.0f / S_);
    }
    __syncthreads();
    // ---- keep mask (top-U as a set, tie-break lower index)
    if (tid < T_) {
        float mt = Mv[tid];
        int cnt2 = 0;
        for (int t2 = 0; t2 < T_; t2++) {
            float m2 = Mv[t2];
            cnt2 += (m2 > mt) || (m2 == mt && t2 < tid);
        }
        keepS[tid] = (cnt2 < U_) ? 1 : 0;
    }
    // ---- softmax in registers
#pragma unroll
    for (int rt = 0; rt < 2; rt++) {
        f32x4 c0 = rt ? s10 : s00;
        f32x4 c1 = rt ? s11 : s01;
        float lm = fmaxf(fmaxf(c0[0], c0[1]), fmaxf(c0[2], c0[3]));
        if (lk < 2) lm = fmaxf(lm, fmaxf(fmaxf(c1[0], c1[1]), fmaxf(c1[2], c1[3])));
        lm = fmaxf(lm, __shfl_xor(lm, 16));
        lm = fmaxf(lm, __shfl_xor(lm, 32));
        float e0[4], e1[4];
        float ls = 0.f;
#pragma unroll
        for (int i = 0; i < 4; i++) { e0[i] = __expf(0.25f * (c0[i] - lm)); ls += e0[i]; }
#pragma unroll
        for (int i = 0; i < 4; i++) { e1[i] = (lk < 2) ? __expf(0.25f * (c1[i] - lm)) : 0.f; ls += e1[i]; }
        ls += __shfl_xor(ls, 16);
        ls += __shfl_xor(ls, 32);
        float inv = 1.0f / ls;
        short4_ w0, w1;
        w0.x = f2bf(e0[0] * inv); w0.y = f2bf(e0[1] * inv);
        w0.z = f2bf(e0[2] * inv); w0.w = f2bf(e0[3] * inv);
        w1.x = f2bf(e1[0] * inv); w1.y = f2bf(e1[1] * inv);
        w1.z = f2bf(e1[2] * inv); w1.w = f2bf(e1[3] * inv);
        int trow = rt * 16 + lr;
        *(short4_*)&Pbf[trow * 40 + lk * 4] = w0;
        *(short4_*)&Pbf[trow * 40 + 16 + lk * 4] = w1;    // lk>=2 writes zeros (cols 24-31)
    }
    __syncthreads();
    // ---- PV via MFMA: upd[t][d], A = Vt rows (d), B = attn rows (t), K = 32
    short8 vf = *(const short8*)&Vt[lr * 40 + lk * 8];
    short8 pf0 = *(const short8*)&Pbf[lr * 40 + lk * 8];
    short8 pf1 = *(const short8*)&Pbf[(16 + lr) * 40 + lk * 8];
    f32x4 u0 = __builtin_amdgcn_mfma_f32_16x16x32_bf16(vf, pf0, zf, 0, 0, 0);
    f32x4 u1 = __builtin_amdgcn_mfma_f32_16x16x32_bf16(vf, pf1, zf, 0, 0, 0);
    // ---- store bf16 ctx: kept rows get upd, dropped rows get meanV
    int b = e / (H_ * N_);
    int h = (e / N_) % H_;
    int n = e % N_;
    float4 mv4 = *(const float4*)&meanVs[lk * 4];
#pragma unroll
    for (int rt = 0; rt < 2; rt++) {
        int t = rt * 16 + lr;
        if (t < T_) {
            f32x4 u = rt ? u1 : u0;
            float4 o;
            if (keepS[t]) { o.x = u[0]; o.y = u[1]; o.z = u[2]; o.w = u[3]; }
            else o = mv4;
            short4_ sv;
            sv.x = f2bf(o.x); sv.y = f2bf(o.y); sv.z = f2bf(o.z); sv.w = f2bf(o.w);
            *(short4_*)&ctx[((size_t)(b * N_ + n) * T_ + t) * C_ + h * D_ + lk * 4] = sv;
        }
    }
}

// ---------------- kernel 3: att_out = ctx@Wo + bo (MFMA); y = att_out + x; x1 = LN1(y)
__global__ __launch_bounds__(256) void k_out_ln_mfma(
    const short* __restrict__ ctx, const short* __restrict__ wof, const float* __restrict__ bo,
    const float* __restrict__ query, const float* __restrict__ tepe,
    const float* __restrict__ g1, const float* __restrict__ b1,
    float* __restrict__ x1) {
    __shared__ __align__(16) short cbf[BM * C_];
    __shared__ __align__(16) float xf[BM][132];
    int tid = threadIdx.x;
    int r0 = blockIdx.x * BM;
    {
        int row = tid >> 3;
        int cb = (tid & 7) * 16;
        int gr = r0 + row;
        int t = gr % T_;
        int b = gr / (N_ * T_);
        const short* src = ctx + (size_t)gr * C_ + cb;
        const float* qsrc = query + (size_t)gr * C_ + cb;
        const float* tsrc = tepe + (size_t)(b * T_ + t) * C_ + cb;
        short8 v0 = *(const short8*)(src);
        short8 v1 = *(const short8*)(src + 8);
        int swz0 = (row & 7) << 3;
        *(short8*)&cbf[(row * C_ + cb) ^ swz0] = v0;
        *(short8*)&cbf[(row * C_ + cb + 8) ^ swz0] = v1;
#pragma unroll
        for (int i = 0; i < 4; i++) {
            float4 q4 = *(const float4*)(qsrc + 4 * i);
            float4 t4 = *(const float4*)(tsrc + 4 * i);
            float4 xr;
            xr.x = q4.x + t4.x; xr.y = q4.y + t4.y;
            xr.z = q4.z + t4.z; xr.w = q4.w + t4.w;
            *(float4*)&xf[row][cb + 4 * i] = xr;
        }
    }
    __syncthreads();
    int w = tid >> 6, l = tid & 63;
    int lr = l & 15, lk = l >> 4;
    int swz = (lr & 7) << 3;
    short8 bc[2][4];
#pragma unroll
    for (int rt = 0; rt < 2; rt++)
#pragma unroll
        for (int ks = 0; ks < 4; ks++)
            bc[rt][ks] = *(const short8*)&cbf[((rt * 16 + lr) * C_ + ks * 32 + lk * 8) ^ swz];
#pragma unroll
    for (int ct = 0; ct < 2; ct++) {
        int c_tile = w * 2 + ct;                // 0..7
        const short* ap = wof + (size_t)c_tile * 2048 + l * 8;
        short8 acur[4];
#pragma unroll
        for (int ks = 0; ks < 4; ks++) acur[ks] = *(const short8*)(ap + ks * 512);
        f32x4 acc[2] = {{0.f, 0.f, 0.f, 0.f}, {0.f, 0.f, 0.f, 0.f}};
#pragma unroll
        for (int ks = 0; ks < 4; ks++) {
#pragma unroll
            for (int rt = 0; rt < 2; rt++)
                acc[rt] = __builtin_amdgcn_mfma_f32_16x16x32_bf16(acur[ks], bc[rt][ks], acc[rt], 0, 0, 0);
        }
        int cc = c_tile * 16 + lk * 4;
        float4 bias = *(const float4*)(bo + cc);
#pragma unroll
        for (int rt = 0; rt < 2; rt++) {
            int rrow = rt * 16 + lr;
            float4 res = *(const float4*)&xf[rrow][cc];
            float4 o;
            o.x = acc[rt][0] + bias.x + res.x;
            o.y = acc[rt][1] + bias.y + res.y;
            o.z = acc[rt][2] + bias.z + res.z;
            o.w = acc[rt][3] + bias.w + res.w;
            *(float4*)&xf[rrow][cc] = o;
        }
    }
    __syncthreads();
    {
        int r = tid >> 3;
        int q = tid & 7;
        int cb = q * 16;
        float vals[16];
        float s = 0.f;
#pragma unroll
        for (int i = 0; i < 16; i++) { vals[i] = xf[r][cb + i]; s += vals[i]; }
        s += __shfl_xor(s, 1, 8);
        s += __shfl_xor(s, 2, 8);
        s += __shfl_xor(s, 4, 8);
        float mean = s * (1.f / C_);
        float vv = 0.f;
#pragma unroll
        for (int i = 0; i < 16; i++) { float d = vals[i] - mean; vv += d * d; }
        vv += __shfl_xor(vv, 1, 8);
        vv += __shfl_xor(vv, 2, 8);
        vv += __shfl_xor(vv, 4, 8);
        float rstd = rsqrtf(vv * (1.f / C_) + 1e-5f);
        float* op = x1 + (size_t)(r0 + r) * C_ + cb;
#pragma unroll
        for (int i4 = 0; i4 < 4; i4++) {
            float4 gv = *(const float4*)(g1 + cb + 4 * i4);
            float4 bv = *(const float4*)(b1 + cb + 4 * i4);
            float4 ov;
            ov.x = (vals[4 * i4 + 0] - mean) * rstd * gv.x + bv.x;
            ov.y = (vals[4 * i4 + 1] - mean) * rstd * gv.y + bv.y;
            ov.z = (vals[4 * i4 + 2] - mean) * rstd * gv.z + bv.z;
            ov.w = (vals[4 * i4 + 3] - mean) * rstd * gv.w + bv.w;
            *(float4*)(op + 4 * i4) = ov;
        }
    }
}

// ---------------- kernel 4: FF via bf16 MFMA + residual + LN2 -> out
__global__ __launch_bounds__(512, 4) void k_ff_mfma(
    const float* __restrict__ x1, const short* __restrict__ w1f, const float* __restrict__ b1f,
    const short* __restrict__ w2f, const float* __restrict__ b2f,
    const float* __restrict__ g2, const float* __restrict__ b2ln,
    float* __restrict__ out) {
    __shared__ __align__(16) short xbf[BMF * C_];    // 16 KB, bf16 x, swizzled
    __shared__ __align__(16) short hbf[BMF * FF];    // 64 KB, bf16 hidden, swizzled
    float (*yf)[132] = (float(*)[132])hbf;           // f32 y aliases hbf (33 KB)
    int tid = threadIdx.x;
    int r0 = blockIdx.x * BMF;
    {
        int row = tid >> 3;                 // 0..63
        int cb = (tid & 7) * 16;
        const float* src = x1 + (size_t)(r0 + row) * C_ + cb;
#pragma unroll
        for (int i = 0; i < 4; i++) {
            float4 v = *(const float4*)(src + 4 * i);
            short4_ sv;
            sv.x = f2bf(v.x); sv.y = f2bf(v.y); sv.z = f2bf(v.z); sv.w = f2bf(v.w);
            *(short4_*)&xbf[(row * C_ + cb + 4 * i) ^ ((row & 7) << 3)] = sv;
        }
    }
    __syncthreads();
    int w = tid >> 6, l = tid & 63;
    int lr = l & 15, lk = l >> 4;           // lk in 0..3
    int swz = (lr & 7) << 3;                // row-tile-invariant swizzle
    {
        short8 bx[4][4];
#pragma unroll
        for (int rt = 0; rt < 4; rt++)
#pragma unroll
            for (int ks = 0; ks < 4; ks++)
                bx[rt][ks] = *(const short8*)&xbf[((rt * 16 + lr) * C_ + ks * 32 + lk * 8) ^ swz];
#pragma unroll
        for (int jt = 0; jt < 4; jt++) {
            int jtile = w * 4 + jt;             // 0..31
            const short* ap = w1f + (size_t)jtile * 2048 + l * 8;
            short8 acur[4];
#pragma unroll
            for (int ks = 0; ks < 4; ks++) acur[ks] = *(const short8*)(ap + ks * 512);
            f32x4 acc[4] = {{0.f, 0.f, 0.f, 0.f}, {0.f, 0.f, 0.f, 0.f},
                            {0.f, 0.f, 0.f, 0.f}, {0.f, 0.f, 0.f, 0.f}};
#pragma unroll
            for (int ks = 0; ks < 4; ks++) {
#pragma unroll
                for (int rt = 0; rt < 4; rt++)
                    acc[rt] = __builtin_amdgcn_mfma_f32_16x16x32_bf16(acur[ks], bx[rt][ks], acc[rt], 0, 0, 0);
            }
            int j0 = jtile * 16 + lk * 4;
            float4 bias = *(const float4*)(b1f + j0);
#pragma unroll
            for (int rt = 0; rt < 4; rt++) {
                int rr = rt * 16 + lr;
                short4_ hv;
                hv.x = f2bf(fmaxf(acc[rt][0] + bias.x, 0.f));
                hv.y = f2bf(fmaxf(acc[rt][1] + bias.y, 0.f));
                hv.z = f2bf(fmaxf(acc[rt][2] + bias.z, 0.f));
                hv.w = f2bf(fmaxf(acc[rt][3] + bias.w, 0.f));
                *(short4_*)&hbf[(rr * FF + j0) ^ swz] = hv;
            }
        }
    }
    __syncthreads();
    f32x4 acc2[4] = {{0.f, 0.f, 0.f, 0.f}, {0.f, 0.f, 0.f, 0.f},
                     {0.f, 0.f, 0.f, 0.f}, {0.f, 0.f, 0.f, 0.f}};
    int ctile = w;
#pragma unroll 4
    for (int ks = 0; ks < 16; ks++) {
        short8 aw = *(const short8*)(w2f + ((size_t)(ctile * 16 + ks)) * 512 + l * 8);
#pragma unroll
        for (int rt = 0; rt < 4; rt++) {
            short8 hx = *(const short8*)&hbf[((rt * 16 + lr) * FF + ks * 32 + lk * 8) ^ swz];
            acc2[rt] = __builtin_amdgcn_mfma_f32_16x16x32_bf16(aw, hx, acc2[rt], 0, 0, 0);
        }
    }
    int cc = ctile * 16 + lk * 4;
    float4 bias2 = *(const float4*)(b2f + cc);
    float4 res[4];
#pragma unroll
    for (int rt = 0; rt < 4; rt++)
        res[rt] = *(const float4*)(x1 + (size_t)(r0 + rt * 16 + lr) * C_ + cc);
    __syncthreads();    // all hbf reads done -> safe to overwrite with y
#pragma unroll
    for (int rt = 0; rt < 4; rt++) {
        float4 o;
        o.x = acc2[rt][0] + bias2.x + res[rt].x;
        o.y = acc2[rt][1] + bias2.y + res[rt].y;
        o.z = acc2[rt][2] + bias2.z + res[rt].z;
        o.w = acc2[rt][3] + bias2.w + res[rt].w;
        *(float4*)&yf[rt * 16 + lr][cc] = o;
    }
    __syncthreads();
    {
        int r = tid >> 3;                   // 0..63
        int q = tid & 7;
        int cb = q * 16;
        float vals[16];
        float s = 0.f;
#pragma unroll
        for (int i = 0; i < 16; i++) { vals[i] = yf[r][cb + i]; s += vals[i]; }
        s += __shfl_xor(s, 1, 8);
        s += __shfl_xor(s, 2, 8);
        s += __shfl_xor(s, 4, 8);
        float mean = s * (1.f / C_);
        float vv = 0.f;
#pragma unroll
        for (int i = 0; i < 16; i++) { float d = vals[i] - mean; vv += d * d; }
        vv += __shfl_xor(vv, 1, 8);
        vv += __shfl_xor(vv, 2, 8);
        vv += __shfl_xor(vv, 4, 8);
        float rstd = rsqrtf(vv * (1.f / C_) + 1e-5f);
        float* op = out + (size_t)(r0 + r) * C_ + cb;
#pragma unroll
        for (int i4 = 0; i4 < 4; i4++) {
            float4 gv = *(const float4*)(g2 + cb + 4 * i4);
            float4 bv = *(const float4*)(b2ln + cb + 4 * i4);
            float4 ov;
            ov.x = (vals[4 * i4 + 0] - mean) * rstd * gv.x + bv.x;
            ov.y = (vals[4 * i4 + 1] - mean) * rstd * gv.y + bv.y;
            ov.z = (vals[4 * i4 + 2] - mean) * rstd * gv.z + bv.z;
            ov.w = (vals[4 * i4 + 3] - mean) * rstd * gv.w + bv.w;
            *(float4*)(op + 4 * i4) = ov;
        }
    }
}

extern "C" void kernel_launch(void* const* d_in, const int* in_sizes, int n_in,
                              void* d_out, int out_size, void* d_ws, size_t ws_size,
                              hipStream_t stream) {
    const float* query = (const float*)d_in[2];
    const int* time_enc = (const int*)d_in[4];
    const int* index_sample = (const int*)d_in[5];
    const float* e_min = (const float*)d_in[6];
    const float* e_hr  = (const float*)d_in[7];
    const float* e_wd  = (const float*)d_in[8];
    const float* e_mo  = (const float*)d_in[9];
    const float* e_yr  = (const float*)d_in[10];
    const float* Wq = (const float*)d_in[11];
    const float* Wk = (const float*)d_in[12];
    const float* Wv = (const float*)d_in[13];
    const float* Wo = (const float*)d_in[14];
    const float* bo = (const float*)d_in[15];
    const float* ffw1 = (const float*)d_in[16];
    const float* ffb1 = (const float*)d_in[17];
    const float* ffw2 = (const float*)d_in[18];
    const float* ffb2 = (const float*)d_in[19];
    const float* ln1g = (const float*)d_in[20];
    const float* ln1b = (const float*)d_in[21];
    const float* ln2g = (const float*)d_in[22];
    const float* ln2b = (const float*)d_in[23];

    float* ws = (float*)d_ws;
    float* tepe = ws;                     // TEPE_N floats
    float* region1 = ws + TEPE_N;         // NX floats: bf16 Q, then x1 (f32)
    float* region2 = region1 + NX;        // NX floats: bf16 K, then w1f/w2f/wof
    float* region3 = region2 + NX;        // NX floats: bf16 V
    float* region4 = region3 + NX;        // NX floats: xbf+wqkvf, then bf16 ctx

    short* Qb = (short*)region1;
    short* Kb = (short*)region2;
    short* Vb = (short*)region3;
    short* ctxb = (short*)region4;
    float* x1 = region1;

    short* xbf = (short*)region4;               // NX shorts (dead after qkv)
    short* wqkvf = (short*)region4 + NX;        // 49152 shorts (dead after qkv)
    short* w1f = (short*)region2;               // 65536 shorts (K dead after attn)
    short* w2f = w1f + C_ * FF;                 // 65536 shorts
    short* wof = w2f + C_ * FF;                 // 16384 shorts

    k_tepe<<<dim3(TEPE_N / 256), dim3(256), 0, stream>>>(
        time_enc, e_min, e_hr, e_wd, e_mo, e_yr, tepe);
    k_xprep<<<dim3(NX / 4 / 256), dim3(256), 0, stream>>>(query, tepe, xbf);
    k_wcvt_qkv<<<dim3(384 * C_ / 256), dim3(256), 0, stream>>>(Wq, Wk, Wv, wqkvf);
    k_qkv_mfma<<<dim3(NBLK_MM), dim3(256), 0, stream>>>(xbf, wqkvf, Qb, Kb, Vb);
    k_attn<<<dim3(B_ * H_ * N_), dim3(64), 0, stream>>>(
        Qb, Kb, Vb, index_sample, ctxb);
    k_wcvt2<<<dim3((2 * C_ * FF + C_ * C_) / 256), dim3(256), 0, stream>>>(
        ffw1, ffw2, Wo, w1f, w2f, wof);
    k_out_ln_mfma<<<dim3(NBLK_MM), dim3(256), 0, stream>>>(
        ctxb, wof, bo, query, tepe, ln1g, ln1b, x1);
    k_ff_mfma<<<dim3(NBLK_FF), dim3(512), 0, stream>>>(
        x1, w1f, ffb1, w2f, ffb2, ln2g, ln2b, (float*)d_out);
}

// Round 9
// 199.627 us; speedup vs baseline: 3.0304x; 1.1234x over previous
//
#include <hip/hip_runtime.h>
#include <hip/hip_bf16.h>
#include <cmath>

namespace {
constexpr int B_ = 16, N_ = 307, T_ = 24, C_ = 128, H_ = 8, D_ = 16, S_ = 20, U_ = 20;
constexpr int NROW = B_ * N_ * T_;          // 117888
constexpr int NX = NROW * C_;               // 15089664
constexpr int TEPE_N = B_ * T_ * C_;        // 49152
constexpr int FF = 4 * C_;                  // 512
constexpr int BM = 32;                      // rows per MFMA block (qkv/out_ln)
constexpr int NBLK_MM = NROW / BM;          // 3684
constexpr int BMF = 64;                     // rows per FF block
constexpr int NBLK_FF = NROW / BMF;         // 1842
constexpr int NUNIT = B_ * H_ * N_;         // 39296
}

typedef __attribute__((ext_vector_type(8))) short short8;
typedef __attribute__((ext_vector_type(4))) short short4_;
typedef __attribute__((ext_vector_type(4))) float f32x4;

__device__ inline short f2bf(float v) {
    union { float f; unsigned u; } a; a.f = v;
    unsigned r = a.u + 0x7fff + ((a.u >> 16) & 1);   // round-to-nearest-even
    return (short)(r >> 16);
}
__device__ inline float bf2f(short s) {
    return __bfloat162float(*(const __hip_bfloat16*)&s);
}

// ---------------- kernel 0: tepe + (block 0) global sample-count table
__global__ void k_tepe(const int* __restrict__ te,
                       const float* __restrict__ e_min, const float* __restrict__ e_hr,
                       const float* __restrict__ e_wd, const float* __restrict__ e_mo,
                       const float* __restrict__ e_yr, float* __restrict__ tepe,
                       const int* __restrict__ idxs, unsigned char* __restrict__ cntg) {
    int i = blockIdx.x * blockDim.x + threadIdx.x;
    if (i < TEPE_N) {
        int c = i & (C_ - 1);
        int bt = i >> 7;              // b*T + t
        int t = bt % T_;
        const int* enc = te + bt * 5;
        float v = e_min[enc[0] * C_ + c] + e_hr[enc[1] * C_ + c] + e_wd[enc[2] * C_ + c]
                + e_mo[enc[3] * C_ + c] + e_yr[enc[4] * C_ + c];
        float ang = (float)t * expf(-(float)(c & ~1) * (9.210340371976184f / 128.0f));
        v += (c & 1) ? cosf(ang) : sinf(ang);
        tepe[i] = v;
    }
    if (blockIdx.x == 0) {      // build cnt[24][32] once (shared by all attn blocks)
        __shared__ int scnt[T_ * 32];
        for (int j = threadIdx.x; j < T_ * 32; j += 256) scnt[j] = 0;
        __syncthreads();
        for (int j = threadIdx.x; j < T_ * S_; j += 256) {
            int t = j / S_;
            atomicAdd(&scnt[t * 32 + idxs[j]], 1);
        }
        __syncthreads();
        for (int j = threadIdx.x; j < 192; j += 256) {
            unsigned v = (unsigned)scnt[4 * j] | ((unsigned)scnt[4 * j + 1] << 8)
                       | ((unsigned)scnt[4 * j + 2] << 16) | ((unsigned)scnt[4 * j + 3] << 24);
            ((unsigned*)cntg)[j] = v;
        }
    }
}

// ---------------- kernel 0b: xbf = bf16(query + tepe)
__global__ void k_xprep(const float* __restrict__ query, const float* __restrict__ tepe,
                        short* __restrict__ xbf) {
    int i = blockIdx.x * 256 + threadIdx.x;     // i indexes float4s; NX/4 total
    int c4 = i & 31;
    int gr = i >> 5;
    int t = gr % T_;
    int b = gr / (N_ * T_);
    float4 q = *(const float4*)(query + 4 * (size_t)i);
    float4 p = *(const float4*)(tepe + (size_t)(b * T_ + t) * C_ + c4 * 4);
    short4_ s;
    s.x = f2bf(q.x + p.x); s.y = f2bf(q.y + p.y);
    s.z = f2bf(q.z + p.z); s.w = f2bf(q.w + p.w);
    *(short4_*)&xbf[4 * (size_t)i] = s;
}

// ---------------- weight converts: FRAGMENT-LINEAR layout (see round 4 notes).
__global__ void k_wcvt_qkv(const float* __restrict__ Wq, const float* __restrict__ Wk,
                           const float* __restrict__ Wv, short* __restrict__ wqkvf) {
    int i = blockIdx.x * 256 + threadIdx.x;     // 49152
    int tile = i >> 9, l = (i >> 3) & 63, e = i & 7;
    int c_tile = tile >> 2, ks = tile & 3;
    int c_all = c_tile * 16 + (l & 15);
    int k = ks * 32 + (l >> 4) * 8 + e;
    int m = c_all >> 7, c = c_all & (C_ - 1);
    const float* W = (m == 0) ? Wq : (m == 1) ? Wk : Wv;
    wqkvf[i] = f2bf(W[k * C_ + c]);
}

__global__ void k_wcvt2(const float* __restrict__ w1, const float* __restrict__ w2,
                        const float* __restrict__ Wo,
                        short* __restrict__ w1f, short* __restrict__ w2f,
                        short* __restrict__ wof) {
    int i = blockIdx.x * 256 + threadIdx.x;     // 147456
    if (i < C_ * FF) {
        int tile = i >> 9, l = (i >> 3) & 63, e = i & 7;
        int jtile = tile >> 2, ks = tile & 3;
        int j = jtile * 16 + (l & 15);
        int k = ks * 32 + (l >> 4) * 8 + e;
        w1f[i] = f2bf(w1[k * FF + j]);          // w1 is [C][FF] = [k][j]
    } else if (i < 2 * C_ * FF) {
        int i2 = i - C_ * FF;
        int tile = i2 >> 9, l = (i2 >> 3) & 63, e = i2 & 7;
        int c_tile = tile >> 4, ks = tile & 15;
        int c = c_tile * 16 + (l & 15);
        int j = ks * 32 + (l >> 4) * 8 + e;
        w2f[i2] = f2bf(w2[j * C_ + c]);         // w2 is [FF][C] = [j][c]
    } else {
        int i3 = i - 2 * C_ * FF;
        int tile = i3 >> 9, l = (i3 >> 3) & 63, e = i3 & 7;
        int c_tile = tile >> 2, ks = tile & 3;
        int c = c_tile * 16 + (l & 15);
        int k = ks * 32 + (l >> 4) * 8 + e;
        wof[i3] = f2bf(Wo[k * C_ + c]);         // Wo is [C][C] = [k][c]
    }
}

// ---------------- kernel 1: QKV projection via MFMA -> bf16 Q/K/V
__global__ __launch_bounds__(256) void k_qkv_mfma(
    const short* __restrict__ xbf, const short* __restrict__ wqkvf,
    short* __restrict__ Q, short* __restrict__ K, short* __restrict__ V) {
    __shared__ __align__(16) short xs[BM * C_];
    int tid = threadIdx.x;
    int r0 = blockIdx.x * BM;
    {
        int row = tid >> 3;                 // 0..31
        int cb = (tid & 7) * 16;
        const short* src = xbf + (size_t)(r0 + row) * C_ + cb;
        short8 v0 = *(const short8*)(src);
        short8 v1 = *(const short8*)(src + 8);
        *(short8*)&xs[(row * C_ + cb) ^ ((row & 7) << 3)] = v0;
        *(short8*)&xs[(row * C_ + cb + 8) ^ ((row & 7) << 3)] = v1;
    }
    __syncthreads();
    int w = tid >> 6, l = tid & 63;
    int lr = l & 15, lk = l >> 4;
    int swz = (lr & 7) << 3;                // row-tile-invariant swizzle
    short8 bx[2][4];
#pragma unroll
    for (int rt = 0; rt < 2; rt++)
#pragma unroll
        for (int ks = 0; ks < 4; ks++)
            bx[rt][ks] = *(const short8*)&xs[((rt * 16 + lr) * C_ + ks * 32 + lk * 8) ^ swz];
    size_t base[2];
#pragma unroll
    for (int rt = 0; rt < 2; rt++) {
        int gr = r0 + rt * 16 + lr;
        int t = gr % T_;
        int n = (gr / T_) % N_;
        int b = gr / (N_ * T_);
        base[rt] = ((size_t)b * H_ * N_ + n) * (T_ * D_) + t * D_;
    }
#pragma unroll
    for (int jt = 0; jt < 6; jt++) {
        int ctile = w * 6 + jt;                 // c-tile index 0..23
        const short* ap = wqkvf + (size_t)ctile * 2048 + l * 8;
        short8 acur[4];
#pragma unroll
        for (int ks = 0; ks < 4; ks++) acur[ks] = *(const short8*)(ap + ks * 512);
        f32x4 acc[2] = {{0.f, 0.f, 0.f, 0.f}, {0.f, 0.f, 0.f, 0.f}};
#pragma unroll
        for (int ks = 0; ks < 4; ks++) {
#pragma unroll
            for (int rt = 0; rt < 2; rt++)
                acc[rt] = __builtin_amdgcn_mfma_f32_16x16x32_bf16(acur[ks], bx[rt][ks], acc[rt], 0, 0, 0);
        }
        int c0 = ctile * 16 + lk * 4;
        int m = c0 >> 7;
        int c = c0 & (C_ - 1);
        int h = c >> 4, d = c & 15;
        short* dst = (m == 0) ? Q : (m == 1) ? K : V;
#pragma unroll
        for (int rt = 0; rt < 2; rt++) {
            short4_ sv;
            sv.x = f2bf(acc[rt][0]); sv.y = f2bf(acc[rt][1]);
            sv.z = f2bf(acc[rt][2]); sv.w = f2bf(acc[rt][3]);
            *(short4_*)&dst[base[rt] + (size_t)h * (N_ * T_ * D_) + d] = sv;
        }
    }
}

// ---------------- kernel 2: attention, 4 units per 256-thread block (1 wave/unit)
__global__ __launch_bounds__(256) void k_attn(
    const short* __restrict__ Q, const short* __restrict__ K, const short* __restrict__ V,
    const unsigned char* __restrict__ cntg, short* __restrict__ ctx) {
    __shared__ __align__(16) short Qbf[4][32 * 24], Kbf[4][32 * 24];
    __shared__ __align__(16) short Vt[4][16 * 40];       // [d][t2], cols 24-31 zeroed
    __shared__ __align__(16) short Pbf[4][32 * 40];      // attn weights, cols 24-31 zeroed
    __shared__ unsigned char cntS[T_ * 32];              // shared by all 4 units
    __shared__ float Mv[4][T_];
    __shared__ int keepS[4][T_];
    __shared__ float meanVs[4][D_];
    int tid = threadIdx.x;
    int wid = tid >> 6, l = tid & 63;
    int e = blockIdx.x * 4 + wid;
    const short* qb = Q + (size_t)e * (T_ * D_);
    const short* kb = K + (size_t)e * (T_ * D_);
    const short* vb = V + (size_t)e * (T_ * D_);
    // ---- stage Q,K rows; V transposed; cnt table
    if (l < 48) {
        int t = l >> 1, hf = l & 1;
        *(short8*)&Qbf[wid][t * 24 + hf * 8] = *(const short8*)(qb + t * 16 + hf * 8);
        *(short8*)&Kbf[wid][t * 24 + hf * 8] = *(const short8*)(kb + t * 16 + hf * 8);
    }
    for (int i = l; i < 96; i += 64) {
        int t = i >> 2, c4 = i & 3;
        short4_ v = *(const short4_*)(vb + t * 16 + c4 * 4);
        Vt[wid][(c4 * 4 + 0) * 40 + t] = v.x;
        Vt[wid][(c4 * 4 + 1) * 40 + t] = v.y;
        Vt[wid][(c4 * 4 + 2) * 40 + t] = v.z;
        Vt[wid][(c4 * 4 + 3) * 40 + t] = v.w;
    }
    for (int i = l; i < 128; i += 64) {       // zero Vt cols 24-31
        int d = i >> 3, c = 24 + (i & 7);
        Vt[wid][d * 40 + c] = 0;
    }
    if (tid < 192) ((int*)cntS)[tid] = ((const int*)cntg)[tid];
    __syncthreads();
    // ---- meanV (lanes 48-63 of each wave)
    if (l >= 48) {
        int d = l - 48;
        float s = 0.f;
        for (int t = 0; t < T_; t++) s += bf2f(Vt[wid][d * 40 + t]);
        meanVs[wid][d] = s * (1.0f / T_);
    }
    // ---- scores via MFMA: sc[t][t2], A = K rows (t2), B = Q rows (t)
    int lr = l & 15, lk = l >> 4;
    short8 zz = {};
    short8 kf0 = zz, kf1 = zz, qf0 = zz, qf1 = zz;
    if (lk < 2) {
        kf0 = *(const short8*)&Kbf[wid][lr * 24 + lk * 8];
        kf1 = *(const short8*)&Kbf[wid][(16 + lr) * 24 + lk * 8];
        qf0 = *(const short8*)&Qbf[wid][lr * 24 + lk * 8];
        qf1 = *(const short8*)&Qbf[wid][(16 + lr) * 24 + lk * 8];
    }
    f32x4 zf = {0.f, 0.f, 0.f, 0.f};
    f32x4 s00 = __builtin_amdgcn_mfma_f32_16x16x32_bf16(kf0, qf0, zf, 0, 0, 0);
    f32x4 s01 = __builtin_amdgcn_mfma_f32_16x16x32_bf16(kf1, qf0, zf, 0, 0, 0);
    f32x4 s10 = __builtin_amdgcn_mfma_f32_16x16x32_bf16(kf0, qf1, zf, 0, 0, 0);
    f32x4 s11 = __builtin_amdgcn_mfma_f32_16x16x32_bf16(kf1, qf1, zf, 0, 0, 0);
    // ---- M[t] = max(sampled) - sum(sampled)/S from the score registers
#pragma unroll
    for (int rt = 0; rt < 2; rt++) {
        int t = rt * 16 + lr;
        int tt = (t < T_) ? t : 0;
        f32x4 c0 = rt ? s10 : s00;
        f32x4 c1 = rt ? s11 : s01;
        float mx = -1e30f, sm = 0.f;
#pragma unroll
        for (int i = 0; i < 4; i++) {
            int cA = cntS[tt * 32 + lk * 4 + i];
            if (cA) { mx = fmaxf(mx, c0[i]); sm += (float)cA * c0[i]; }
        }
        if (lk < 2) {
#pragma unroll
            for (int i = 0; i < 4; i++) {
                int cB = cntS[tt * 32 + 16 + lk * 4 + i];
                if (cB) { mx = fmaxf(mx, c1[i]); sm += (float)cB * c1[i]; }
            }
        }
        mx = fmaxf(mx, __shfl_xor(mx, 16));
        mx = fmaxf(mx, __shfl_xor(mx, 32));
        sm += __shfl_xor(sm, 16);
        sm += __shfl_xor(sm, 32);
        if (lk == 0 && t < T_) Mv[wid][t] = mx - sm * (1.0f / S_);
    }
    __syncthreads();
    // ---- keep mask (top-U as a set, tie-break lower index)
    if (l < T_) {
        float mt = Mv[wid][l];
        int cnt2 = 0;
        for (int t2 = 0; t2 < T_; t2++) {
            float m2 = Mv[wid][t2];
            cnt2 += (m2 > mt) || (m2 == mt && t2 < l);
        }
        keepS[wid][l] = (cnt2 < U_) ? 1 : 0;
    }
    // ---- softmax in registers
#pragma unroll
    for (int rt = 0; rt < 2; rt++) {
        f32x4 c0 = rt ? s10 : s00;
        f32x4 c1 = rt ? s11 : s01;
        float lm = fmaxf(fmaxf(c0[0], c0[1]), fmaxf(c0[2], c0[3]));
        if (lk < 2) lm = fmaxf(lm, fmaxf(fmaxf(c1[0], c1[1]), fmaxf(c1[2], c1[3])));
        lm = fmaxf(lm, __shfl_xor(lm, 16));
        lm = fmaxf(lm, __shfl_xor(lm, 32));
        float e0[4], e1[4];
        float ls = 0.f;
#pragma unroll
        for (int i = 0; i < 4; i++) { e0[i] = __expf(0.25f * (c0[i] - lm)); ls += e0[i]; }
#pragma unroll
        for (int i = 0; i < 4; i++) { e1[i] = (lk < 2) ? __expf(0.25f * (c1[i] - lm)) : 0.f; ls += e1[i]; }
        ls += __shfl_xor(ls, 16);
        ls += __shfl_xor(ls, 32);
        float inv = 1.0f / ls;
        short4_ w0, w1;
        w0.x = f2bf(e0[0] * inv); w0.y = f2bf(e0[1] * inv);
        w0.z = f2bf(e0[2] * inv); w0.w = f2bf(e0[3] * inv);
        w1.x = f2bf(e1[0] * inv); w1.y = f2bf(e1[1] * inv);
        w1.z = f2bf(e1[2] * inv); w1.w = f2bf(e1[3] * inv);
        int trow = rt * 16 + lr;
        *(short4_*)&Pbf[wid][trow * 40 + lk * 4] = w0;
        *(short4_*)&Pbf[wid][trow * 40 + 16 + lk * 4] = w1;   // lk>=2 writes zeros
    }
    __syncthreads();
    // ---- PV via MFMA: upd[t][d], A = Vt rows (d), B = attn rows (t), K = 32
    short8 vf = *(const short8*)&Vt[wid][lr * 40 + lk * 8];
    short8 pf0 = *(const short8*)&Pbf[wid][lr * 40 + lk * 8];
    short8 pf1 = *(const short8*)&Pbf[wid][(16 + lr) * 40 + lk * 8];
    f32x4 u0 = __builtin_amdgcn_mfma_f32_16x16x32_bf16(vf, pf0, zf, 0, 0, 0);
    f32x4 u1 = __builtin_amdgcn_mfma_f32_16x16x32_bf16(vf, pf1, zf, 0, 0, 0);
    // ---- store bf16 ctx
    int b = e / (H_ * N_);
    int h = (e / N_) % H_;
    int n = e % N_;
    float4 mv4 = *(const float4*)&meanVs[wid][lk * 4];
#pragma unroll
    for (int rt = 0; rt < 2; rt++) {
        int t = rt * 16 + lr;
        if (t < T_) {
            f32x4 u = rt ? u1 : u0;
            float4 o;
            if (keepS[wid][t]) { o.x = u[0]; o.y = u[1]; o.z = u[2]; o.w = u[3]; }
            else o = mv4;
            short4_ sv;
            sv.x = f2bf(o.x); sv.y = f2bf(o.y); sv.z = f2bf(o.z); sv.w = f2bf(o.w);
            *(short4_*)&ctx[((size_t)(b * N_ + n) * T_ + t) * C_ + h * D_ + lk * 4] = sv;
        }
    }
}

// ---------------- kernel 3: att_out = ctx@Wo + bo (MFMA); y = att_out + x; x1 = LN1(y)
__global__ __launch_bounds__(256) void k_out_ln_mfma(
    const short* __restrict__ ctx, const short* __restrict__ wof, const float* __restrict__ bo,
    const float* __restrict__ query, const float* __restrict__ tepe,
    const float* __restrict__ g1, const float* __restrict__ b1,
    float* __restrict__ x1) {
    __shared__ __align__(16) short cbf[BM * C_];
    __shared__ __align__(16) float xf[BM][132];
    int tid = threadIdx.x;
    int r0 = blockIdx.x * BM;
    {
        int row = tid >> 3;
        int cb = (tid & 7) * 16;
        int gr = r0 + row;
        int t = gr % T_;
        int b = gr / (N_ * T_);
        const short* src = ctx + (size_t)gr * C_ + cb;
        const float* qsrc = query + (size_t)gr * C_ + cb;
        const float* tsrc = tepe + (size_t)(b * T_ + t) * C_ + cb;
        short8 v0 = *(const short8*)(src);
        short8 v1 = *(const short8*)(src + 8);
        int swz0 = (row & 7) << 3;
        *(short8*)&cbf[(row * C_ + cb) ^ swz0] = v0;
        *(short8*)&cbf[(row * C_ + cb + 8) ^ swz0] = v1;
#pragma unroll
        for (int i = 0; i < 4; i++) {
            float4 q4 = *(const float4*)(qsrc + 4 * i);
            float4 t4 = *(const float4*)(tsrc + 4 * i);
            float4 xr;
            xr.x = q4.x + t4.x; xr.y = q4.y + t4.y;
            xr.z = q4.z + t4.z; xr.w = q4.w + t4.w;
            *(float4*)&xf[row][cb + 4 * i] = xr;
        }
    }
    __syncthreads();
    int w = tid >> 6, l = tid & 63;
    int lr = l & 15, lk = l >> 4;
    int swz = (lr & 7) << 3;
    short8 bc[2][4];
#pragma unroll
    for (int rt = 0; rt < 2; rt++)
#pragma unroll
        for (int ks = 0; ks < 4; ks++)
            bc[rt][ks] = *(const short8*)&cbf[((rt * 16 + lr) * C_ + ks * 32 + lk * 8) ^ swz];
#pragma unroll
    for (int ct = 0; ct < 2; ct++) {
        int c_tile = w * 2 + ct;                // 0..7
        const short* ap = wof + (size_t)c_tile * 2048 + l * 8;
        short8 acur[4];
#pragma unroll
        for (int ks = 0; ks < 4; ks++) acur[ks] = *(const short8*)(ap + ks * 512);
        f32x4 acc[2] = {{0.f, 0.f, 0.f, 0.f}, {0.f, 0.f, 0.f, 0.f}};
#pragma unroll
        for (int ks = 0; ks < 4; ks++) {
#pragma unroll
            for (int rt = 0; rt < 2; rt++)
                acc[rt] = __builtin_amdgcn_mfma_f32_16x16x32_bf16(acur[ks], bc[rt][ks], acc[rt], 0, 0, 0);
        }
        int cc = c_tile * 16 + lk * 4;
        float4 bias = *(const float4*)(bo + cc);
#pragma unroll
        for (int rt = 0; rt < 2; rt++) {
            int rrow = rt * 16 + lr;
            float4 res = *(const float4*)&xf[rrow][cc];
            float4 o;
            o.x = acc[rt][0] + bias.x + res.x;
            o.y = acc[rt][1] + bias.y + res.y;
            o.z = acc[rt][2] + bias.z + res.z;
            o.w = acc[rt][3] + bias.w + res.w;
            *(float4*)&xf[rrow][cc] = o;
        }
    }
    __syncthreads();
    {
        int r = tid >> 3;
        int q = tid & 7;
        int cb = q * 16;
        float vals[16];
        float s = 0.f;
#pragma unroll
        for (int i = 0; i < 16; i++) { vals[i] = xf[r][cb + i]; s += vals[i]; }
        s += __shfl_xor(s, 1, 8);
        s += __shfl_xor(s, 2, 8);
        s += __shfl_xor(s, 4, 8);
        float mean = s * (1.f / C_);
        float vv = 0.f;
#pragma unroll
        for (int i = 0; i < 16; i++) { float d = vals[i] - mean; vv += d * d; }
        vv += __shfl_xor(vv, 1, 8);
        vv += __shfl_xor(vv, 2, 8);
        vv += __shfl_xor(vv, 4, 8);
        float rstd = rsqrtf(vv * (1.f / C_) + 1e-5f);
        float* op = x1 + (size_t)(r0 + r) * C_ + cb;
#pragma unroll
        for (int i4 = 0; i4 < 4; i4++) {
            float4 gv = *(const float4*)(g1 + cb + 4 * i4);
            float4 bv = *(const float4*)(b1 + cb + 4 * i4);
            float4 ov;
            ov.x = (vals[4 * i4 + 0] - mean) * rstd * gv.x + bv.x;
            ov.y = (vals[4 * i4 + 1] - mean) * rstd * gv.y + bv.y;
            ov.z = (vals[4 * i4 + 2] - mean) * rstd * gv.z + bv.z;
            ov.w = (vals[4 * i4 + 3] - mean) * rstd * gv.w + bv.w;
            *(float4*)(op + 4 * i4) = ov;
        }
    }
}

// ---------------- kernel 4: FF via bf16 MFMA + residual + LN2 -> out
__global__ __launch_bounds__(512, 4) void k_ff_mfma(
    const float* __restrict__ x1, const short* __restrict__ w1f, const float* __restrict__ b1f,
    const short* __restrict__ w2f, const float* __restrict__ b2f,
    const float* __restrict__ g2, const float* __restrict__ b2ln,
    float* __restrict__ out) {
    __shared__ __align__(16) short xbf[BMF * C_];    // 16 KB, bf16 x, swizzled
    __shared__ __align__(16) short hbf[BMF * FF];    // 64 KB, bf16 hidden, swizzled
    float (*yf)[132] = (float(*)[132])hbf;           // f32 y aliases hbf (33 KB)
    int tid = threadIdx.x;
    int r0 = blockIdx.x * BMF;
    {
        int row = tid >> 3;                 // 0..63
        int cb = (tid & 7) * 16;
        const float* src = x1 + (size_t)(r0 + row) * C_ + cb;
#pragma unroll
        for (int i = 0; i < 4; i++) {
            float4 v = *(const float4*)(src + 4 * i);
            short4_ sv;
            sv.x = f2bf(v.x); sv.y = f2bf(v.y); sv.z = f2bf(v.z); sv.w = f2bf(v.w);
            *(short4_*)&xbf[(row * C_ + cb + 4 * i) ^ ((row & 7) << 3)] = sv;
        }
    }
    __syncthreads();
    int w = tid >> 6, l = tid & 63;
    int lr = l & 15, lk = l >> 4;           // lk in 0..3
    int swz = (lr & 7) << 3;                // row-tile-invariant swizzle
    {
        short8 bx[4][4];
#pragma unroll
        for (int rt = 0; rt < 4; rt++)
#pragma unroll
            for (int ks = 0; ks < 4; ks++)
                bx[rt][ks] = *(const short8*)&xbf[((rt * 16 + lr) * C_ + ks * 32 + lk * 8) ^ swz];
#pragma unroll
        for (int jt = 0; jt < 4; jt++) {
            int jtile = w * 4 + jt;             // 0..31
            const short* ap = w1f + (size_t)jtile * 2048 + l * 8;
            short8 acur[4];
#pragma unroll
            for (int ks = 0; ks < 4; ks++) acur[ks] = *(const short8*)(ap + ks * 512);
            f32x4 acc[4] = {{0.f, 0.f, 0.f, 0.f}, {0.f, 0.f, 0.f, 0.f},
                            {0.f, 0.f, 0.f, 0.f}, {0.f, 0.f, 0.f, 0.f}};
#pragma unroll
            for (int ks = 0; ks < 4; ks++) {
#pragma unroll
                for (int rt = 0; rt < 4; rt++)
                    acc[rt] = __builtin_amdgcn_mfma_f32_16x16x32_bf16(acur[ks], bx[rt][ks], acc[rt], 0, 0, 0);
            }
            int j0 = jtile * 16 + lk * 4;
            float4 bias = *(const float4*)(b1f + j0);
#pragma unroll
            for (int rt = 0; rt < 4; rt++) {
                int rr = rt * 16 + lr;
                short4_ hv;
                hv.x = f2bf(fmaxf(acc[rt][0] + bias.x, 0.f));
                hv.y = f2bf(fmaxf(acc[rt][1] + bias.y, 0.f));
                hv.z = f2bf(fmaxf(acc[rt][2] + bias.z, 0.f));
                hv.w = f2bf(fmaxf(acc[rt][3] + bias.w, 0.f));
                *(short4_*)&hbf[(rr * FF + j0) ^ swz] = hv;
            }
        }
    }
    __syncthreads();
    f32x4 acc2[4] = {{0.f, 0.f, 0.f, 0.f}, {0.f, 0.f, 0.f, 0.f},
                     {0.f, 0.f, 0.f, 0.f}, {0.f, 0.f, 0.f, 0.f}};
    int ctile = w;
#pragma unroll 4
    for (int ks = 0; ks < 16; ks++) {
        short8 aw = *(const short8*)(w2f + ((size_t)(ctile * 16 + ks)) * 512 + l * 8);
#pragma unroll
        for (int rt = 0; rt < 4; rt++) {
            short8 hx = *(const short8*)&hbf[((rt * 16 + lr) * FF + ks * 32 + lk * 8) ^ swz];
            acc2[rt] = __builtin_amdgcn_mfma_f32_16x16x32_bf16(aw, hx, acc2[rt], 0, 0, 0);
        }
    }
    int cc = ctile * 16 + lk * 4;
    float4 bias2 = *(const float4*)(b2f + cc);
    float4 res[4];
#pragma unroll
    for (int rt = 0; rt < 4; rt++)
        res[rt] = *(const float4*)(x1 + (size_t)(r0 + rt * 16 + lr) * C_ + cc);
    __syncthreads();    // all hbf reads done -> safe to overwrite with y
#pragma unroll
    for (int rt = 0; rt < 4; rt++) {
        float4 o;
        o.x = acc2[rt][0] + bias2.x + res[rt].x;
        o.y = acc2[rt][1] + bias2.y + res[rt].y;
        o.z = acc2[rt][2] + bias2.z + res[rt].z;
        o.w = acc2[rt][3] + bias2.w + res[rt].w;
        *(float4*)&yf[rt * 16 + lr][cc] = o;
    }
    __syncthreads();
    {
        int r = tid >> 3;                   // 0..63
        int q = tid & 7;
        int cb = q * 16;
        float vals[16];
        float s = 0.f;
#pragma unroll
        for (int i = 0; i < 16; i++) { vals[i] = yf[r][cb + i]; s += vals[i]; }
        s += __shfl_xor(s, 1, 8);
        s += __shfl_xor(s, 2, 8);
        s += __shfl_xor(s, 4, 8);
        float mean = s * (1.f / C_);
        float vv = 0.f;
#pragma unroll
        for (int i = 0; i < 16; i++) { float d = vals[i] - mean; vv += d * d; }
        vv += __shfl_xor(vv, 1, 8);
        vv += __shfl_xor(vv, 2, 8);
        vv += __shfl_xor(vv, 4, 8);
        float rstd = rsqrtf(vv * (1.f / C_) + 1e-5f);
        float* op = out + (size_t)(r0 + r) * C_ + cb;
#pragma unroll
        for (int i4 = 0; i4 < 4; i4++) {
            float4 gv = *(const float4*)(g2 + cb + 4 * i4);
            float4 bv = *(const float4*)(b2ln + cb + 4 * i4);
            float4 ov;
            ov.x = (vals[4 * i4 + 0] - mean) * rstd * gv.x + bv.x;
            ov.y = (vals[4 * i4 + 1] - mean) * rstd * gv.y + bv.y;
            ov.z = (vals[4 * i4 + 2] - mean) * rstd * gv.z + bv.z;
            ov.w = (vals[4 * i4 + 3] - mean) * rstd * gv.w + bv.w;
            *(float4*)(op + 4 * i4) = ov;
        }
    }
}

extern "C" void kernel_launch(void* const* d_in, const int* in_sizes, int n_in,
                              void* d_out, int out_size, void* d_ws, size_t ws_size,
                              hipStream_t stream) {
    const float* query = (const float*)d_in[2];
    const int* time_enc = (const int*)d_in[4];
    const int* index_sample = (const int*)d_in[5];
    const float* e_min = (const float*)d_in[6];
    const float* e_hr  = (const float*)d_in[7];
    const float* e_wd  = (const float*)d_in[8];
    const float* e_mo  = (const float*)d_in[9];
    const float* e_yr  = (const float*)d_in[10];
    const float* Wq = (const float*)d_in[11];
    const float* Wk = (const float*)d_in[12];
    const float* Wv = (const float*)d_in[13];
    const float* Wo = (const float*)d_in[14];
    const float* bo = (const float*)d_in[15];
    const float* ffw1 = (const float*)d_in[16];
    const float* ffb1 = (const float*)d_in[17];
    const float* ffw2 = (const float*)d_in[18];
    const float* ffb2 = (const float*)d_in[19];
    const float* ln1g = (const float*)d_in[20];
    const float* ln1b = (const float*)d_in[21];
    const float* ln2g = (const float*)d_in[22];
    const float* ln2b = (const float*)d_in[23];

    float* ws = (float*)d_ws;
    float* tepe = ws;                     // TEPE_N floats
    float* region1 = ws + TEPE_N;         // NX floats: bf16 Q, then x1 (f32)
    float* region2 = region1 + NX;        // NX floats: bf16 K, then w1f/w2f/wof
    float* region3 = region2 + NX;        // NX floats: bf16 V
    float* region4 = region3 + NX;        // NX floats: xbf+wqkvf+cnt, then bf16 ctx

    short* Qb = (short*)region1;
    short* Kb = (short*)region2;
    short* Vb = (short*)region3;
    short* ctxb = (short*)region4;
    float* x1 = region1;

    short* xbf = (short*)region4;               // NX shorts (dead after qkv)
    short* wqkvf = (short*)region4 + NX;        // 49152 shorts (dead after qkv)
    unsigned char* cntg = (unsigned char*)((short*)region4 + NX + 49152);  // 768 B
    short* w1f = (short*)region2;               // 65536 shorts (K dead after attn)
    short* w2f = w1f + C_ * FF;                 // 65536 shorts
    short* wof = w2f + C_ * FF;                 // 16384 shorts

    k_tepe<<<dim3(TEPE_N / 256), dim3(256), 0, stream>>>(
        time_enc, e_min, e_hr, e_wd, e_mo, e_yr, tepe, index_sample, cntg);
    k_xprep<<<dim3(NX / 4 / 256), dim3(256), 0, stream>>>(query, tepe, xbf);
    k_wcvt_qkv<<<dim3(384 * C_ / 256), dim3(256), 0, stream>>>(Wq, Wk, Wv, wqkvf);
    k_qkv_mfma<<<dim3(NBLK_MM), dim3(256), 0, stream>>>(xbf, wqkvf, Qb, Kb, Vb);
    k_attn<<<dim3(NUNIT / 4), dim3(256), 0, stream>>>(
        Qb, Kb, Vb, cntg, ctxb);
    k_wcvt2<<<dim3((2 * C_ * FF + C_ * C_) / 256), dim3(256), 0, stream>>>(
        ffw1, ffw2, Wo, w1f, w2f, wof);
    k_out_ln_mfma<<<dim3(NBLK_MM), dim3(256), 0, stream>>>(
        ctxb, wof, bo, query, tepe, ln1g, ln1b, x1);
    k_ff_mfma<<<dim3(NBLK_FF), dim3(512), 0, stream>>>(
        x1, w1f, ffb1, w2f, ffb2, ln2g, ln2b, (float*)d_out);
}

// Round 10
// 170.592 us; speedup vs baseline: 3.5462x; 1.1702x over previous
//
#include <hip/hip_runtime.h>
#include <hip/hip_bf16.h>
#include <cmath>

namespace {
constexpr int B_ = 16, N_ = 307, T_ = 24, C_ = 128, H_ = 8, D_ = 16, S_ = 20, U_ = 20;
constexpr int NROW = B_ * N_ * T_;          // 117888
constexpr int NX = NROW * C_;               // 15089664
constexpr int TEPE_N = B_ * T_ * C_;        // 49152
constexpr int FF = 4 * C_;                  // 512
constexpr int BM = 32;                      // rows per qkv block
constexpr int NBLK_MM = NROW / BM;          // 3684
constexpr int BMT = 64;                     // rows per tail block
constexpr int NBLK_T = NROW / BMT;          // 1842
constexpr int NUNIT = B_ * H_ * N_;         // 39296
}

typedef __attribute__((ext_vector_type(8))) short short8;
typedef __attribute__((ext_vector_type(4))) short short4_;
typedef __attribute__((ext_vector_type(4))) float f32x4;

__device__ inline short f2bf(float v) {
    union { float f; unsigned u; } a; a.f = v;
    unsigned r = a.u + 0x7fff + ((a.u >> 16) & 1);   // round-to-nearest-even
    return (short)(r >> 16);
}
__device__ inline float bf2f(short s) {
    return __bfloat162float(*(const __hip_bfloat16*)&s);
}

// ---------------- kernel 0: tepe + (block 0) global sample-count table
__global__ void k_tepe(const int* __restrict__ te,
                       const float* __restrict__ e_min, const float* __restrict__ e_hr,
                       const float* __restrict__ e_wd, const float* __restrict__ e_mo,
                       const float* __restrict__ e_yr, float* __restrict__ tepe,
                       const int* __restrict__ idxs, unsigned char* __restrict__ cntg) {
    int i = blockIdx.x * blockDim.x + threadIdx.x;
    if (i < TEPE_N) {
        int c = i & (C_ - 1);
        int bt = i >> 7;              // b*T + t
        int t = bt % T_;
        const int* enc = te + bt * 5;
        float v = e_min[enc[0] * C_ + c] + e_hr[enc[1] * C_ + c] + e_wd[enc[2] * C_ + c]
                + e_mo[enc[3] * C_ + c] + e_yr[enc[4] * C_ + c];
        float ang = (float)t * expf(-(float)(c & ~1) * (9.210340371976184f / 128.0f));
        v += (c & 1) ? cosf(ang) : sinf(ang);
        tepe[i] = v;
    }
    if (blockIdx.x == 0) {      // build cnt[24][32] once (shared by all attn blocks)
        __shared__ int scnt[T_ * 32];
        for (int j = threadIdx.x; j < T_ * 32; j += 256) scnt[j] = 0;
        __syncthreads();
        for (int j = threadIdx.x; j < T_ * S_; j += 256) {
            int t = j / S_;
            atomicAdd(&scnt[t * 32 + idxs[j]], 1);
        }
        __syncthreads();
        for (int j = threadIdx.x; j < 192; j += 256) {
            unsigned v = (unsigned)scnt[4 * j] | ((unsigned)scnt[4 * j + 1] << 8)
                       | ((unsigned)scnt[4 * j + 2] << 16) | ((unsigned)scnt[4 * j + 3] << 24);
            ((unsigned*)cntg)[j] = v;
        }
    }
}

// ---------------- weight converts: FRAGMENT-LINEAR layout (see round 4 notes).
__global__ void k_wcvt_qkv(const float* __restrict__ Wq, const float* __restrict__ Wk,
                           const float* __restrict__ Wv, short* __restrict__ wqkvf) {
    int i = blockIdx.x * 256 + threadIdx.x;     // 49152
    int tile = i >> 9, l = (i >> 3) & 63, e = i & 7;
    int c_tile = tile >> 2, ks = tile & 3;
    int c_all = c_tile * 16 + (l & 15);
    int k = ks * 32 + (l >> 4) * 8 + e;
    int m = c_all >> 7, c = c_all & (C_ - 1);
    const float* W = (m == 0) ? Wq : (m == 1) ? Wk : Wv;
    wqkvf[i] = f2bf(W[k * C_ + c]);
}

__global__ void k_wcvt2(const float* __restrict__ w1, const float* __restrict__ w2,
                        const float* __restrict__ Wo,
                        short* __restrict__ w1f, short* __restrict__ w2f,
                        short* __restrict__ wof) {
    int i = blockIdx.x * 256 + threadIdx.x;     // 147456
    if (i < C_ * FF) {
        int tile = i >> 9, l = (i >> 3) & 63, e = i & 7;
        int jtile = tile >> 2, ks = tile & 3;
        int j = jtile * 16 + (l & 15);
        int k = ks * 32 + (l >> 4) * 8 + e;
        w1f[i] = f2bf(w1[k * FF + j]);          // w1 is [C][FF] = [k][j]
    } else if (i < 2 * C_ * FF) {
        int i2 = i - C_ * FF;
        int tile = i2 >> 9, l = (i2 >> 3) & 63, e = i2 & 7;
        int c_tile = tile >> 4, ks = tile & 15;
        int c = c_tile * 16 + (l & 15);
        int j = ks * 32 + (l >> 4) * 8 + e;
        w2f[i2] = f2bf(w2[j * C_ + c]);         // w2 is [FF][C] = [j][c]
    } else {
        int i3 = i - 2 * C_ * FF;
        int tile = i3 >> 9, l = (i3 >> 3) & 63, e = i3 & 7;
        int c_tile = tile >> 2, ks = tile & 3;
        int c = c_tile * 16 + (l & 15);
        int k = ks * 32 + (l >> 4) * 8 + e;
        wof[i3] = f2bf(Wo[k * C_ + c]);         // Wo is [C][C] = [k][c]
    }
}

// ---------------- kernel 1: QKV projection via MFMA (x = query+tepe fused in staging)
__global__ __launch_bounds__(256) void k_qkv_mfma(
    const float* __restrict__ query, const float* __restrict__ tepe,
    const short* __restrict__ wqkvf,
    short* __restrict__ Q, short* __restrict__ K, short* __restrict__ V) {
    __shared__ __align__(16) short xs[BM * C_];
    int tid = threadIdx.x;
    int r0 = blockIdx.x * BM;
    {
        int row = tid >> 3;                 // 0..31
        int cb = (tid & 7) * 16;
        int gr = r0 + row;
        int t = gr % T_;
        int b = gr / (N_ * T_);
        const float* qsrc = query + (size_t)gr * C_ + cb;
        const float* tsrc = tepe + (size_t)(b * T_ + t) * C_ + cb;
        int swz0 = (row & 7) << 3;
#pragma unroll
        for (int i = 0; i < 4; i++) {
            float4 q4 = *(const float4*)(qsrc + 4 * i);
            float4 t4 = *(const float4*)(tsrc + 4 * i);
            short4_ sv;
            sv.x = f2bf(q4.x + t4.x); sv.y = f2bf(q4.y + t4.y);
            sv.z = f2bf(q4.z + t4.z); sv.w = f2bf(q4.w + t4.w);
            *(short4_*)&xs[(row * C_ + cb + 4 * i) ^ swz0] = sv;
        }
    }
    __syncthreads();
    int w = tid >> 6, l = tid & 63;
    int lr = l & 15, lk = l >> 4;
    int swz = (lr & 7) << 3;                // row-tile-invariant swizzle
    short8 bx[2][4];
#pragma unroll
    for (int rt = 0; rt < 2; rt++)
#pragma unroll
        for (int ks = 0; ks < 4; ks++)
            bx[rt][ks] = *(const short8*)&xs[((rt * 16 + lr) * C_ + ks * 32 + lk * 8) ^ swz];
    size_t base[2];
#pragma unroll
    for (int rt = 0; rt < 2; rt++) {
        int gr = r0 + rt * 16 + lr;
        int t = gr % T_;
        int n = (gr / T_) % N_;
        int b = gr / (N_ * T_);
        base[rt] = ((size_t)b * H_ * N_ + n) * (T_ * D_) + t * D_;
    }
#pragma unroll
    for (int jt = 0; jt < 6; jt++) {
        int ctile = w * 6 + jt;                 // c-tile index 0..23
        const short* ap = wqkvf + (size_t)ctile * 2048 + l * 8;
        short8 acur[4];
#pragma unroll
        for (int ks = 0; ks < 4; ks++) acur[ks] = *(const short8*)(ap + ks * 512);
        f32x4 acc[2] = {{0.f, 0.f, 0.f, 0.f}, {0.f, 0.f, 0.f, 0.f}};
#pragma unroll
        for (int ks = 0; ks < 4; ks++) {
#pragma unroll
            for (int rt = 0; rt < 2; rt++)
                acc[rt] = __builtin_amdgcn_mfma_f32_16x16x32_bf16(acur[ks], bx[rt][ks], acc[rt], 0, 0, 0);
        }
        int c0 = ctile * 16 + lk * 4;
        int m = c0 >> 7;
        int c = c0 & (C_ - 1);
        int h = c >> 4, d = c & 15;
        short* dst = (m == 0) ? Q : (m == 1) ? K : V;
#pragma unroll
        for (int rt = 0; rt < 2; rt++) {
            short4_ sv;
            sv.x = f2bf(acc[rt][0]); sv.y = f2bf(acc[rt][1]);
            sv.z = f2bf(acc[rt][2]); sv.w = f2bf(acc[rt][3]);
            *(short4_*)&dst[base[rt] + (size_t)h * (N_ * T_ * D_) + d] = sv;
        }
    }
}

// ---------------- kernel 2: attention, 4 units per 256-thread block (1 wave/unit)
__global__ __launch_bounds__(256) void k_attn(
    const short* __restrict__ Q, const short* __restrict__ K, const short* __restrict__ V,
    const unsigned char* __restrict__ cntg, short* __restrict__ ctx) {
    __shared__ __align__(16) short Qbf[4][32 * 24], Kbf[4][32 * 24];
    __shared__ __align__(16) short Vt[4][16 * 40];       // [d][t2], cols 24-31 zeroed
    __shared__ __align__(16) short Pbf[4][32 * 40];      // attn weights, cols 24-31 zeroed
    __shared__ unsigned char cntS[T_ * 32];              // shared by all 4 units
    __shared__ float Mv[4][T_];
    __shared__ int keepS[4][T_];
    __shared__ float meanVs[4][D_];
    int tid = threadIdx.x;
    int wid = tid >> 6, l = tid & 63;
    int e = blockIdx.x * 4 + wid;
    const short* qb = Q + (size_t)e * (T_ * D_);
    const short* kb = K + (size_t)e * (T_ * D_);
    const short* vb = V + (size_t)e * (T_ * D_);
    if (l < 48) {
        int t = l >> 1, hf = l & 1;
        *(short8*)&Qbf[wid][t * 24 + hf * 8] = *(const short8*)(qb + t * 16 + hf * 8);
        *(short8*)&Kbf[wid][t * 24 + hf * 8] = *(const short8*)(kb + t * 16 + hf * 8);
    }
    for (int i = l; i < 96; i += 64) {
        int t = i >> 2, c4 = i & 3;
        short4_ v = *(const short4_*)(vb + t * 16 + c4 * 4);
        Vt[wid][(c4 * 4 + 0) * 40 + t] = v.x;
        Vt[wid][(c4 * 4 + 1) * 40 + t] = v.y;
        Vt[wid][(c4 * 4 + 2) * 40 + t] = v.z;
        Vt[wid][(c4 * 4 + 3) * 40 + t] = v.w;
    }
    for (int i = l; i < 128; i += 64) {       // zero Vt cols 24-31
        int d = i >> 3, c = 24 + (i & 7);
        Vt[wid][d * 40 + c] = 0;
    }
    if (tid < 192) ((int*)cntS)[tid] = ((const int*)cntg)[tid];
    __syncthreads();
    if (l >= 48) {
        int d = l - 48;
        float s = 0.f;
        for (int t = 0; t < T_; t++) s += bf2f(Vt[wid][d * 40 + t]);
        meanVs[wid][d] = s * (1.0f / T_);
    }
    int lr = l & 15, lk = l >> 4;
    short8 zz = {};
    short8 kf0 = zz, kf1 = zz, qf0 = zz, qf1 = zz;
    if (lk < 2) {
        kf0 = *(const short8*)&Kbf[wid][lr * 24 + lk * 8];
        kf1 = *(const short8*)&Kbf[wid][(16 + lr) * 24 + lk * 8];
        qf0 = *(const short8*)&Qbf[wid][lr * 24 + lk * 8];
        qf1 = *(const short8*)&Qbf[wid][(16 + lr) * 24 + lk * 8];
    }
    f32x4 zf = {0.f, 0.f, 0.f, 0.f};
    f32x4 s00 = __builtin_amdgcn_mfma_f32_16x16x32_bf16(kf0, qf0, zf, 0, 0, 0);
    f32x4 s01 = __builtin_amdgcn_mfma_f32_16x16x32_bf16(kf1, qf0, zf, 0, 0, 0);
    f32x4 s10 = __builtin_amdgcn_mfma_f32_16x16x32_bf16(kf0, qf1, zf, 0, 0, 0);
    f32x4 s11 = __builtin_amdgcn_mfma_f32_16x16x32_bf16(kf1, qf1, zf, 0, 0, 0);
#pragma unroll
    for (int rt = 0; rt < 2; rt++) {
        int t = rt * 16 + lr;
        int tt = (t < T_) ? t : 0;
        f32x4 c0 = rt ? s10 : s00;
        f32x4 c1 = rt ? s11 : s01;
        float mx = -1e30f, sm = 0.f;
#pragma unroll
        for (int i = 0; i < 4; i++) {
            int cA = cntS[tt * 32 + lk * 4 + i];
            if (cA) { mx = fmaxf(mx, c0[i]); sm += (float)cA * c0[i]; }
        }
        if (lk < 2) {
#pragma unroll
            for (int i = 0; i < 4; i++) {
                int cB = cntS[tt * 32 + 16 + lk * 4 + i];
                if (cB) { mx = fmaxf(mx, c1[i]); sm += (float)cB * c1[i]; }
            }
        }
        mx = fmaxf(mx, __shfl_xor(mx, 16));
        mx = fmaxf(mx, __shfl_xor(mx, 32));
        sm += __shfl_xor(sm, 16);
        sm += __shfl_xor(sm, 32);
        if (lk == 0 && t < T_) Mv[wid][t] = mx - sm * (1.0f / S_);
    }
    __syncthreads();
    if (l < T_) {
        float mt = Mv[wid][l];
        int cnt2 = 0;
        for (int t2 = 0; t2 < T_; t2++) {
            float m2 = Mv[wid][t2];
            cnt2 += (m2 > mt) || (m2 == mt && t2 < l);
        }
        keepS[wid][l] = (cnt2 < U_) ? 1 : 0;
    }
#pragma unroll
    for (int rt = 0; rt < 2; rt++) {
        f32x4 c0 = rt ? s10 : s00;
        f32x4 c1 = rt ? s11 : s01;
        float lm = fmaxf(fmaxf(c0[0], c0[1]), fmaxf(c0[2], c0[3]));
        if (lk < 2) lm = fmaxf(lm, fmaxf(fmaxf(c1[0], c1[1]), fmaxf(c1[2], c1[3])));
        lm = fmaxf(lm, __shfl_xor(lm, 16));
        lm = fmaxf(lm, __shfl_xor(lm, 32));
        float e0[4], e1[4];
        float ls = 0.f;
#pragma unroll
        for (int i = 0; i < 4; i++) { e0[i] = __expf(0.25f * (c0[i] - lm)); ls += e0[i]; }
#pragma unroll
        for (int i = 0; i < 4; i++) { e1[i] = (lk < 2) ? __expf(0.25f * (c1[i] - lm)) : 0.f; ls += e1[i]; }
        ls += __shfl_xor(ls, 16);
        ls += __shfl_xor(ls, 32);
        float inv = 1.0f / ls;
        short4_ w0, w1;
        w0.x = f2bf(e0[0] * inv); w0.y = f2bf(e0[1] * inv);
        w0.z = f2bf(e0[2] * inv); w0.w = f2bf(e0[3] * inv);
        w1.x = f2bf(e1[0] * inv); w1.y = f2bf(e1[1] * inv);
        w1.z = f2bf(e1[2] * inv); w1.w = f2bf(e1[3] * inv);
        int trow = rt * 16 + lr;
        *(short4_*)&Pbf[wid][trow * 40 + lk * 4] = w0;
        *(short4_*)&Pbf[wid][trow * 40 + 16 + lk * 4] = w1;   // lk>=2 writes zeros
    }
    __syncthreads();
    short8 vf = *(const short8*)&Vt[wid][lr * 40 + lk * 8];
    short8 pf0 = *(const short8*)&Pbf[wid][lr * 40 + lk * 8];
    short8 pf1 = *(const short8*)&Pbf[wid][(16 + lr) * 40 + lk * 8];
    f32x4 u0 = __builtin_amdgcn_mfma_f32_16x16x32_bf16(vf, pf0, zf, 0, 0, 0);
    f32x4 u1 = __builtin_amdgcn_mfma_f32_16x16x32_bf16(vf, pf1, zf, 0, 0, 0);
    int b = e / (H_ * N_);
    int h = (e / N_) % H_;
    int n = e % N_;
    float4 mv4 = *(const float4*)&meanVs[wid][lk * 4];
#pragma unroll
    for (int rt = 0; rt < 2; rt++) {
        int t = rt * 16 + lr;
        if (t < T_) {
            f32x4 u = rt ? u1 : u0;
            float4 o;
            if (keepS[wid][t]) { o.x = u[0]; o.y = u[1]; o.z = u[2]; o.w = u[3]; }
            else o = mv4;
            short4_ sv;
            sv.x = f2bf(o.x); sv.y = f2bf(o.y); sv.z = f2bf(o.z); sv.w = f2bf(o.w);
            *(short4_*)&ctx[((size_t)(b * N_ + n) * T_ + t) * C_ + h * D_ + lk * 4] = sv;
        }
    }
}

// ---------------- kernel 3: fused tail — Wo GEMM + LN1 + FF + LN2 -> out
// 64 rows, 512 threads, exactly 80 KB LDS (2 blocks/CU). Phase-aliased LDS:
//   [0,16K) cbf | [16K,50K) xf  --(after LN1)-->  [0,64K) hbf | [64K,80K) x1bf
//   yf (f32 y for LN2) aliases hbf[0,33.8K).
__global__ __launch_bounds__(512, 4) void k_tail(
    const short* __restrict__ ctx, const short* __restrict__ wof, const float* __restrict__ bo,
    const float* __restrict__ query, const float* __restrict__ tepe,
    const float* __restrict__ g1, const float* __restrict__ b1,
    const short* __restrict__ w1f, const float* __restrict__ b1f,
    const short* __restrict__ w2f, const float* __restrict__ b2f,
    const float* __restrict__ g2, const float* __restrict__ b2ln,
    float* __restrict__ out) {
    __shared__ __align__(16) char smem[81920];
    short* cbf = (short*)smem;                          // 64x128 bf16, swizzled
    float (*xf)[132] = (float(*)[132])(smem + 16384);   // 64x132 f32
    short* x1bf = (short*)(smem + 65536);               // 64x128 bf16, swizzled
    short* hbf = (short*)smem;                          // 64x512 bf16, swizzled
    float (*yf)[132] = (float(*)[132])smem;             // 64x132 f32
    int tid = threadIdx.x;
    int r0 = blockIdx.x * BMT;
    // ---- phase 0: stage ctx -> cbf, query+tepe -> xf
    {
        int row = tid >> 3;                 // 0..63
        int cb = (tid & 7) * 16;
        int gr = r0 + row;
        int t = gr % T_;
        int b = gr / (N_ * T_);
        const short* csrc = ctx + (size_t)gr * C_ + cb;
        const float* qsrc = query + (size_t)gr * C_ + cb;
        const float* tsrc = tepe + (size_t)(b * T_ + t) * C_ + cb;
        int swz0 = (row & 7) << 3;
        *(short8*)&cbf[(row * C_ + cb) ^ swz0] = *(const short8*)csrc;
        *(short8*)&cbf[(row * C_ + cb + 8) ^ swz0] = *(const short8*)(csrc + 8);
#pragma unroll
        for (int i = 0; i < 4; i++) {
            float4 q4 = *(const float4*)(qsrc + 4 * i);
            float4 t4 = *(const float4*)(tsrc + 4 * i);
            float4 xr;
            xr.x = q4.x + t4.x; xr.y = q4.y + t4.y;
            xr.z = q4.z + t4.z; xr.w = q4.w + t4.w;
            *(float4*)&xf[row][cb + 4 * i] = xr;
        }
    }
    __syncthreads();
    int w = tid >> 6, l = tid & 63;
    int lr = l & 15, lk = l >> 4;
    int swz = (lr & 7) << 3;
    // ---- phase 1: Wo GEMM, wave w owns c-tile w x all 4 row-tiles; y -> xf
    {
        const short* ap = wof + (size_t)w * 2048 + l * 8;
        f32x4 acc[4] = {{0.f, 0.f, 0.f, 0.f}, {0.f, 0.f, 0.f, 0.f},
                        {0.f, 0.f, 0.f, 0.f}, {0.f, 0.f, 0.f, 0.f}};
#pragma unroll
        for (int ks = 0; ks < 4; ks++) {
            short8 aw = *(const short8*)(ap + ks * 512);
#pragma unroll
            for (int rt = 0; rt < 4; rt++) {
                short8 bc = *(const short8*)&cbf[((rt * 16 + lr) * C_ + ks * 32 + lk * 8) ^ swz];
                acc[rt] = __builtin_amdgcn_mfma_f32_16x16x32_bf16(aw, bc, acc[rt], 0, 0, 0);
            }
        }
        int cc = w * 16 + lk * 4;
        float4 bias = *(const float4*)(bo + cc);
#pragma unroll
        for (int rt = 0; rt < 4; rt++) {
            int rr = rt * 16 + lr;
            float4 res = *(const float4*)&xf[rr][cc];
            float4 o;
            o.x = acc[rt][0] + bias.x + res.x;
            o.y = acc[rt][1] + bias.y + res.y;
            o.z = acc[rt][2] + bias.z + res.z;
            o.w = acc[rt][3] + bias.w + res.w;
            *(float4*)&xf[rr][cc] = o;
        }
    }
    __syncthreads();
    // ---- phase 2: LN1 -> x1bf (bf16, swizzled)
    {
        int r = tid >> 3;
        int q = tid & 7;
        int cb = q * 16;
        float vals[16];
        float s = 0.f;
#pragma unroll
        for (int i = 0; i < 16; i++) { vals[i] = xf[r][cb + i]; s += vals[i]; }
        s += __shfl_xor(s, 1, 8);
        s += __shfl_xor(s, 2, 8);
        s += __shfl_xor(s, 4, 8);
        float mean = s * (1.f / C_);
        float vv = 0.f;
#pragma unroll
        for (int i = 0; i < 16; i++) { float d = vals[i] - mean; vv += d * d; }
        vv += __shfl_xor(vv, 1, 8);
        vv += __shfl_xor(vv, 2, 8);
        vv += __shfl_xor(vv, 4, 8);
        float rstd = rsqrtf(vv * (1.f / C_) + 1e-5f);
        short8 o0, o1;
#pragma unroll
        for (int i = 0; i < 8; i++) {
            o0[i] = f2bf((vals[i] - mean) * rstd * g1[cb + i] + b1[cb + i]);
            o1[i] = f2bf((vals[8 + i] - mean) * rstd * g1[cb + 8 + i] + b1[cb + 8 + i]);
        }
        int swz0 = (r & 7) << 3;
        // NOTE: x1bf does not alias xf; safe to write before the barrier
        *(short8*)&x1bf[(r * C_ + cb) ^ swz0] = o0;
        *(short8*)&x1bf[(r * C_ + cb + 8) ^ swz0] = o1;
    }
    __syncthreads();    // xf/cbf dead from here; hbf may overwrite
    // ---- phase 3: FF GEMM1 -> hbf
    {
        short8 bx[4][4];
#pragma unroll
        for (int rt = 0; rt < 4; rt++)
#pragma unroll
            for (int ks = 0; ks < 4; ks++)
                bx[rt][ks] = *(const short8*)&x1bf[((rt * 16 + lr) * C_ + ks * 32 + lk * 8) ^ swz];
#pragma unroll
        for (int jt = 0; jt < 4; jt++) {
            int jtile = w * 4 + jt;             // 0..31
            const short* ap = w1f + (size_t)jtile * 2048 + l * 8;
            short8 acur[4];
#pragma unroll
            for (int ks = 0; ks < 4; ks++) acur[ks] = *(const short8*)(ap + ks * 512);
            f32x4 acc[4] = {{0.f, 0.f, 0.f, 0.f}, {0.f, 0.f, 0.f, 0.f},
                            {0.f, 0.f, 0.f, 0.f}, {0.f, 0.f, 0.f, 0.f}};
#pragma unroll
            for (int ks = 0; ks < 4; ks++) {
#pragma unroll
                for (int rt = 0; rt < 4; rt++)
                    acc[rt] = __builtin_amdgcn_mfma_f32_16x16x32_bf16(acur[ks], bx[rt][ks], acc[rt], 0, 0, 0);
            }
            int j0 = jtile * 16 + lk * 4;
            float4 bias = *(const float4*)(b1f + j0);
#pragma unroll
            for (int rt = 0; rt < 4; rt++) {
                int rr = rt * 16 + lr;
                short4_ hv;
                hv.x = f2bf(fmaxf(acc[rt][0] + bias.x, 0.f));
                hv.y = f2bf(fmaxf(acc[rt][1] + bias.y, 0.f));
                hv.z = f2bf(fmaxf(acc[rt][2] + bias.z, 0.f));
                hv.w = f2bf(fmaxf(acc[rt][3] + bias.w, 0.f));
                *(short4_*)&hbf[(rr * FF + j0) ^ swz] = hv;
            }
        }
    }
    __syncthreads();
    // ---- phase 4: FF GEMM2; residual from x1bf
    f32x4 acc2[4] = {{0.f, 0.f, 0.f, 0.f}, {0.f, 0.f, 0.f, 0.f},
                     {0.f, 0.f, 0.f, 0.f}, {0.f, 0.f, 0.f, 0.f}};
#pragma unroll 4
    for (int ks = 0; ks < 16; ks++) {
        short8 aw = *(const short8*)(w2f + ((size_t)(w * 16 + ks)) * 512 + l * 8);
#pragma unroll
        for (int rt = 0; rt < 4; rt++) {
            short8 hx = *(const short8*)&hbf[((rt * 16 + lr) * FF + ks * 32 + lk * 8) ^ swz];
            acc2[rt] = __builtin_amdgcn_mfma_f32_16x16x32_bf16(aw, hx, acc2[rt], 0, 0, 0);
        }
    }
    int cc = w * 16 + lk * 4;
    float4 bias2 = *(const float4*)(b2f + cc);
    float4 res[4];
#pragma unroll
    for (int rt = 0; rt < 4; rt++) {
        short4_ rb = *(const short4_*)&x1bf[((rt * 16 + lr) * C_ + cc) ^ swz];
        res[rt].x = bf2f(rb.x); res[rt].y = bf2f(rb.y);
        res[rt].z = bf2f(rb.z); res[rt].w = bf2f(rb.w);
    }
    __syncthreads();    // all hbf reads done -> safe to overwrite with y
#pragma unroll
    for (int rt = 0; rt < 4; rt++) {
        float4 o;
        o.x = acc2[rt][0] + bias2.x + res[rt].x;
        o.y = acc2[rt][1] + bias2.y + res[rt].y;
        o.z = acc2[rt][2] + bias2.z + res[rt].z;
        o.w = acc2[rt][3] + bias2.w + res[rt].w;
        *(float4*)&yf[rt * 16 + lr][cc] = o;
    }
    __syncthreads();
    // ---- phase 5: LN2 + store
    {
        int r = tid >> 3;
        int q = tid & 7;
        int cb = q * 16;
        float vals[16];
        float s = 0.f;
#pragma unroll
        for (int i = 0; i < 16; i++) { vals[i] = yf[r][cb + i]; s += vals[i]; }
        s += __shfl_xor(s, 1, 8);
        s += __shfl_xor(s, 2, 8);
        s += __shfl_xor(s, 4, 8);
        float mean = s * (1.f / C_);
        float vv = 0.f;
#pragma unroll
        for (int i = 0; i < 16; i++) { float d = vals[i] - mean; vv += d * d; }
        vv += __shfl_xor(vv, 1, 8);
        vv += __shfl_xor(vv, 2, 8);
        vv += __shfl_xor(vv, 4, 8);
        float rstd = rsqrtf(vv * (1.f / C_) + 1e-5f);
        float* op = out + (size_t)(r0 + r) * C_ + cb;
#pragma unroll
        for (int i4 = 0; i4 < 4; i4++) {
            float4 gv = *(const float4*)(g2 + cb + 4 * i4);
            float4 bv = *(const float4*)(b2ln + cb + 4 * i4);
            float4 ov;
            ov.x = (vals[4 * i4 + 0] - mean) * rstd * gv.x + bv.x;
            ov.y = (vals[4 * i4 + 1] - mean) * rstd * gv.y + bv.y;
            ov.z = (vals[4 * i4 + 2] - mean) * rstd * gv.z + bv.z;
            ov.w = (vals[4 * i4 + 3] - mean) * rstd * gv.w + bv.w;
            *(float4*)(op + 4 * i4) = ov;
        }
    }
}

extern "C" void kernel_launch(void* const* d_in, const int* in_sizes, int n_in,
                              void* d_out, int out_size, void* d_ws, size_t ws_size,
                              hipStream_t stream) {
    const float* query = (const float*)d_in[2];
    const int* time_enc = (const int*)d_in[4];
    const int* index_sample = (const int*)d_in[5];
    const float* e_min = (const float*)d_in[6];
    const float* e_hr  = (const float*)d_in[7];
    const float* e_wd  = (const float*)d_in[8];
    const float* e_mo  = (const float*)d_in[9];
    const float* e_yr  = (const float*)d_in[10];
    const float* Wq = (const float*)d_in[11];
    const float* Wk = (const float*)d_in[12];
    const float* Wv = (const float*)d_in[13];
    const float* Wo = (const float*)d_in[14];
    const float* bo = (const float*)d_in[15];
    const float* ffw1 = (const float*)d_in[16];
    const float* ffb1 = (const float*)d_in[17];
    const float* ffw2 = (const float*)d_in[18];
    const float* ffb2 = (const float*)d_in[19];
    const float* ln1g = (const float*)d_in[20];
    const float* ln1b = (const float*)d_in[21];
    const float* ln2g = (const float*)d_in[22];
    const float* ln2b = (const float*)d_in[23];

    float* ws = (float*)d_ws;
    float* tepe = ws;                     // TEPE_N floats
    float* region1 = ws + TEPE_N;         // NX floats: bf16 Q
    float* region2 = region1 + NX;        // NX floats: bf16 K, then w1f/w2f/wof
    float* region3 = region2 + NX;        // NX floats: bf16 V
    float* region4 = region3 + NX;        // NX floats: bf16 ctx + wqkvf + cntg

    short* Qb = (short*)region1;
    short* Kb = (short*)region2;
    short* Vb = (short*)region3;
    short* ctxb = (short*)region4;
    short* wqkvf = (short*)region4 + NX;        // dead after qkv
    unsigned char* cntg = (unsigned char*)((short*)region4 + NX + 49152);  // 768 B
    short* w1f = (short*)region2;               // K dead after attn
    short* w2f = w1f + C_ * FF;
    short* wof = w2f + C_ * FF;

    k_tepe<<<dim3(TEPE_N / 256), dim3(256), 0, stream>>>(
        time_enc, e_min, e_hr, e_wd, e_mo, e_yr, tepe, index_sample, cntg);
    k_wcvt_qkv<<<dim3(384 * C_ / 256), dim3(256), 0, stream>>>(Wq, Wk, Wv, wqkvf);
    k_qkv_mfma<<<dim3(NBLK_MM), dim3(256), 0, stream>>>(
        query, tepe, wqkvf, Qb, Kb, Vb);
    k_attn<<<dim3(NUNIT / 4), dim3(256), 0, stream>>>(
        Qb, Kb, Vb, cntg, ctxb);
    k_wcvt2<<<dim3((2 * C_ * FF + C_ * C_) / 256), dim3(256), 0, stream>>>(
        ffw1, ffw2, Wo, w1f, w2f, wof);
    k_tail<<<dim3(NBLK_T), dim3(512), 0, stream>>>(
        ctxb, wof, bo, query, tepe, ln1g, ln1b,
        w1f, ffb1, w2f, ffb2, ln2g, ln2b, (float*)d_out);
}